// Round 14
// baseline (1344.390 us; speedup 1.0000x reference)
//
#include <hip/hip_runtime.h>

typedef unsigned short u16;
typedef __bf16 v8bf __attribute__((ext_vector_type(8)));
typedef unsigned short v8u __attribute__((ext_vector_type(8)));
typedef unsigned short v4u __attribute__((ext_vector_type(4)));
typedef float f32x4 __attribute__((ext_vector_type(4)));
typedef float v8f __attribute__((ext_vector_type(8)));

static constexpr int DIMC = 768;
static constexpr int HEADS = 12;
static constexpr int WINS  = 14;
static constexpr int ACCH  = 192;   // adapter channels
static constexpr int NTOK  = 196;   // 14*14
static constexpr int MW    = 24500; // 125 windows * 196 tokens
static constexpr int MWP   = 24576; // padded to tile multiple
static constexpr int MS    = 20480; // 5*64*64 spatial tokens

__device__ __forceinline__ float bf2f(u16 u) {
  union { unsigned int i; float f; } x; x.i = ((unsigned int)u) << 16; return x.f;
}
__device__ __forceinline__ u16 f2bf(float f) {
  union { float f; unsigned int i; } x; x.f = f;
  unsigned int r = x.i + 0x7fffu + ((x.i >> 16) & 1u);
  return (u16)(r >> 16);
}
// fast tanh-form GELU: max abs err ~2e-3 (well under threshold)
__device__ __forceinline__ float gelu_f(float x) {
  float y = 0.79788456080286536f * (x + 0.044715f * x * x * x);
  y = fminf(fmaxf(y, -15.f), 15.f);
  const float e = __expf(2.f * y);
  const float th = 1.f - 2.f * __builtin_amdgcn_rcpf(e + 1.f);
  return 0.5f * x * (1.f + th);
}
// async global->LDS, 16B per lane. LDS dest is wave-uniform base + lane*16.
__device__ __forceinline__ void cp16(const u16* g, u16* l) {
  __builtin_amdgcn_global_load_lds(
      (const __attribute__((address_space(1))) unsigned int*)(const void*)g,
      (__attribute__((address_space(3))) unsigned int*)(void*)l, 16, 0, 0);
}

// ---------------- weight prep ----------------
__global__ void k_zero16(u16* p, int n) {
  int i = blockIdx.x * 256 + threadIdx.x;
  if (i < n) p[i] = 0;
}
// U[k][b] = sum_a facu_W[a][k] * fac_W[b][a]   (fac = qfac or vfac)
__global__ void k_compute_U(const float* __restrict__ facu, const float* __restrict__ qfac,
                            const float* __restrict__ vfac, float* __restrict__ Uq,
                            float* __restrict__ Uv) {
  int idx = blockIdx.x * 256 + threadIdx.x;
  if (idx >= 2 * 768 * 32) return;
  const int which = idx / (768 * 32);
  const int rem = idx - which * 768 * 32;
  const int k = rem >> 5, b = rem & 31;
  const float* fac = which ? vfac : qfac;
  float s = 0.f;
  for (int a = 0; a < 32; ++a) s += facu[a * 768 + k] * fac[b * 32 + a];
  (which ? Uv : Uq)[rem] = s;
}
// Wc[n][k] = qkv_W[n][k] (+ sum_b U{q,v}[k][b]*facv_W[n'][b] for q/v blocks), cast bf16
__global__ void k_build_wcomb(const float* __restrict__ qkvW, const float* __restrict__ Uq,
                              const float* __restrict__ Uv, const float* __restrict__ facv,
                              u16* __restrict__ Wc) {
  int idx = blockIdx.x * 256 + threadIdx.x;
  if (idx >= 2304 * 768) return;
  const int n = idx / 768, k = idx - n * 768;
  float v = qkvW[idx];
  if (n < 768) {
    float s = 0.f;
    for (int b = 0; b < 32; ++b) s += Uq[k * 32 + b] * facv[n * 32 + b];
    v += s;
  } else if (n >= 1536) {
    const int nn = n - 1536;
    float s = 0.f;
    for (int b = 0; b < 32; ++b) s += Uv[k * 32 + b] * facv[nn * 32 + b];
    v += s;
  }
  Wc[idx] = f2bf(v);
}
// vectorized cast+pad: 4 elems/thread (cols % 4 == 0 so a group shares its row)
__global__ void k_cast_pad(const float* __restrict__ src, u16* __restrict__ dst,
                           int rows, int cols, int rowsPad) {
  int idx = blockIdx.x * 256 + threadIdx.x;
  const int base = idx * 4;
  if (base >= rowsPad * cols) return;
  const int r = base / cols;
  v4u o;
  if (r < rows) {
    const float4 v = *(const float4*)(src + base);
    o[0] = f2bf(v.x); o[1] = f2bf(v.y); o[2] = f2bf(v.z); o[3] = f2bf(v.w);
  } else {
    o[0] = o[1] = o[2] = o[3] = 0;
  }
  *(v4u*)(dst + base) = o;
}
// ac_W [192][192][3][3][3] -> Wconv [256 pad][27*192] with k = tap*192+ci  (4 ci/thread)
__global__ void k_conv_repack(const float* __restrict__ src, u16* __restrict__ dst) {
  int idx = blockIdx.x * 256 + threadIdx.x;
  const int base = idx * 4;
  if (base >= 256 * 5184) return;
  const int co = base / 5184;
  const int rem = base - co * 5184;
  const int tap = rem / 192, ci = rem - tap * 192;   // ci % 4 == 0 (192 % 4 == 0)
  v4u o;
  if (co < 192) {
    const float* sp = src + co * 5184 + ci * 27 + tap;
#pragma unroll
    for (int e = 0; e < 4; ++e) o[e] = f2bf(sp[e * 27]);
  } else {
    o[0] = o[1] = o[2] = o[3] = 0;
  }
  *(v4u*)(dst + base) = o;
}

// ---------------- LayerNorm (optionally fused window-partition) ----------------
template<bool WINDOWED>
__global__ __launch_bounds__(256)
void ln_k(const float* __restrict__ X, const float* __restrict__ w,
          const float* __restrict__ b, u16* __restrict__ out) {
  const int r = (int)blockIdx.x;
  const int t = (int)threadIdx.x;
  int src = r;
  bool zero = false;
  if (WINDOWED) {
    if (r >= MW) zero = true;
    else {
      const int win = r / NTOK, tk = r - win * NTOK;
      const int img = win / 25, wrem = win - img * 25, wy = wrem / 5, wx = wrem - wy * 5;
      const int ty = tk / WINS, tx = tk - ty * WINS;
      const int y = wy * WINS + ty, x = wx * WINS + tx;
      if (y >= 64 || x >= 64) zero = true;
      else src = (img << 12) + (y << 6) + x;
    }
  }
  u16* orow = out + (size_t)r * DIMC;
  if (zero) {
    for (int c = t; c < DIMC; c += 256) orow[c] = 0;
    return;
  }
  const float* xr = X + (size_t)src * DIMC;
  const float v0 = xr[t], v1 = xr[t + 256], v2 = xr[t + 512];
  float s = v0 + v1 + v2, ss = v0 * v0 + v1 * v1 + v2 * v2;
#pragma unroll
  for (int o = 32; o > 0; o >>= 1) { s += __shfl_xor(s, o, 64); ss += __shfl_xor(ss, o, 64); }
  __shared__ float red[8];
  const int wave = t >> 6, lane = t & 63;
  if (lane == 0) { red[wave] = s; red[4 + wave] = ss; }
  __syncthreads();
  s = red[0] + red[1] + red[2] + red[3];
  ss = red[4] + red[5] + red[6] + red[7];
  const float mean = s * (1.0f / 768.0f);
  const float var = ss * (1.0f / 768.0f) - mean * mean;
  const float rstd = rsqrtf(var + 1e-5f);
  orow[t]       = f2bf((v0 - mean) * rstd * w[t]       + b[t]);
  orow[t + 256] = f2bf((v1 - mean) * rstd * w[t + 256] + b[t + 256]);
  orow[t + 512] = f2bf((v2 - mean) * rstd * w[t + 512] + b[t + 512]);
}

// ---------------- 128-tile GEMM (small-N ops: down / conv) ----------------
// EPI: 1 = bf16 out (bias); 2 = bf16 out (bias+GELU)
// CONV: A rows gathered as 3x3x3 SAME conv over [5][64][64][192]; K = tap*192+ci
template<int EPI, bool CONV>
__global__ __launch_bounds__(256)
void gemm_bt(const u16* __restrict__ A, const u16* __restrict__ B,
             const float* __restrict__ bias, const float* __restrict__ resid,
             float* __restrict__ outF, u16* __restrict__ outB,
             int M, int N, int K, const u16* __restrict__ zrow, int GN) {
  __shared__ u16 smem[2 * 128 * 64];
  u16* At = smem;
  u16* Bt = smem + 128 * 64;
  const int gx = (int)gridDim.x;
  const int nwg = gx * (int)gridDim.y;
  const int lin = (int)blockIdx.y * gx + (int)blockIdx.x;
  const int csz = nwg >> 3;
  const int xcd = lin & 7;
  const int c = lin >> 3;
  const int bmc = csz / gx;
  const int gsz = bmc * GN;
  const int grp = c / gsz, rr = c - grp * gsz;
  const int bn = grp * GN + (rr % GN);
  const int bm = xcd * bmc + (rr / GN);
  const int t = (int)threadIdx.x;
  const int wave = t >> 6, lane = t & 63;
  const int wm = wave >> 1, wn = wave & 1;
  const int lrow = lane >> 3;
  const int c16s = (lane & 7) ^ lrow;
  const int li = lane & 15, lq = lane >> 4;

  f32x4 acc[4][4];
  const f32x4 vzero = {0.f, 0.f, 0.f, 0.f};
#pragma unroll
  for (int a = 0; a < 4; ++a)
#pragma unroll
    for (int b = 0; b < 4; ++b) acc[a][b] = vzero;

  const int nk = K >> 6;
  for (int kt = 0; kt < nk; ++kt) {
    int cD = 0, cY = 0, cX = 0, cblk = 0;
    if (CONV) {
      const int tap = kt / 3;
      cblk = (kt - tap * 3) << 6;
      const int kd = tap / 9, r9 = tap - kd * 9, ky = r9 / 3;
      cD = kd - 1; cY = ky - 1; cX = (r9 - ky * 3) - 1;
    }
#pragma unroll
    for (int i = 0; i < 4; ++i) {           // stage A: 128x64 bf16
      const int r0 = i * 32 + wave * 8;
      const int grow = bm * 128 + r0 + lrow;
      const u16* src;
      if (CONV) {
        const int d = (grow >> 12) + cD, y = ((grow >> 6) & 63) + cY, x = (grow & 63) + cX;
        if ((unsigned)d < 5u && (unsigned)y < 64u && (unsigned)x < 64u)
          src = A + (size_t)((d << 12) + (y << 6) + x) * ACCH + cblk + c16s * 8;
        else
          src = zrow + c16s * 8;
      } else {
        src = A + (size_t)grow * K + (kt << 6) + c16s * 8;
      }
      cp16(src, &At[r0 * 64]);
    }
#pragma unroll
    for (int i = 0; i < 4; ++i) {           // stage B: 128x64 bf16
      const int r0 = i * 32 + wave * 8;
      const int grow = bn * 128 + r0 + lrow;
      cp16(B + (size_t)grow * K + (kt << 6) + c16s * 8, &Bt[r0 * 64]);
    }
    __syncthreads();
#pragma unroll
    for (int kk = 0; kk < 2; ++kk) {
      v8bf af[4], bg[4];
#pragma unroll
      for (int mf = 0; mf < 4; ++mf) {
        const int row = wm * 64 + mf * 16 + li;
        const int c16 = (kk * 4 + lq) ^ (li & 7);
        af[mf] = *(const v8bf*)&At[row * 64 + c16 * 8];
      }
#pragma unroll
      for (int nf = 0; nf < 4; ++nf) {
        const int row = wn * 64 + nf * 16 + li;
        const int c16 = (kk * 4 + lq) ^ (li & 7);
        bg[nf] = *(const v8bf*)&Bt[row * 64 + c16 * 8];
      }
#pragma unroll
      for (int mf = 0; mf < 4; ++mf)
#pragma unroll
        for (int nf = 0; nf < 4; ++nf)
          acc[mf][nf] = __builtin_amdgcn_mfma_f32_16x16x32_bf16(af[mf], bg[nf], acc[mf][nf], 0, 0, 0);
    }
    __syncthreads();
  }

  // epilogue: bf16 through LDS, 16B stores
  u16* Ct = smem;  // [128][128] bf16, col ^ ((row&7)<<3)
#pragma unroll
  for (int mf = 0; mf < 4; ++mf)
#pragma unroll
    for (int nf = 0; nf < 4; ++nf)
#pragma unroll
      for (int r = 0; r < 4; ++r) {
        const int row = wm * 64 + mf * 16 + lq * 4 + r;
        const int col = wn * 64 + nf * 16 + li;
        float v = acc[mf][nf][r] + bias[bn * 128 + col];
        if (EPI == 2) v = gelu_f(v);
        Ct[row * 128 + (col ^ ((row & 7) << 3))] = f2bf(v);
      }
  __syncthreads();
#pragma unroll
  for (int it = 0; it < 8; ++it) {
    const int row = it * 16 + (t >> 4);
    const int seg = t & 15;
    const int gr = bm * 128 + row;
    const int col8 = bn * 128 + seg * 8;
    if (gr < M && col8 < N) {
      v8u val = *(const v8u*)&Ct[row * 128 + ((seg ^ (row & 7)) * 8)];
      *(v8u*)(outB + (size_t)gr * N + col8) = val;
    }
  }
}

// ---------------- 128x256-tile GEMM (big-N ops): 4 waves, 128x64 per wave ----------------
// EPI: 2 = bf16 out (bias+GELU); 3 = f32 out (bias+residual);
//      4 = bf16 qkv-scatter per (win,head); 5 = f32 window-unpartition + in-place resid add
// Per-wave: acc[8][4] (128 accum regs), 64 MFMA / 24 ds_read / 12 cp16 per k-step.
template<int EPI>
__global__ __launch_bounds__(256)
void gemm_wide(const u16* __restrict__ A, const u16* __restrict__ B,
               const float* __restrict__ bias, const float* __restrict__ resid,
               float* __restrict__ outF, u16* __restrict__ outB,
               int M, int N, int K, int GN) {
  __shared__ u16 smem[(128 + 256) * 64];   // At 16 KB | Bt 32 KB (single-buffered)
  u16* At = smem;
  u16* Bt = smem + 128 * 64;
  const int gx = N >> 8;                   // 256-wide N tiles
  const int nwg = (int)gridDim.x;
  const int lin = (int)blockIdx.x;
  const int csz = nwg >> 3;
  const int xcd = lin & 7;
  const int c = lin >> 3;
  const int bmc = csz / gx;
  const int gsz = bmc * GN;
  const int grp = c / gsz, rr = c - grp * gsz;
  const int bn = grp * GN + (rr % GN);
  const int bm = xcd * bmc + (rr / GN);
  const int t = (int)threadIdx.x;
  const int wave = t >> 6, lane = t & 63;
  const int lrow = lane >> 3;
  const int c16s = (lane & 7) ^ lrow;
  const int li = lane & 15, lq = lane >> 4;

  f32x4 acc[8][4];
  const f32x4 vz = {0.f, 0.f, 0.f, 0.f};
#pragma unroll
  for (int a = 0; a < 8; ++a)
#pragma unroll
    for (int b = 0; b < 4; ++b) acc[a][b] = vz;

  const u16* Arow = A + (size_t)(bm * 128) * K;
  const u16* Brow = B + (size_t)(bn * 256) * K;

  const int nk = K >> 6;
  for (int kt = 0; kt < nk; ++kt) {
#pragma unroll
    for (int i = 0; i < 4; ++i) {           // stage A: 128 rows
      const int r0 = i * 32 + wave * 8;
      const int row = r0 + lrow;
      cp16(Arow + (size_t)row * K + (kt << 6) + c16s * 8, &At[r0 * 64]);
    }
#pragma unroll
    for (int i = 0; i < 8; ++i) {           // stage B: 256 rows
      const int r0 = i * 32 + wave * 8;
      const int row = r0 + lrow;
      cp16(Brow + (size_t)row * K + (kt << 6) + c16s * 8, &Bt[r0 * 64]);
    }
    __syncthreads();
#pragma unroll
    for (int kk = 0; kk < 2; ++kk) {
      const int c16 = (kk * 4 + lq) ^ (li & 7);
      v8bf af[8], bg[4];
#pragma unroll
      for (int mf = 0; mf < 8; ++mf) {
        const int row = mf * 16 + li;
        af[mf] = *(const v8bf*)&At[row * 64 + c16 * 8];
      }
#pragma unroll
      for (int nf = 0; nf < 4; ++nf) {
        const int row = wave * 64 + nf * 16 + li;
        bg[nf] = *(const v8bf*)&Bt[row * 64 + c16 * 8];
      }
#pragma unroll
      for (int mf = 0; mf < 8; ++mf)
#pragma unroll
        for (int nf = 0; nf < 4; ++nf)
          acc[mf][nf] = __builtin_amdgcn_mfma_f32_16x16x32_bf16(af[mf], bg[nf], acc[mf][nf], 0, 0, 0);
    }
    __syncthreads();
  }

  // ---- epilogue: chunked through LDS, vectorized stores ----
  if (EPI == 2 || EPI == 4) {
    u16* Ct = smem;  // [64][256] bf16 chunk, colseg ^ (row&7)
#pragma unroll
    for (int ch = 0; ch < 2; ++ch) {
      if (ch) __syncthreads();
#pragma unroll
      for (int m2 = 0; m2 < 4; ++m2) {
        const int mf = ch * 4 + m2;
#pragma unroll
        for (int nf = 0; nf < 4; ++nf)
#pragma unroll
          for (int r = 0; r < 4; ++r) {
            const int lr = m2 * 16 + lq * 4 + r;         // 0..63
            const int col = wave * 64 + nf * 16 + li;    // 0..255
            float v = acc[mf][nf][r] + bias[bn * 256 + col];
            if (EPI == 2) v = gelu_f(v);
            Ct[lr * 256 + (col ^ ((lr & 7) << 3))] = f2bf(v);
          }
      }
      __syncthreads();
#pragma unroll
      for (int pass = 0; pass < 8; ++pass) {
        const int row = pass * 8 + (t >> 5);             // 0..63
        const int seg = t & 31;
        const int gr = bm * 128 + ch * 64 + row;
        const int col8 = bn * 256 + seg * 8;
        if (gr < M) {
          v8u val = *(const v8u*)&Ct[row * 256 + ((seg ^ (row & 7)) * 8)];
          if (EPI == 4) {
            const int sec = col8 / 768;
            const int hm = col8 - sec * 768;
            const int hd = hm >> 6, dd = hm & 63;
            const int win = gr / 196, tk = gr - win * 196;
            *(v8u*)(outB + (size_t)(((win * HEADS + hd) * 3 + sec) * NTOK + tk) * 64 + dd) = val;
          } else {
            *(v8u*)(outB + (size_t)gr * N + col8) = val;
          }
        }
      }
    }
  } else {  // EPI 3 / 5: f32, four 32-row chunks
    float* Cf = (float*)smem;  // [32][256] f32 chunk, colseg ^ (row&3)
#pragma unroll
    for (int ch = 0; ch < 4; ++ch) {
      if (ch) __syncthreads();
#pragma unroll
      for (int m2 = 0; m2 < 2; ++m2) {
        const int mf = ch * 2 + m2;
#pragma unroll
        for (int nf = 0; nf < 4; ++nf)
#pragma unroll
          for (int r = 0; r < 4; ++r) {
            const int lr = m2 * 16 + lq * 4 + r;         // 0..31
            const int col = wave * 64 + nf * 16 + li;
            Cf[lr * 256 + (col ^ ((lr & 3) << 3))] = acc[mf][nf][r] + bias[bn * 256 + col];
          }
      }
      __syncthreads();
#pragma unroll
      for (int pass = 0; pass < 4; ++pass) {
        const int row = pass * 8 + (t >> 5);             // 0..31
        const int seg = t & 31;
        const int gr = bm * 128 + ch * 32 + row;
        const int col8 = bn * 256 + seg * 8;
        if (gr < M) {
          v8f val = *(const v8f*)&Cf[row * 256 + ((seg ^ (row & 3)) * 8)];
          if (EPI == 3) {
            const float* rp = resid + (size_t)gr * N + col8;
#pragma unroll
            for (int e = 0; e < 8; ++e) val[e] += rp[e];
            *(v8f*)(outF + (size_t)gr * N + col8) = val;
          } else {  // EPI 5
            const int win = gr / 196, tk = gr - win * 196;
            const int img = win / 25, wrem = win - img * 25, wy = wrem / 5, wx = wrem - wy * 5;
            const int ty = tk / WINS, tx = tk - ty * WINS;
            const int y = wy * WINS + ty, x = wx * WINS + tx;
            if (y < 64 && x < 64) {
              const size_t o = (size_t)((img << 12) + (y << 6) + x) * DIMC + col8;
              const float* rp = resid + o;
#pragma unroll
              for (int e = 0; e < 8; ++e) val[e] += rp[e];
              *(v8f*)(outF + o) = val;
            }
          }
        }
      }
    }
  }
}

// ---------------- fused windowed attention (round-13 version, unchanged) ----------------
__global__ __launch_bounds__(512, 2)
void attn_k(const u16* __restrict__ qkvR, const float* __restrict__ relh,
            const float* __restrict__ relw, u16* __restrict__ out) {
  const int blk = (int)blockIdx.x;
  const int win = blk / HEADS, h = blk - win * HEADS;
  const int t = (int)threadIdx.x, w = t >> 6, lane = t & 63;
  const int li = lane & 15, g = lane >> 4;
  const int nmf = (w < 6) ? 2 : (w == 6 ? 1 : 0);

  __shared__ u16 Kt[64 * 64];
  __shared__ u16 Vt[64 * 64];
  __shared__ u16 Pb[8 * 32 * 32];
  __shared__ u16 dhwT[28 * 268];

  const u16* Qb = qkvR + (size_t)(win * HEADS + h) * 3 * NTOK * 64;
  const u16* Kb = Qb + NTOK * 64;
  const u16* Vb = Kb + NTOK * 64;

  v8bf qf[2][2];
#pragma unroll
  for (int mf = 0; mf < 2; ++mf) {
    const int row = min(32 * w + mf * 16 + li, NTOK - 1);
#pragma unroll
    for (int ks = 0; ks < 2; ++ks)
      qf[mf][ks] = *(const v8bf*)(Qb + (size_t)row * 64 + ks * 32 + g * 8);
  }

  u16* relb = Pb;
  for (int idx = t; idx < 2 * 32 * 64; idx += 512) {
    const int which = idx >> 11, rem = idx & 2047, r = rem >> 6, c = rem & 63;
    const float v = (r < 27) ? (which ? relw[r * 64 + c] : relh[r * 64 + c]) : 0.f;
    relb[which * 2048 + r * 64 + (((c >> 3) ^ (r & 7)) * 8) + (c & 7)] = f2bf(v);
  }
  __syncthreads();

  {
    f32x4 dacc[2][2], eacc[2][2];
    const f32x4 vz = {0.f, 0.f, 0.f, 0.f};
#pragma unroll
    for (int mf = 0; mf < 2; ++mf)
#pragma unroll
      for (int nf = 0; nf < 2; ++nf) { dacc[mf][nf] = vz; eacc[mf][nf] = vz; }
#pragma unroll
    for (int ks = 0; ks < 2; ++ks) {
#pragma unroll
      for (int nf = 0; nf < 2; ++nf) {
        const int row = nf * 16 + li;
        const int off = row * 64 + (((ks * 4 + g) ^ (li & 7)) * 8);
        v8bf bh = *(const v8bf*)&relb[off];
        v8bf bw = *(const v8bf*)&relb[2048 + off];
#pragma unroll
        for (int mf = 0; mf < 2; ++mf) if (mf < nmf) {
          dacc[mf][nf] = __builtin_amdgcn_mfma_f32_16x16x32_bf16(qf[mf][ks], bh, dacc[mf][nf], 0, 0, 0);
          eacc[mf][nf] = __builtin_amdgcn_mfma_f32_16x16x32_bf16(qf[mf][ks], bw, eacc[mf][nf], 0, 0, 0);
        }
      }
    }
#pragma unroll
    for (int mf = 0; mf < 2; ++mf) if (mf < nmf)
#pragma unroll
      for (int nf = 0; nf < 2; ++nf)
#pragma unroll
        for (int r = 0; r < 4; ++r) {
          const int i = 32 * w + mf * 16 + 4 * g + r;
          if (i < 196) {
            const int c = nf * 16 + li;
            const int ih = (i * 2341) >> 15, iw = i - ih * 14;
            const int jh = ih + 13 - c;
            if ((unsigned)jh < 14u) dhwT[jh * 268 + i] = f2bf(dacc[mf][nf][r]);
            const int jw = iw + 13 - c;
            if ((unsigned)jw < 14u) dhwT[(14 + jw) * 268 + i] = f2bf(eacc[mf][nf][r]);
          }
        }
  }
  __syncthreads();

  f32x4 oacc[2][4];
  const f32x4 vz = {0.f, 0.f, 0.f, 0.f};
#pragma unroll
  for (int a = 0; a < 2; ++a)
#pragma unroll
    for (int b = 0; b < 4; ++b) oacc[a][b] = vz;
  float mrun[8], lrun[8];
#pragma unroll
  for (int a = 0; a < 8; ++a) { mrun[a] = -1e30f; lrun[a] = 0.f; }

  u16* Pw = Pb + w * 1024;
  const int jv = t & 63;
  const int dv = w * 8;

  for (int jt = 0; jt < 4; ++jt) {
    const int j0 = jt * 64;
    const int njf = (jt < 3) ? 4 : 1;
    const int nhalf = (jt < 3) ? 2 : 1;

    {
      const int rbase = w * 8;
      const int row = rbase + (lane >> 3);
      const int jg = min(j0 + row, NTOK - 1);
      const int cbs = (lane & 7) ^ (row & 7);
      cp16(Kb + (size_t)jg * 64 + cbs * 8, &Kt[rbase * 64]);
    }
    __builtin_amdgcn_sched_barrier(0);
    const int jgv = min(j0 + jv, NTOK - 1);
    v8u vg = *(const v8u*)(Vb + (size_t)jgv * 64 + dv);
    __builtin_amdgcn_sched_barrier(0);
    asm volatile("s_waitcnt vmcnt(1)" ::: "memory");
    __builtin_amdgcn_sched_barrier(0);
    __builtin_amdgcn_s_barrier();
    __builtin_amdgcn_sched_barrier(0);

    f32x4 sacc[2][4];
#pragma unroll
    for (int a = 0; a < 2; ++a)
#pragma unroll
      for (int b = 0; b < 4; ++b) sacc[a][b] = vz;
    if (nmf > 0) {
#pragma unroll
      for (int ks = 0; ks < 2; ++ks) {
#pragma unroll
        for (int jf = 0; jf < 4; ++jf) if (jf < njf) {
          const int row = jf * 16 + li;
          v8bf kb = *(const v8bf*)&Kt[row * 64 + (((ks * 4 + g) ^ (li & 7)) * 8)];
#pragma unroll
          for (int mf = 0; mf < 2; ++mf) if (mf < nmf)
            sacc[mf][jf] = __builtin_amdgcn_mfma_f32_16x16x32_bf16(qf[mf][ks], kb, sacc[mf][jf], 0, 0, 0);
        }
      }
    }

    asm volatile("s_waitcnt vmcnt(0)" ::: "memory");
    __builtin_amdgcn_sched_barrier(0);
#pragma unroll
    for (int e = 0; e < 8; ++e) {
      const int da = dv + e;
      Vt[da * 64 + (((jv >> 3) ^ (da & 7)) * 8) + (jv & 7)] = vg[e];
    }

#pragma unroll
    for (int jf = 0; jf < 4; ++jf) if (jf < njf) {
      const int j = j0 + jf * 16 + li;
      const bool jok = j < 196;
      int jh = (j * 2341) >> 15;
      const int jw = j - jh * 14;
      if (jh > 13) jh = 13;
#pragma unroll
      for (int mf = 0; mf < 2; ++mf) if (mf < nmf) {
        const int i0 = 32 * w + mf * 16 + 4 * g;
        v4u hv = *(const v4u*)&dhwT[jh * 268 + i0];
        v4u wv = *(const v4u*)&dhwT[(14 + jw) * 268 + i0];
#pragma unroll
        for (int r = 0; r < 4; ++r) {
          float v;
          if (jok && (i0 + r) < 196)
            v = sacc[mf][jf][r] * 0.125f + bf2f(hv[r]) + bf2f(wv[r]);
          else v = -1e30f;
          sacc[mf][jf][r] = v;
        }
      }
    }

#pragma unroll
    for (int mf = 0; mf < 2; ++mf) if (mf < nmf)
#pragma unroll
      for (int r = 0; r < 4; ++r) {
        float tmx = -1e30f;
#pragma unroll
        for (int jf = 0; jf < 4; ++jf) if (jf < njf) tmx = fmaxf(tmx, sacc[mf][jf][r]);
#pragma unroll
        for (int o = 1; o < 16; o <<= 1) tmx = fmaxf(tmx, __shfl_xor(tmx, o, 16));
        const int idx = mf * 4 + r;
        const float mnew = fmaxf(mrun[idx], tmx);
        const float sf = __expf(mrun[idx] - mnew);
        mrun[idx] = mnew;
        float ls = 0.f;
#pragma unroll
        for (int jf = 0; jf < 4; ++jf) if (jf < njf) {
          const float p = __expf(sacc[mf][jf][r] - mnew);
          sacc[mf][jf][r] = p;
          ls += p;
        }
#pragma unroll
        for (int o = 1; o < 16; o <<= 1) ls += __shfl_xor(ls, o, 16);
        lrun[idx] = lrun[idx] * sf + ls;
#pragma unroll
        for (int nf = 0; nf < 4; ++nf) oacc[mf][nf][r] *= sf;
      }

#pragma unroll
    for (int half = 0; half < 2; ++half) if (half < nhalf) {
#pragma unroll
      for (int c = 0; c < 2; ++c) {
        const int jf = half * 2 + c;
        const int jloc = c * 16 + li;
#pragma unroll
        for (int mf = 0; mf < 2; ++mf)
#pragma unroll
          for (int r = 0; r < 4; ++r) {
            const int il = mf * 16 + 4 * g + r;
            u16 pv = 0;
            if (mf < nmf && jf < njf) pv = f2bf(sacc[mf][jf][r]);
            Pw[il * 32 + (jloc ^ (g << 3))] = pv;
          }
      }
      if (half == 0) __syncthreads();
      if (nmf > 0) {
        v8bf pa[2];
#pragma unroll
        for (int mf = 0; mf < 2; ++mf) {
          const int row = mf * 16 + li;
          pa[mf] = *(const v8bf*)&Pw[row * 32 + ((g ^ ((li >> 2) & 3)) * 8)];
        }
#pragma unroll
        for (int nf = 0; nf < 4; ++nf) {
          const int d = nf * 16 + li;
          v8bf vb = *(const v8bf*)&Vt[d * 64 + (((half * 4 + g) ^ (li & 7)) * 8)];
#pragma unroll
          for (int mf = 0; mf < 2; ++mf)
            oacc[mf][nf] = __builtin_amdgcn_mfma_f32_16x16x32_bf16(pa[mf], vb, oacc[mf][nf], 0, 0, 0);
        }
      }
    }
    __syncthreads();
  }

  if (nmf > 0) {
    float rinv[8];
#pragma unroll
    for (int a = 0; a < 8; ++a) rinv[a] = 1.0f / lrun[a];
#pragma unroll
    for (int half = 0; half < 2; ++half) {
#pragma unroll
      for (int c = 0; c < 2; ++c) {
        const int nf = half * 2 + c;
        const int dloc = c * 16 + li;
#pragma unroll
        for (int mf = 0; mf < 2; ++mf)
#pragma unroll
          for (int r = 0; r < 4; ++r) {
            const int il = mf * 16 + 4 * g + r;
            float val = (mf < nmf) ? oacc[mf][nf][r] * rinv[mf * 4 + r] : 0.f;
            Pw[il * 32 + (dloc ^ (g << 3))] = f2bf(val);
          }
      }
#pragma unroll
      for (int p = 0; p < 2; ++p) {
        const int row = p * 16 + (lane >> 2);
        const int seg = lane & 3;
        const int i = 32 * w + row;
        if (i < 196) {
          const int segp = seg ^ ((row >> 2) & 3);
          v8u val = *(const v8u*)&Pw[row * 32 + segp * 8];
          *(v8u*)(out + (size_t)(win * NTOK + i) * DIMC + h * 64 + half * 32 + seg * 8) = val;
        }
      }
    }
  }
}

extern "C" void kernel_launch(void* const* d_in, const int* in_sizes, int n_in,
                              void* d_out, int out_size, void* d_ws, size_t ws_size,
                              hipStream_t stream) {
  (void)in_sizes; (void)n_in; (void)out_size; (void)ws_size;
  const float* x0     = (const float*)d_in[0];
  const float* an1_w  = (const float*)d_in[1];
  const float* an1_b  = (const float*)d_in[2];
  const float* ad1_W  = (const float*)d_in[3];
  const float* ad1_b  = (const float*)d_in[4];
  const float* ac1_W  = (const float*)d_in[5];
  const float* ac1_b  = (const float*)d_in[6];
  const float* au1_W  = (const float*)d_in[7];
  const float* au1_b  = (const float*)d_in[8];
  const float* an2_w  = (const float*)d_in[9];
  const float* an2_b  = (const float*)d_in[10];
  const float* ad2_W  = (const float*)d_in[11];
  const float* ad2_b  = (const float*)d_in[12];
  const float* ac2_W  = (const float*)d_in[13];
  const float* ac2_b  = (const float*)d_in[14];
  const float* au2_W  = (const float*)d_in[15];
  const float* au2_b  = (const float*)d_in[16];
  const float* n1_w   = (const float*)d_in[17];
  const float* n1_b   = (const float*)d_in[18];
  const float* qkv_W  = (const float*)d_in[19];
  const float* qkv_b  = (const float*)d_in[20];
  const float* facu_W = (const float*)d_in[21];
  const float* facv_W = (const float*)d_in[22];
  const float* qfac_W = (const float*)d_in[23];
  const float* vfac_W = (const float*)d_in[24];
  const float* rel_h  = (const float*)d_in[25];
  const float* rel_w  = (const float*)d_in[26];
  const float* proj_W = (const float*)d_in[27];
  const float* proj_b = (const float*)d_in[28];
  const float* n2_w   = (const float*)d_in[29];
  const float* n2_b   = (const float*)d_in[30];
  const float* mlp_W1 = (const float*)d_in[31];
  const float* mlp_b1 = (const float*)d_in[32];
  const float* mlp_W2 = (const float*)d_in[33];
  const float* mlp_b2 = (const float*)d_in[34];

  char* ws = (char*)d_ws;
  size_t off = 0;
  auto alloc = [&](size_t bytes) -> void* {
    void* p = (void*)(ws + off);
    off += (bytes + 255) & ~(size_t)255;
    return p;
  };
  u16*  bufA  = (u16*)alloc((size_t)MS * 3072 * 2);      // qkvR bf16 / mlp hidden bf16
  u16*  bufB  = (u16*)alloc((size_t)MWP * DIMC * 2);     // LN/window tokens + attn out, bf16
  float* bufX = (float*)alloc((size_t)MS * DIMC * 4);    // residual stream f32
  u16*  bufD  = (u16*)alloc((size_t)MS * ACCH * 2);      // adapter down out
  u16*  bufE  = (u16*)alloc((size_t)MS * ACCH * 2);      // adapter conv+gelu out
  u16*  Wcomb = (u16*)alloc((size_t)2304 * 768 * 2);
  u16*  Wproj = (u16*)alloc((size_t)768 * 768 * 2);
  u16*  Wm1   = (u16*)alloc((size_t)3072 * 768 * 2);
  u16*  Wm2   = (u16*)alloc((size_t)768 * 3072 * 2);
  u16*  Wad1  = (u16*)alloc((size_t)256 * 768 * 2);
  u16*  Wau1  = (u16*)alloc((size_t)768 * 192 * 2);
  u16*  Wcv1  = (u16*)alloc((size_t)256 * 5184 * 2);
  u16*  Wad2  = (u16*)alloc((size_t)256 * 768 * 2);
  u16*  Wau2  = (u16*)alloc((size_t)768 * 192 * 2);
  u16*  Wcv2  = (u16*)alloc((size_t)256 * 5184 * 2);
  float* Uq   = (float*)alloc(768 * 32 * 4);
  float* Uv   = (float*)alloc(768 * 32 * 4);
  u16*  zrow  = (u16*)alloc(256);

  // ---- weight prep (every launch; deterministic) ----
  k_zero16<<<1, 256, 0, stream>>>(zrow, 128);
  k_compute_U<<<192, 256, 0, stream>>>(facu_W, qfac_W, vfac_W, Uq, Uv);
  k_build_wcomb<<<(2304 * 768 + 255) / 256, 256, 0, stream>>>(qkv_W, Uq, Uv, facv_W, Wcomb);
  k_cast_pad<<<(768 * 768 / 4 + 255) / 256, 256, 0, stream>>>(proj_W, Wproj, 768, 768, 768);
  k_cast_pad<<<(3072 * 768 / 4 + 255) / 256, 256, 0, stream>>>(mlp_W1, Wm1, 3072, 768, 3072);
  k_cast_pad<<<(768 * 3072 / 4 + 255) / 256, 256, 0, stream>>>(mlp_W2, Wm2, 768, 3072, 768);
  k_cast_pad<<<(256 * 768 / 4 + 255) / 256, 256, 0, stream>>>(ad1_W, Wad1, 192, 768, 256);
  k_cast_pad<<<(768 * 192 / 4 + 255) / 256, 256, 0, stream>>>(au1_W, Wau1, 768, 192, 768);
  k_cast_pad<<<(256 * 768 / 4 + 255) / 256, 256, 0, stream>>>(ad2_W, Wad2, 192, 768, 256);
  k_cast_pad<<<(768 * 192 / 4 + 255) / 256, 256, 0, stream>>>(au2_W, Wau2, 768, 192, 768);
  k_conv_repack<<<(256 * 5184 / 4 + 255) / 256, 256, 0, stream>>>(ac1_W, Wcv1);
  k_conv_repack<<<(256 * 5184 / 4 + 255) / 256, 256, 0, stream>>>(ac2_W, Wcv2);

  // ---- adapter 1: x1 = x0 + up(gelu(conv(down(LN(x0))))) ----
  ln_k<false><<<MS, 256, 0, stream>>>(x0, an1_w, an1_b, bufB);
  gemm_bt<1, false><<<dim3(2, 160), 256, 0, stream>>>(bufB, Wad1, ad1_b, nullptr, nullptr, bufD, MS, 192, 768, nullptr, 2);
  gemm_bt<2, true><<<dim3(2, 160), 256, 0, stream>>>(bufD, Wcv1, ac1_b, nullptr, nullptr, bufE, MS, 192, 5184, zrow, 2);
  gemm_wide<3><<<480, 256, 0, stream>>>(bufE, Wau1, au1_b, x0, bufX, nullptr, MS, 768, 192, 3);

  // ---- windowed attention ----
  ln_k<true><<<MWP, 256, 0, stream>>>(bufX, n1_w, n1_b, bufB);
  gemm_wide<4><<<1728, 256, 0, stream>>>(bufB, Wcomb, qkv_b, nullptr, nullptr, bufA, MW, 2304, 768, 3);
  attn_k<<<125 * HEADS, 512, 0, stream>>>(bufA, rel_h, rel_w, bufB);
  gemm_wide<5><<<576, 256, 0, stream>>>(bufB, Wproj, proj_b, bufX, bufX, nullptr, MW, 768, 768, 3);

  // ---- adapter 2 ----
  ln_k<false><<<MS, 256, 0, stream>>>(bufX, an2_w, an2_b, bufB);
  gemm_bt<1, false><<<dim3(2, 160), 256, 0, stream>>>(bufB, Wad2, ad2_b, nullptr, nullptr, bufD, MS, 192, 768, nullptr, 2);
  gemm_bt<2, true><<<dim3(2, 160), 256, 0, stream>>>(bufD, Wcv2, ac2_b, nullptr, nullptr, bufE, MS, 192, 5184, zrow, 2);
  gemm_wide<3><<<480, 256, 0, stream>>>(bufE, Wau2, au2_b, bufX, bufX, nullptr, MS, 768, 192, 3);

  // ---- MLP ----
  ln_k<false><<<MS, 256, 0, stream>>>(bufX, n2_w, n2_b, bufB);
  gemm_wide<2><<<1920, 256, 0, stream>>>(bufB, Wm1, mlp_b1, nullptr, nullptr, bufA, MS, 3072, 768, 4);
  gemm_wide<3><<<480, 256, 0, stream>>>(bufA, Wm2, mlp_b2, bufX, (float*)d_out, nullptr, MS, 768, 3072, 3);
}

// Round 15
// 1127.994 us; speedup vs baseline: 1.1918x; 1.1918x over previous
//
#include <hip/hip_runtime.h>

typedef unsigned short u16;
typedef __bf16 v8bf __attribute__((ext_vector_type(8)));
typedef unsigned short v8u __attribute__((ext_vector_type(8)));
typedef unsigned short v4u __attribute__((ext_vector_type(4)));
typedef float f32x4 __attribute__((ext_vector_type(4)));
typedef float v8f __attribute__((ext_vector_type(8)));

static constexpr int DIMC = 768;
static constexpr int HEADS = 12;
static constexpr int WINS  = 14;
static constexpr int ACCH  = 192;   // adapter channels
static constexpr int NTOK  = 196;   // 14*14
static constexpr int MW    = 24500; // 125 windows * 196 tokens
static constexpr int MWP   = 24576; // padded to tile multiple
static constexpr int MS    = 20480; // 5*64*64 spatial tokens

__device__ __forceinline__ float bf2f(u16 u) {
  union { unsigned int i; float f; } x; x.i = ((unsigned int)u) << 16; return x.f;
}
__device__ __forceinline__ u16 f2bf(float f) {
  union { float f; unsigned int i; } x; x.f = f;
  unsigned int r = x.i + 0x7fffu + ((x.i >> 16) & 1u);
  return (u16)(r >> 16);
}
// fast tanh-form GELU: max abs err ~2e-3 (well under threshold)
__device__ __forceinline__ float gelu_f(float x) {
  float y = 0.79788456080286536f * (x + 0.044715f * x * x * x);
  y = fminf(fmaxf(y, -15.f), 15.f);
  const float e = __expf(2.f * y);
  const float th = 1.f - 2.f * __builtin_amdgcn_rcpf(e + 1.f);
  return 0.5f * x * (1.f + th);
}
// async global->LDS, 16B per lane. LDS dest is wave-uniform base + lane*16.
__device__ __forceinline__ void cp16(const u16* g, u16* l) {
  __builtin_amdgcn_global_load_lds(
      (const __attribute__((address_space(1))) unsigned int*)(const void*)g,
      (__attribute__((address_space(3))) unsigned int*)(void*)l, 16, 0, 0);
}

// ---------------- weight prep ----------------
__global__ void k_zero16(u16* p, int n) {
  int i = blockIdx.x * 256 + threadIdx.x;
  if (i < n) p[i] = 0;
}
// U[k][b] = sum_a facu_W[a][k] * fac_W[b][a]   (fac = qfac or vfac)
__global__ void k_compute_U(const float* __restrict__ facu, const float* __restrict__ qfac,
                            const float* __restrict__ vfac, float* __restrict__ Uq,
                            float* __restrict__ Uv) {
  int idx = blockIdx.x * 256 + threadIdx.x;
  if (idx >= 2 * 768 * 32) return;
  const int which = idx / (768 * 32);
  const int rem = idx - which * 768 * 32;
  const int k = rem >> 5, b = rem & 31;
  const float* fac = which ? vfac : qfac;
  float s = 0.f;
  for (int a = 0; a < 32; ++a) s += facu[a * 768 + k] * fac[b * 32 + a];
  (which ? Uv : Uq)[rem] = s;
}
// Wc[n][k] = qkv_W[n][k] (+ sum_b U{q,v}[k][b]*facv_W[n'][b] for q/v blocks), cast bf16
__global__ void k_build_wcomb(const float* __restrict__ qkvW, const float* __restrict__ Uq,
                              const float* __restrict__ Uv, const float* __restrict__ facv,
                              u16* __restrict__ Wc) {
  int idx = blockIdx.x * 256 + threadIdx.x;
  if (idx >= 2304 * 768) return;
  const int n = idx / 768, k = idx - n * 768;
  float v = qkvW[idx];
  if (n < 768) {
    float s = 0.f;
    for (int b = 0; b < 32; ++b) s += Uq[k * 32 + b] * facv[n * 32 + b];
    v += s;
  } else if (n >= 1536) {
    const int nn = n - 1536;
    float s = 0.f;
    for (int b = 0; b < 32; ++b) s += Uv[k * 32 + b] * facv[nn * 32 + b];
    v += s;
  }
  Wc[idx] = f2bf(v);
}
// vectorized cast+pad: 4 elems/thread (cols % 4 == 0 so a group shares its row)
__global__ void k_cast_pad(const float* __restrict__ src, u16* __restrict__ dst,
                           int rows, int cols, int rowsPad) {
  int idx = blockIdx.x * 256 + threadIdx.x;
  const int base = idx * 4;
  if (base >= rowsPad * cols) return;
  const int r = base / cols;
  v4u o;
  if (r < rows) {
    const float4 v = *(const float4*)(src + base);
    o[0] = f2bf(v.x); o[1] = f2bf(v.y); o[2] = f2bf(v.z); o[3] = f2bf(v.w);
  } else {
    o[0] = o[1] = o[2] = o[3] = 0;
  }
  *(v4u*)(dst + base) = o;
}
// ac_W [192][192][3][3][3] -> Wconv [256 pad][27*192] with k = tap*192+ci  (4 ci/thread)
__global__ void k_conv_repack(const float* __restrict__ src, u16* __restrict__ dst) {
  int idx = blockIdx.x * 256 + threadIdx.x;
  const int base = idx * 4;
  if (base >= 256 * 5184) return;
  const int co = base / 5184;
  const int rem = base - co * 5184;
  const int tap = rem / 192, ci = rem - tap * 192;   // ci % 4 == 0 (192 % 4 == 0)
  v4u o;
  if (co < 192) {
    const float* sp = src + co * 5184 + ci * 27 + tap;
#pragma unroll
    for (int e = 0; e < 4; ++e) o[e] = f2bf(sp[e * 27]);
  } else {
    o[0] = o[1] = o[2] = o[3] = 0;
  }
  *(v4u*)(dst + base) = o;
}

// ---------------- LayerNorm (optionally fused window-partition) ----------------
template<bool WINDOWED>
__global__ __launch_bounds__(256)
void ln_k(const float* __restrict__ X, const float* __restrict__ w,
          const float* __restrict__ b, u16* __restrict__ out) {
  const int r = (int)blockIdx.x;
  const int t = (int)threadIdx.x;
  int src = r;
  bool zero = false;
  if (WINDOWED) {
    if (r >= MW) zero = true;
    else {
      const int win = r / NTOK, tk = r - win * NTOK;
      const int img = win / 25, wrem = win - img * 25, wy = wrem / 5, wx = wrem - wy * 5;
      const int ty = tk / WINS, tx = tk - ty * WINS;
      const int y = wy * WINS + ty, x = wx * WINS + tx;
      if (y >= 64 || x >= 64) zero = true;
      else src = (img << 12) + (y << 6) + x;
    }
  }
  u16* orow = out + (size_t)r * DIMC;
  if (zero) {
    for (int c = t; c < DIMC; c += 256) orow[c] = 0;
    return;
  }
  const float* xr = X + (size_t)src * DIMC;
  const float v0 = xr[t], v1 = xr[t + 256], v2 = xr[t + 512];
  float s = v0 + v1 + v2, ss = v0 * v0 + v1 * v1 + v2 * v2;
#pragma unroll
  for (int o = 32; o > 0; o >>= 1) { s += __shfl_xor(s, o, 64); ss += __shfl_xor(ss, o, 64); }
  __shared__ float red[8];
  const int wave = t >> 6, lane = t & 63;
  if (lane == 0) { red[wave] = s; red[4 + wave] = ss; }
  __syncthreads();
  s = red[0] + red[1] + red[2] + red[3];
  ss = red[4] + red[5] + red[6] + red[7];
  const float mean = s * (1.0f / 768.0f);
  const float var = ss * (1.0f / 768.0f) - mean * mean;
  const float rstd = rsqrtf(var + 1e-5f);
  orow[t]       = f2bf((v0 - mean) * rstd * w[t]       + b[t]);
  orow[t + 256] = f2bf((v1 - mean) * rstd * w[t + 256] + b[t + 256]);
  orow[t + 512] = f2bf((v2 - mean) * rstd * w[t + 512] + b[t + 512]);
}

// ---------------- GEMM: C[M,N] = A[M,K] @ B[N,K]^T (+bias, epilogues) ----------------
// EPI: 1 = bf16 out (bias); 2 = bf16 out (bias+GELU); 3 = f32 out (bias+residual);
//      4 = bf16 qkv-scatter per (win,head); 5 = f32 window-unpartition + in-place resid add
// CONV: A rows gathered as 3x3x3 SAME conv over [5][64][64][192]; K = tap*192+ci
// Block swizzle: XCD-chunked + bn-grouping GN (round 11). Epilogue: LDS-staged (round 12).
template<int EPI, bool CONV>
__global__ __launch_bounds__(256)
void gemm_bt(const u16* __restrict__ A, const u16* __restrict__ B,
             const float* __restrict__ bias, const float* __restrict__ resid,
             float* __restrict__ outF, u16* __restrict__ outB,
             int M, int N, int K, const u16* __restrict__ zrow, int GN) {
  __shared__ u16 smem[2 * 128 * 64];
  u16* At = smem;
  u16* Bt = smem + 128 * 64;
  const int gx = (int)gridDim.x;
  const int nwg = gx * (int)gridDim.y;
  const int lin = (int)blockIdx.y * gx + (int)blockIdx.x;
  const int csz = nwg >> 3;            // blocks per XCD chunk
  const int xcd = lin & 7;
  const int c = lin >> 3;              // position within chunk
  const int bmc = csz / gx;            // bm rows per chunk
  const int gsz = bmc * GN;
  const int grp = c / gsz, rr = c - grp * gsz;
  const int bn = grp * GN + (rr % GN);
  const int bm = xcd * bmc + (rr / GN);
  const int t = (int)threadIdx.x;
  const int wave = t >> 6, lane = t & 63;
  const int wm = wave >> 1, wn = wave & 1;
  const int lrow = lane >> 3;                // 0..7 (row within 8-row group)
  const int c16s = (lane & 7) ^ lrow;        // pre-swizzled source col16
  const int li = lane & 15, lq = lane >> 4;

  f32x4 acc[4][4];
  const f32x4 vzero = {0.f, 0.f, 0.f, 0.f};
#pragma unroll
  for (int a = 0; a < 4; ++a)
#pragma unroll
    for (int b = 0; b < 4; ++b) acc[a][b] = vzero;

  const int nk = K >> 6;
  for (int kt = 0; kt < nk; ++kt) {
    int cD = 0, cY = 0, cX = 0, cblk = 0;
    if (CONV) {
      const int tap = kt / 3;
      cblk = (kt - tap * 3) << 6;
      const int kd = tap / 9, r9 = tap - kd * 9, ky = r9 / 3;
      cD = kd - 1; cY = ky - 1; cX = (r9 - ky * 3) - 1;
    }
#pragma unroll
    for (int i = 0; i < 4; ++i) {           // stage A: 128x64 bf16
      const int r0 = i * 32 + wave * 8;
      const int grow = bm * 128 + r0 + lrow;
      const u16* src;
      if (CONV) {
        const int d = (grow >> 12) + cD, y = ((grow >> 6) & 63) + cY, x = (grow & 63) + cX;
        if ((unsigned)d < 5u && (unsigned)y < 64u && (unsigned)x < 64u)
          src = A + (size_t)((d << 12) + (y << 6) + x) * ACCH + cblk + c16s * 8;
        else
          src = zrow + c16s * 8;
      } else {
        src = A + (size_t)grow * K + (kt << 6) + c16s * 8;
      }
      cp16(src, &At[r0 * 64]);
    }
#pragma unroll
    for (int i = 0; i < 4; ++i) {           // stage B: 128x64 bf16
      const int r0 = i * 32 + wave * 8;
      const int grow = bn * 128 + r0 + lrow;
      cp16(B + (size_t)grow * K + (kt << 6) + c16s * 8, &Bt[r0 * 64]);
    }
    __syncthreads();                         // drains vmcnt for global_load_lds
#pragma unroll
    for (int kk = 0; kk < 2; ++kk) {
      v8bf af[4], bg[4];
#pragma unroll
      for (int mf = 0; mf < 4; ++mf) {
        const int row = wm * 64 + mf * 16 + li;
        const int c16 = (kk * 4 + lq) ^ (li & 7);
        af[mf] = *(const v8bf*)&At[row * 64 + c16 * 8];
      }
#pragma unroll
      for (int nf = 0; nf < 4; ++nf) {
        const int row = wn * 64 + nf * 16 + li;
        const int c16 = (kk * 4 + lq) ^ (li & 7);
        bg[nf] = *(const v8bf*)&Bt[row * 64 + c16 * 8];
      }
#pragma unroll
      for (int mf = 0; mf < 4; ++mf)
#pragma unroll
        for (int nf = 0; nf < 4; ++nf)
          acc[mf][nf] = __builtin_amdgcn_mfma_f32_16x16x32_bf16(af[mf], bg[nf], acc[mf][nf], 0, 0, 0);
    }
    __syncthreads();
  }

  // ---- epilogue: stage C through LDS, vectorized stores ----
  if (EPI == 1 || EPI == 2 || EPI == 4) {
    u16* Ct = smem;  // [128][128] bf16, col ^ ((row&7)<<3)
#pragma unroll
    for (int mf = 0; mf < 4; ++mf)
#pragma unroll
      for (int nf = 0; nf < 4; ++nf)
#pragma unroll
        for (int r = 0; r < 4; ++r) {
          const int row = wm * 64 + mf * 16 + lq * 4 + r;
          const int col = wn * 64 + nf * 16 + li;
          float v = acc[mf][nf][r] + bias[bn * 128 + col];
          if (EPI == 2) v = gelu_f(v);
          Ct[row * 128 + (col ^ ((row & 7) << 3))] = f2bf(v);
        }
    __syncthreads();
#pragma unroll
    for (int it = 0; it < 8; ++it) {
      const int row = it * 16 + (t >> 4);
      const int seg = t & 15;
      const int gr = bm * 128 + row;
      const int col8 = bn * 128 + seg * 8;
      if (gr < M && col8 < N) {
        v8u val = *(const v8u*)&Ct[row * 128 + ((seg ^ (row & 7)) * 8)];
        if (EPI == 4) {
          const int sec = col8 / 768;
          const int hm = col8 - sec * 768;
          const int hd = hm >> 6, dd = hm & 63;
          const int win = gr / 196, tk = gr - win * 196;
          *(v8u*)(outB + (size_t)(((win * HEADS + hd) * 3 + sec) * NTOK + tk) * 64 + dd) = val;
        } else {
          *(v8u*)(outB + (size_t)gr * N + col8) = val;
        }
      }
    }
  } else {  // EPI 3 / 5: f32, two wm-halves through [64][128] f32 tile
    float* Cf = (float*)smem;
#pragma unroll
    for (int h2 = 0; h2 < 2; ++h2) {
      if (h2) __syncthreads();               // half-0 reads done before overwrite
      if (wm == h2) {
#pragma unroll
        for (int mf = 0; mf < 4; ++mf)
#pragma unroll
          for (int nf = 0; nf < 4; ++nf)
#pragma unroll
            for (int r = 0; r < 4; ++r) {
              const int row = mf * 16 + lq * 4 + r;      // 0..63 within half
              const int col = wn * 64 + nf * 16 + li;
              const float v = acc[mf][nf][r] + bias[bn * 128 + col];
              Cf[row * 128 + (col ^ (((row >> 2) & 3) << 3))] = v;
            }
      }
      __syncthreads();
#pragma unroll
      for (int it = 0; it < 4; ++it) {
        const int row = it * 16 + (t >> 4);              // 0..63
        const int seg = t & 15;
        const int gr = bm * 128 + h2 * 64 + row;
        const int col8 = bn * 128 + seg * 8;
        if (gr < M && col8 < N) {
          v8f val = *(const v8f*)&Cf[row * 128 + ((seg ^ ((row >> 2) & 3)) * 8)];
          if (EPI == 3) {
            const float* rp = resid + (size_t)gr * N + col8;
#pragma unroll
            for (int e = 0; e < 8; ++e) val[e] += rp[e];
            *(v8f*)(outF + (size_t)gr * N + col8) = val;
          } else {  // EPI 5: window-unpartition + in-place residual add
            const int win = gr / 196, tk = gr - win * 196;
            const int img = win / 25, wrem = win - img * 25, wy = wrem / 5, wx = wrem - wy * 5;
            const int ty = tk / WINS, tx = tk - ty * WINS;
            const int y = wy * WINS + ty, x = wx * WINS + tx;
            if (y < 64 && x < 64) {
              const size_t o = (size_t)((img << 12) + (y << 6) + x) * DIMC + col8;
              const float* rp = resid + o;
#pragma unroll
              for (int e = 0; e < 8; ++e) val[e] += rp[e];
              *(v8f*)(outF + o) = val;
            }
          }
        }
      }
    }
  }
}

// ---------------- fused windowed attention, MFMA flash-style, 8 waves ----------------
// block = (win, head), 512 threads; wave w owns q-rows [32w, 32w+32).
// Q held in REGISTERS (qf[2][2], one-time global loads) -> LDS 47 KB.
// qkvR layout per (win,head): [Q(196x64) | K(196x64) | V(196x64)]
__global__ __launch_bounds__(512, 2)
void attn_k(const u16* __restrict__ qkvR, const float* __restrict__ relh,
            const float* __restrict__ relw, u16* __restrict__ out) {
  const int blk = (int)blockIdx.x;
  const int win = blk / HEADS, h = blk - win * HEADS;
  const int t = (int)threadIdx.x, w = t >> 6, lane = t & 63;
  const int li = lane & 15, g = lane >> 4;
  const int nmf = (w < 6) ? 2 : (w == 6 ? 1 : 0);   // valid 16-row fragments this wave

  __shared__ u16 Kt[64 * 64];     // 8 KB [j][d], swizzled (cp16 linear dest)
  __shared__ u16 Vt[64 * 64];     // 8 KB [d][j], seg-XOR swizzled
  __shared__ u16 Pb[8 * 32 * 32]; // 16 KB per-wave P/O chunks; aliases rel buf in phase A
  __shared__ u16 dhwT[28 * 268];  // 15 KB: rows 0..13 = dh[jh][i], 14..27 = dw[jw][i]

  const u16* Qb = qkvR + (size_t)(win * HEADS + h) * 3 * NTOK * 64;
  const u16* Kb = Qb + NTOK * 64;
  const u16* Vb = Kb + NTOK * 64;

  // ---- Q fragments in registers: qf[mf][ks], rows clamped to 195 ----
  v8bf qf[2][2];
#pragma unroll
  for (int mf = 0; mf < 2; ++mf) {
    const int row = min(32 * w + mf * 16 + li, NTOK - 1);
#pragma unroll
    for (int ks = 0; ks < 2; ++ks)
      qf[mf][ks] = *(const v8bf*)(Qb + (size_t)row * 64 + ks * 32 + g * 8);
  }

  // ---- stage rel tables into Pb (phase-A alias) ----
  u16* relb = Pb; // [2][32 rows][64 cols], swizzled like Kt
  for (int idx = t; idx < 2 * 32 * 64; idx += 512) {
    const int which = idx >> 11, rem = idx & 2047, r = rem >> 6, c = rem & 63;
    const float v = (r < 27) ? (which ? relw[r * 64 + c] : relh[r * 64 + c]) : 0.f;
    relb[which * 2048 + r * 64 + (((c >> 3) ^ (r & 7)) * 8) + (c & 7)] = f2bf(v);
  }
  __syncthreads();

  // ---- phase A: rel-pos tables via MFMA (Q from registers), scatter into dhwT ----
  {
    f32x4 dacc[2][2], eacc[2][2];
    const f32x4 vz = {0.f, 0.f, 0.f, 0.f};
#pragma unroll
    for (int mf = 0; mf < 2; ++mf)
#pragma unroll
      for (int nf = 0; nf < 2; ++nf) { dacc[mf][nf] = vz; eacc[mf][nf] = vz; }
#pragma unroll
    for (int ks = 0; ks < 2; ++ks) {
#pragma unroll
      for (int nf = 0; nf < 2; ++nf) {
        const int row = nf * 16 + li;
        const int off = row * 64 + (((ks * 4 + g) ^ (li & 7)) * 8);
        v8bf bh = *(const v8bf*)&relb[off];
        v8bf bw = *(const v8bf*)&relb[2048 + off];
#pragma unroll
        for (int mf = 0; mf < 2; ++mf) if (mf < nmf) {
          dacc[mf][nf] = __builtin_amdgcn_mfma_f32_16x16x32_bf16(qf[mf][ks], bh, dacc[mf][nf], 0, 0, 0);
          eacc[mf][nf] = __builtin_amdgcn_mfma_f32_16x16x32_bf16(qf[mf][ks], bw, eacc[mf][nf], 0, 0, 0);
        }
      }
    }
    // scatter D,E -> dhwT[jh][i] / dhwT[14+jw][i] (bijective per row)
#pragma unroll
    for (int mf = 0; mf < 2; ++mf) if (mf < nmf)
#pragma unroll
      for (int nf = 0; nf < 2; ++nf)
#pragma unroll
        for (int r = 0; r < 4; ++r) {
          const int i = 32 * w + mf * 16 + 4 * g + r;
          if (i < 196) {
            const int c = nf * 16 + li;
            const int ih = (i * 2341) >> 15, iw = i - ih * 14;
            const int jh = ih + 13 - c;
            if ((unsigned)jh < 14u) dhwT[jh * 268 + i] = f2bf(dacc[mf][nf][r]);
            const int jw = iw + 13 - c;
            if ((unsigned)jw < 14u) dhwT[(14 + jw) * 268 + i] = f2bf(eacc[mf][nf][r]);
          }
        }
  }
  __syncthreads();   // phase-A reads of relb done; Pb free for P chunks

  // ---- phase B: flash over 4 j-tiles of 64 ----
  f32x4 oacc[2][4];
  const f32x4 vz = {0.f, 0.f, 0.f, 0.f};
#pragma unroll
  for (int a = 0; a < 2; ++a)
#pragma unroll
    for (int b = 0; b < 4; ++b) oacc[a][b] = vz;
  float mrun[8], lrun[8];
#pragma unroll
  for (int a = 0; a < 8; ++a) { mrun[a] = -1e30f; lrun[a] = 0.f; }

  u16* Pw = Pb + w * 1024; // own chunk [32 i][32 j]
  const int jv = t & 63;   // V-staging: column j
  const int dv = w * 8;    // V-staging: 8-d slab

  for (int jt = 0; jt < 4; ++jt) {
    const int j0 = jt * 64;
    const int njf = (jt < 3) ? 4 : 1;    // valid 16-col j-fragments
    const int nhalf = (jt < 3) ? 2 : 1;  // valid 32-col PV halves

    // stage K FIRST (oldest vm op): 8 waves x 8 rows = 64 rows, one cp16 each
    {
      const int rbase = w * 8;
      const int row = rbase + (lane >> 3);
      const int jg = min(j0 + row, NTOK - 1);
      const int cbs = (lane & 7) ^ (row & 7);
      cp16(Kb + (size_t)jg * 64 + cbs * 8, &Kt[rbase * 64]);
    }
    __builtin_amdgcn_sched_barrier(0);       // pin: K issued before V
    // V prefetch into regs (newest vm op; rides through the K wait)
    const int jgv = min(j0 + jv, NTOK - 1);
    v8u vg = *(const v8u*)(Vb + (size_t)jgv * 64 + dv);
    __builtin_amdgcn_sched_barrier(0);
    asm volatile("s_waitcnt vmcnt(1)" ::: "memory");   // K landed; V still in flight
    __builtin_amdgcn_sched_barrier(0);
    __builtin_amdgcn_s_barrier();            // Kt visible to all waves
    __builtin_amdgcn_sched_barrier(0);

    // QK^T (Q from registers) — V latency hides under this
    f32x4 sacc[2][4];
#pragma unroll
    for (int a = 0; a < 2; ++a)
#pragma unroll
      for (int b = 0; b < 4; ++b) sacc[a][b] = vz;
    if (nmf > 0) {
#pragma unroll
      for (int ks = 0; ks < 2; ++ks) {
#pragma unroll
        for (int jf = 0; jf < 4; ++jf) if (jf < njf) {
          const int row = jf * 16 + li;
          v8bf kb = *(const v8bf*)&Kt[row * 64 + (((ks * 4 + g) ^ (li & 7)) * 8)];
#pragma unroll
          for (int mf = 0; mf < 2; ++mf) if (mf < nmf)
            sacc[mf][jf] = __builtin_amdgcn_mfma_f32_16x16x32_bf16(qf[mf][ks], kb, sacc[mf][jf], 0, 0, 0);
        }
      }
    }

    // V regs -> Vt (seg-XOR swizzled); visible to all waves at the pre-PV barrier
    asm volatile("s_waitcnt vmcnt(0)" ::: "memory");
    __builtin_amdgcn_sched_barrier(0);
#pragma unroll
    for (int e = 0; e < 8; ++e) {
      const int da = dv + e;
      Vt[da * 64 + (((jv >> 3) ^ (da & 7)) * 8) + (jv & 7)] = vg[e];
    }

    // bias + mask (vectorized b64 reads from dhwT)
#pragma unroll
    for (int jf = 0; jf < 4; ++jf) if (jf < njf) {
      const int j = j0 + jf * 16 + li;
      const bool jok = j < 196;
      int jh = (j * 2341) >> 15;
      const int jw = j - jh * 14;
      if (jh > 13) jh = 13;                  // clamp for padded j (masked below)
#pragma unroll
      for (int mf = 0; mf < 2; ++mf) if (mf < nmf) {
        const int i0 = 32 * w + mf * 16 + 4 * g;
        v4u hv = *(const v4u*)&dhwT[jh * 268 + i0];
        v4u wv = *(const v4u*)&dhwT[(14 + jw) * 268 + i0];
#pragma unroll
        for (int r = 0; r < 4; ++r) {
          float v;
          if (jok && (i0 + r) < 196)
            v = sacc[mf][jf][r] * 0.125f + bf2f(hv[r]) + bf2f(wv[r]);
          else v = -1e30f;
          sacc[mf][jf][r] = v;
        }
      }
    }

    // online softmax update
#pragma unroll
    for (int mf = 0; mf < 2; ++mf) if (mf < nmf)
#pragma unroll
      for (int r = 0; r < 4; ++r) {
        float tmx = -1e30f;
#pragma unroll
        for (int jf = 0; jf < 4; ++jf) if (jf < njf) tmx = fmaxf(tmx, sacc[mf][jf][r]);
#pragma unroll
        for (int o = 1; o < 16; o <<= 1) tmx = fmaxf(tmx, __shfl_xor(tmx, o, 16));
        const int idx = mf * 4 + r;
        const float mnew = fmaxf(mrun[idx], tmx);
        const float sf = __expf(mrun[idx] - mnew);
        mrun[idx] = mnew;
        float ls = 0.f;
#pragma unroll
        for (int jf = 0; jf < 4; ++jf) if (jf < njf) {
          const float p = __expf(sacc[mf][jf][r] - mnew);
          sacc[mf][jf][r] = p;
          ls += p;
        }
#pragma unroll
        for (int o = 1; o < 16; o <<= 1) ls += __shfl_xor(ls, o, 16);
        lrun[idx] = lrun[idx] * sf + ls;
#pragma unroll
        for (int nf = 0; nf < 4; ++nf) oacc[mf][nf][r] *= sf;
      }

    // P chunks (32i x 32j per half) -> PV, two halves; own-wave lgkm ordering
#pragma unroll
    for (int half = 0; half < 2; ++half) if (half < nhalf) {
#pragma unroll
      for (int c = 0; c < 2; ++c) {
        const int jf = half * 2 + c;
        const int jloc = c * 16 + li;
#pragma unroll
        for (int mf = 0; mf < 2; ++mf)
#pragma unroll
          for (int r = 0; r < 4; ++r) {
            const int il = mf * 16 + 4 * g + r;
            u16 pv = 0;
            if (mf < nmf && jf < njf) pv = f2bf(sacc[mf][jf][r]);
            Pw[il * 32 + (jloc ^ (g << 3))] = pv;
          }
      }
      if (half == 0) __syncthreads();        // Vt (all waves) + own P visible before PV
      // PV: O[i][d] += P[i][j-half] * V[j-half][d]   (K = 32 -> one MFMA per (mf,nf))
      if (nmf > 0) {
        v8bf pa[2];
#pragma unroll
        for (int mf = 0; mf < 2; ++mf) {
          const int row = mf * 16 + li;
          pa[mf] = *(const v8bf*)&Pw[row * 32 + ((g ^ ((li >> 2) & 3)) * 8)];
        }
#pragma unroll
        for (int nf = 0; nf < 4; ++nf) {
          const int d = nf * 16 + li;
          v8bf vb = *(const v8bf*)&Vt[d * 64 + (((half * 4 + g) ^ (li & 7)) * 8)];
#pragma unroll
          for (int mf = 0; mf < 2; ++mf)
            oacc[mf][nf] = __builtin_amdgcn_mfma_f32_16x16x32_bf16(pa[mf], vb, oacc[mf][nf], 0, 0, 0);
        }
      }
    }
    __syncthreads();   // everyone done with Kt/Vt before next tile's staging
  }

  // ---- epilogue: per d-half, transpose through own chunk, 16B stores ----
  if (nmf > 0) {
    float rinv[8];
#pragma unroll
    for (int a = 0; a < 8; ++a) rinv[a] = 1.0f / lrun[a];
#pragma unroll
    for (int half = 0; half < 2; ++half) {
#pragma unroll
      for (int c = 0; c < 2; ++c) {
        const int nf = half * 2 + c;
        const int dloc = c * 16 + li;
#pragma unroll
        for (int mf = 0; mf < 2; ++mf)
#pragma unroll
          for (int r = 0; r < 4; ++r) {
            const int il = mf * 16 + 4 * g + r;
            float val = (mf < nmf) ? oacc[mf][nf][r] * rinv[mf * 4 + r] : 0.f;
            Pw[il * 32 + (dloc ^ (g << 3))] = f2bf(val);
          }
      }
#pragma unroll
      for (int p = 0; p < 2; ++p) {
        const int row = p * 16 + (lane >> 2);
        const int seg = lane & 3;
        const int i = 32 * w + row;
        if (i < 196) {
          const int segp = seg ^ ((row >> 2) & 3);
          v8u val = *(const v8u*)&Pw[row * 32 + segp * 8];
          *(v8u*)(out + (size_t)(win * NTOK + i) * DIMC + h * 64 + half * 32 + seg * 8) = val;
        }
      }
    }
  }
}

extern "C" void kernel_launch(void* const* d_in, const int* in_sizes, int n_in,
                              void* d_out, int out_size, void* d_ws, size_t ws_size,
                              hipStream_t stream) {
  (void)in_sizes; (void)n_in; (void)out_size; (void)ws_size;
  const float* x0     = (const float*)d_in[0];
  const float* an1_w  = (const float*)d_in[1];
  const float* an1_b  = (const float*)d_in[2];
  const float* ad1_W  = (const float*)d_in[3];
  const float* ad1_b  = (const float*)d_in[4];
  const float* ac1_W  = (const float*)d_in[5];
  const float* ac1_b  = (const float*)d_in[6];
  const float* au1_W  = (const float*)d_in[7];
  const float* au1_b  = (const float*)d_in[8];
  const float* an2_w  = (const float*)d_in[9];
  const float* an2_b  = (const float*)d_in[10];
  const float* ad2_W  = (const float*)d_in[11];
  const float* ad2_b  = (const float*)d_in[12];
  const float* ac2_W  = (const float*)d_in[13];
  const float* ac2_b  = (const float*)d_in[14];
  const float* au2_W  = (const float*)d_in[15];
  const float* au2_b  = (const float*)d_in[16];
  const float* n1_w   = (const float*)d_in[17];
  const float* n1_b   = (const float*)d_in[18];
  const float* qkv_W  = (const float*)d_in[19];
  const float* qkv_b  = (const float*)d_in[20];
  const float* facu_W = (const float*)d_in[21];
  const float* facv_W = (const float*)d_in[22];
  const float* qfac_W = (const float*)d_in[23];
  const float* vfac_W = (const float*)d_in[24];
  const float* rel_h  = (const float*)d_in[25];
  const float* rel_w  = (const float*)d_in[26];
  const float* proj_W = (const float*)d_in[27];
  const float* proj_b = (const float*)d_in[28];
  const float* n2_w   = (const float*)d_in[29];
  const float* n2_b   = (const float*)d_in[30];
  const float* mlp_W1 = (const float*)d_in[31];
  const float* mlp_b1 = (const float*)d_in[32];
  const float* mlp_W2 = (const float*)d_in[33];
  const float* mlp_b2 = (const float*)d_in[34];

  char* ws = (char*)d_ws;
  size_t off = 0;
  auto alloc = [&](size_t bytes) -> void* {
    void* p = (void*)(ws + off);
    off += (bytes + 255) & ~(size_t)255;
    return p;
  };
  u16*  bufA  = (u16*)alloc((size_t)MS * 3072 * 2);      // qkvR bf16 / mlp hidden bf16
  u16*  bufB  = (u16*)alloc((size_t)MWP * DIMC * 2);     // LN/window tokens + attn out, bf16
  float* bufX = (float*)alloc((size_t)MS * DIMC * 4);    // residual stream f32
  u16*  bufD  = (u16*)alloc((size_t)MS * ACCH * 2);      // adapter down out
  u16*  bufE  = (u16*)alloc((size_t)MS * ACCH * 2);      // adapter conv+gelu out
  u16*  Wcomb = (u16*)alloc((size_t)2304 * 768 * 2);
  u16*  Wproj = (u16*)alloc((size_t)768 * 768 * 2);
  u16*  Wm1   = (u16*)alloc((size_t)3072 * 768 * 2);
  u16*  Wm2   = (u16*)alloc((size_t)768 * 3072 * 2);
  u16*  Wad1  = (u16*)alloc((size_t)256 * 768 * 2);
  u16*  Wau1  = (u16*)alloc((size_t)768 * 192 * 2);
  u16*  Wcv1  = (u16*)alloc((size_t)256 * 5184 * 2);
  u16*  Wad2  = (u16*)alloc((size_t)256 * 768 * 2);
  u16*  Wau2  = (u16*)alloc((size_t)768 * 192 * 2);
  u16*  Wcv2  = (u16*)alloc((size_t)256 * 5184 * 2);
  float* Uq   = (float*)alloc(768 * 32 * 4);
  float* Uv   = (float*)alloc(768 * 32 * 4);
  u16*  zrow  = (u16*)alloc(256);

  // ---- weight prep (every launch; deterministic) ----
  k_zero16<<<1, 256, 0, stream>>>(zrow, 128);
  k_compute_U<<<192, 256, 0, stream>>>(facu_W, qfac_W, vfac_W, Uq, Uv);
  k_build_wcomb<<<(2304 * 768 + 255) / 256, 256, 0, stream>>>(qkv_W, Uq, Uv, facv_W, Wcomb);
  k_cast_pad<<<(768 * 768 / 4 + 255) / 256, 256, 0, stream>>>(proj_W, Wproj, 768, 768, 768);
  k_cast_pad<<<(3072 * 768 / 4 + 255) / 256, 256, 0, stream>>>(mlp_W1, Wm1, 3072, 768, 3072);
  k_cast_pad<<<(768 * 3072 / 4 + 255) / 256, 256, 0, stream>>>(mlp_W2, Wm2, 768, 3072, 768);
  k_cast_pad<<<(256 * 768 / 4 + 255) / 256, 256, 0, stream>>>(ad1_W, Wad1, 192, 768, 256);
  k_cast_pad<<<(768 * 192 / 4 + 255) / 256, 256, 0, stream>>>(au1_W, Wau1, 768, 192, 768);
  k_cast_pad<<<(256 * 768 / 4 + 255) / 256, 256, 0, stream>>>(ad2_W, Wad2, 192, 768, 256);
  k_cast_pad<<<(768 * 192 / 4 + 255) / 256, 256, 0, stream>>>(au2_W, Wau2, 768, 192, 768);
  k_conv_repack<<<(256 * 5184 / 4 + 255) / 256, 256, 0, stream>>>(ac1_W, Wcv1);
  k_conv_repack<<<(256 * 5184 / 4 + 255) / 256, 256, 0, stream>>>(ac2_W, Wcv2);

  // ---- adapter 1: x1 = x0 + up(gelu(conv(down(LN(x0))))) ----
  ln_k<false><<<MS, 256, 0, stream>>>(x0, an1_w, an1_b, bufB);
  gemm_bt<1, false><<<dim3(2, 160), 256, 0, stream>>>(bufB, Wad1, ad1_b, nullptr, nullptr, bufD, MS, 192, 768, nullptr, 2);
  gemm_bt<2, true><<<dim3(2, 160), 256, 0, stream>>>(bufD, Wcv1, ac1_b, nullptr, nullptr, bufE, MS, 192, 5184, zrow, 2);
  gemm_bt<3, false><<<dim3(6, 160), 256, 0, stream>>>(bufE, Wau1, au1_b, x0, bufX, nullptr, MS, 768, 192, nullptr, 6);

  // ---- windowed attention ----
  ln_k<true><<<MWP, 256, 0, stream>>>(bufX, n1_w, n1_b, bufB);
  gemm_bt<4, false><<<dim3(18, 192), 256, 0, stream>>>(bufB, Wcomb, qkv_b, nullptr, nullptr, bufA, MW, 2304, 768, nullptr, 6);
  attn_k<<<125 * HEADS, 512, 0, stream>>>(bufA, rel_h, rel_w, bufB);
  gemm_bt<5, false><<<dim3(6, 192), 256, 0, stream>>>(bufB, Wproj, proj_b, bufX, bufX, nullptr, MW, 768, 768, nullptr, 6);

  // ---- adapter 2 ----
  ln_k<false><<<MS, 256, 0, stream>>>(bufX, an2_w, an2_b, bufB);
  gemm_bt<1, false><<<dim3(2, 160), 256, 0, stream>>>(bufB, Wad2, ad2_b, nullptr, nullptr, bufD, MS, 192, 768, nullptr, 2);
  gemm_bt<2, true><<<dim3(2, 160), 256, 0, stream>>>(bufD, Wcv2, ac2_b, nullptr, nullptr, bufE, MS, 192, 5184, zrow, 2);
  gemm_bt<3, false><<<dim3(6, 160), 256, 0, stream>>>(bufE, Wau2, au2_b, bufX, bufX, nullptr, MS, 768, 192, nullptr, 6);

  // ---- MLP ----
  ln_k<false><<<MS, 256, 0, stream>>>(bufX, n2_w, n2_b, bufB);
  gemm_bt<2, false><<<dim3(24, 160), 256, 0, stream>>>(bufB, Wm1, mlp_b1, nullptr, nullptr, bufA, MS, 3072, 768, nullptr, 8);
  gemm_bt<3, false><<<dim3(6, 160), 256, 0, stream>>>(bufA, Wm2, mlp_b2, bufX, (float*)d_out, nullptr, MS, 768, 3072, nullptr, 6);
}

// Round 16
// 1033.350 us; speedup vs baseline: 1.3010x; 1.0916x over previous
//
#include <hip/hip_runtime.h>

typedef unsigned short u16;
typedef __bf16 v8bf __attribute__((ext_vector_type(8)));
typedef unsigned short v8u __attribute__((ext_vector_type(8)));
typedef unsigned short v4u __attribute__((ext_vector_type(4)));
typedef float f32x4 __attribute__((ext_vector_type(4)));
typedef float v8f __attribute__((ext_vector_type(8)));

static constexpr int DIMC = 768;
static constexpr int HEADS = 12;
static constexpr int WINS  = 14;
static constexpr int ACCH  = 192;   // adapter channels
static constexpr int NTOK  = 196;   // 14*14
static constexpr int MW    = 24500; // 125 windows * 196 tokens
static constexpr int MWP   = 24576; // padded to tile multiple
static constexpr int MS    = 20480; // 5*64*64 spatial tokens

__device__ __forceinline__ float bf2f(u16 u) {
  union { unsigned int i; float f; } x; x.i = ((unsigned int)u) << 16; return x.f;
}
__device__ __forceinline__ u16 f2bf(float f) {
  union { float f; unsigned int i; } x; x.f = f;
  unsigned int r = x.i + 0x7fffu + ((x.i >> 16) & 1u);
  return (u16)(r >> 16);
}
// fast tanh-form GELU: max abs err ~2e-3 (well under threshold)
__device__ __forceinline__ float gelu_f(float x) {
  float y = 0.79788456080286536f * (x + 0.044715f * x * x * x);
  y = fminf(fmaxf(y, -15.f), 15.f);
  const float e = __expf(2.f * y);
  const float th = 1.f - 2.f * __builtin_amdgcn_rcpf(e + 1.f);
  return 0.5f * x * (1.f + th);
}
// async global->LDS, 16B per lane. LDS dest is wave-uniform base + lane*16.
__device__ __forceinline__ void cp16(const u16* g, u16* l) {
  __builtin_amdgcn_global_load_lds(
      (const __attribute__((address_space(1))) unsigned int*)(const void*)g,
      (__attribute__((address_space(3))) unsigned int*)(void*)l, 16, 0, 0);
}

// ---------------- weight prep ----------------
__global__ void k_zero16(u16* p, int n) {
  int i = blockIdx.x * 256 + threadIdx.x;
  if (i < n) p[i] = 0;
}
// U[k][b] = sum_a facu_W[a][k] * fac_W[b][a]   (fac = qfac or vfac)
__global__ void k_compute_U(const float* __restrict__ facu, const float* __restrict__ qfac,
                            const float* __restrict__ vfac, float* __restrict__ Uq,
                            float* __restrict__ Uv) {
  int idx = blockIdx.x * 256 + threadIdx.x;
  if (idx >= 2 * 768 * 32) return;
  const int which = idx / (768 * 32);
  const int rem = idx - which * 768 * 32;
  const int k = rem >> 5, b = rem & 31;
  const float* fac = which ? vfac : qfac;
  float s = 0.f;
  for (int a = 0; a < 32; ++a) s += facu[a * 768 + k] * fac[b * 32 + a];
  (which ? Uv : Uq)[rem] = s;
}
// Wc[n][k] = qkv_W[n][k] (+ sum_b U{q,v}[k][b]*facv_W[n'][b] for q/v blocks), cast bf16
__global__ void k_build_wcomb(const float* __restrict__ qkvW, const float* __restrict__ Uq,
                              const float* __restrict__ Uv, const float* __restrict__ facv,
                              u16* __restrict__ Wc) {
  int idx = blockIdx.x * 256 + threadIdx.x;
  if (idx >= 2304 * 768) return;
  const int n = idx / 768, k = idx - n * 768;
  float v = qkvW[idx];
  if (n < 768) {
    float s = 0.f;
    for (int b = 0; b < 32; ++b) s += Uq[k * 32 + b] * facv[n * 32 + b];
    v += s;
  } else if (n >= 1536) {
    const int nn = n - 1536;
    float s = 0.f;
    for (int b = 0; b < 32; ++b) s += Uv[k * 32 + b] * facv[nn * 32 + b];
    v += s;
  }
  Wc[idx] = f2bf(v);
}
// vectorized cast+pad: 4 elems/thread (cols % 4 == 0 so a group shares its row)
__global__ void k_cast_pad(const float* __restrict__ src, u16* __restrict__ dst,
                           int rows, int cols, int rowsPad) {
  int idx = blockIdx.x * 256 + threadIdx.x;
  const int base = idx * 4;
  if (base >= rowsPad * cols) return;
  const int r = base / cols;
  v4u o;
  if (r < rows) {
    const float4 v = *(const float4*)(src + base);
    o[0] = f2bf(v.x); o[1] = f2bf(v.y); o[2] = f2bf(v.z); o[3] = f2bf(v.w);
  } else {
    o[0] = o[1] = o[2] = o[3] = 0;
  }
  *(v4u*)(dst + base) = o;
}
// ac_W [192][192][3][3][3] -> Wconv [256 pad][27*192] with k = tap*192+ci  (4 ci/thread)
__global__ void k_conv_repack(const float* __restrict__ src, u16* __restrict__ dst) {
  int idx = blockIdx.x * 256 + threadIdx.x;
  const int base = idx * 4;
  if (base >= 256 * 5184) return;
  const int co = base / 5184;
  const int rem = base - co * 5184;
  const int tap = rem / 192, ci = rem - tap * 192;   // ci % 4 == 0 (192 % 4 == 0)
  v4u o;
  if (co < 192) {
    const float* sp = src + co * 5184 + ci * 27 + tap;
#pragma unroll
    for (int e = 0; e < 4; ++e) o[e] = f2bf(sp[e * 27]);
  } else {
    o[0] = o[1] = o[2] = o[3] = 0;
  }
  *(v4u*)(dst + base) = o;
}

// ---------------- LayerNorm (optionally fused window-partition) ----------------
template<bool WINDOWED>
__global__ __launch_bounds__(256)
void ln_k(const float* __restrict__ X, const float* __restrict__ w,
          const float* __restrict__ b, u16* __restrict__ out) {
  const int r = (int)blockIdx.x;
  const int t = (int)threadIdx.x;
  int src = r;
  bool zero = false;
  if (WINDOWED) {
    if (r >= MW) zero = true;
    else {
      const int win = r / NTOK, tk = r - win * NTOK;
      const int img = win / 25, wrem = win - img * 25, wy = wrem / 5, wx = wrem - wy * 5;
      const int ty = tk / WINS, tx = tk - ty * WINS;
      const int y = wy * WINS + ty, x = wx * WINS + tx;
      if (y >= 64 || x >= 64) zero = true;
      else src = (img << 12) + (y << 6) + x;
    }
  }
  u16* orow = out + (size_t)r * DIMC;
  if (zero) {
    for (int c = t; c < DIMC; c += 256) orow[c] = 0;
    return;
  }
  const float* xr = X + (size_t)src * DIMC;
  const float v0 = xr[t], v1 = xr[t + 256], v2 = xr[t + 512];
  float s = v0 + v1 + v2, ss = v0 * v0 + v1 * v1 + v2 * v2;
#pragma unroll
  for (int o = 32; o > 0; o >>= 1) { s += __shfl_xor(s, o, 64); ss += __shfl_xor(ss, o, 64); }
  __shared__ float red[8];
  const int wave = t >> 6, lane = t & 63;
  if (lane == 0) { red[wave] = s; red[4 + wave] = ss; }
  __syncthreads();
  s = red[0] + red[1] + red[2] + red[3];
  ss = red[4] + red[5] + red[6] + red[7];
  const float mean = s * (1.0f / 768.0f);
  const float var = ss * (1.0f / 768.0f) - mean * mean;
  const float rstd = rsqrtf(var + 1e-5f);
  orow[t]       = f2bf((v0 - mean) * rstd * w[t]       + b[t]);
  orow[t + 256] = f2bf((v1 - mean) * rstd * w[t + 256] + b[t + 256]);
  orow[t + 512] = f2bf((v2 - mean) * rstd * w[t + 512] + b[t + 512]);
}

// ---------------- GEMM: C[M,N] = A[M,K] @ B[N,K]^T (+bias, epilogues) ----------------
// EPI: 1 = bf16 out (bias); 2 = bf16 out (bias+GELU); 3 = f32 out (bias+residual);
//      4 = bf16 qkv-scatter per (win,head); 5 = f32 window-unpartition + in-place resid add
// CONV: A rows gathered as 3x3x3 SAME conv over [5][64][64][192]; K = tap*192+ci (BK=64 only)
// BK: 64 (K%64==0) or 128 (K%128==0; halves k-loop iters/barriers, LDS 64 KB, same 2 blk/CU)
// Block swizzle: XCD-chunked + bn-grouping GN. Epilogue: LDS-staged vectorized stores.
template<int EPI, bool CONV, int BK>
__global__ __launch_bounds__(256)
void gemm_bt(const u16* __restrict__ A, const u16* __restrict__ B,
             const float* __restrict__ bias, const float* __restrict__ resid,
             float* __restrict__ outF, u16* __restrict__ outB,
             int M, int N, int K, const u16* __restrict__ zrow, int GN) {
  __shared__ u16 smem[2 * 128 * BK];
  u16* At = smem;
  u16* Bt = smem + 128 * BK;
  const int gx = (int)gridDim.x;
  const int nwg = gx * (int)gridDim.y;
  const int lin = (int)blockIdx.y * gx + (int)blockIdx.x;
  const int csz = nwg >> 3;            // blocks per XCD chunk
  const int xcd = lin & 7;
  const int c = lin >> 3;              // position within chunk
  const int bmc = csz / gx;            // bm rows per chunk
  const int gsz = bmc * GN;
  const int grp = c / gsz, rr = c - grp * gsz;
  const int bn = grp * GN + (rr % GN);
  const int bm = xcd * bmc + (rr / GN);
  const int t = (int)threadIdx.x;
  const int wave = t >> 6, lane = t & 63;
  const int wm = wave >> 1, wn = wave & 1;
  const int li = lane & 15, lq = lane >> 4;

  f32x4 acc[4][4];
  const f32x4 vzero = {0.f, 0.f, 0.f, 0.f};
#pragma unroll
  for (int a = 0; a < 4; ++a)
#pragma unroll
    for (int b = 0; b < 4; ++b) acc[a][b] = vzero;

  const int nk = K / BK;
  for (int kt = 0; kt < nk; ++kt) {
    if (BK == 64) {
      const int lrow = lane >> 3;                // 0..7
      const int c16s = (lane & 7) ^ lrow;        // pre-swizzled source chunk
      int cD = 0, cY = 0, cX = 0, cblk = 0;
      if (CONV) {
        const int tap = kt / 3;
        cblk = (kt - tap * 3) << 6;
        const int kd = tap / 9, r9 = tap - kd * 9, ky = r9 / 3;
        cD = kd - 1; cY = ky - 1; cX = (r9 - ky * 3) - 1;
      }
#pragma unroll
      for (int i = 0; i < 4; ++i) {           // stage A: 128x64 bf16
        const int r0 = i * 32 + wave * 8;
        const int grow = bm * 128 + r0 + lrow;
        const u16* src;
        if (CONV) {
          const int d = (grow >> 12) + cD, y = ((grow >> 6) & 63) + cY, x = (grow & 63) + cX;
          if ((unsigned)d < 5u && (unsigned)y < 64u && (unsigned)x < 64u)
            src = A + (size_t)((d << 12) + (y << 6) + x) * ACCH + cblk + c16s * 8;
          else
            src = zrow + c16s * 8;
        } else {
          src = A + (size_t)grow * K + (kt << 6) + c16s * 8;
        }
        cp16(src, &At[r0 * 64]);
      }
#pragma unroll
      for (int i = 0; i < 4; ++i) {           // stage B: 128x64 bf16
        const int r0 = i * 32 + wave * 8;
        const int grow = bn * 128 + r0 + lrow;
        cp16(B + (size_t)grow * K + (kt << 6) + c16s * 8, &Bt[r0 * 64]);
      }
    } else {  // BK == 128: rows of 16 chunks; store chunk c at phys c^(row&15)
      const int srow4 = lane >> 4;               // 0..3 (4 rows per cp16)
      const int sc = lane & 15;                  // phys chunk
#pragma unroll
      for (int i = 0; i < 8; ++i) {           // stage A: 128x128 bf16
        const int rbase = i * 16 + wave * 4;
        const int row = rbase + srow4;
        const int c16s = sc ^ (row & 15);        // logical source chunk
        cp16(A + (size_t)(bm * 128 + row) * K + kt * 128 + c16s * 8, &At[rbase * 128]);
      }
#pragma unroll
      for (int i = 0; i < 8; ++i) {           // stage B: 128x128 bf16
        const int rbase = i * 16 + wave * 4;
        const int row = rbase + srow4;
        const int c16s = sc ^ (row & 15);
        cp16(B + (size_t)(bn * 128 + row) * K + kt * 128 + c16s * 8, &Bt[rbase * 128]);
      }
    }
    __syncthreads();                         // drains vmcnt for global_load_lds
    if (BK == 64) {
#pragma unroll
      for (int kk = 0; kk < 2; ++kk) {
        v8bf af[4], bg[4];
#pragma unroll
        for (int mf = 0; mf < 4; ++mf) {
          const int row = wm * 64 + mf * 16 + li;
          const int c16 = (kk * 4 + lq) ^ (li & 7);
          af[mf] = *(const v8bf*)&At[row * 64 + c16 * 8];
        }
#pragma unroll
        for (int nf = 0; nf < 4; ++nf) {
          const int row = wn * 64 + nf * 16 + li;
          const int c16 = (kk * 4 + lq) ^ (li & 7);
          bg[nf] = *(const v8bf*)&Bt[row * 64 + c16 * 8];
        }
#pragma unroll
        for (int mf = 0; mf < 4; ++mf)
#pragma unroll
          for (int nf = 0; nf < 4; ++nf)
            acc[mf][nf] = __builtin_amdgcn_mfma_f32_16x16x32_bf16(af[mf], bg[nf], acc[mf][nf], 0, 0, 0);
      }
    } else {
#pragma unroll
      for (int kk = 0; kk < 4; ++kk) {
        const int c16 = (kk * 4 + lq) ^ li;      // phys chunk = logical ^ (row&15), row&15 == li
        v8bf af[4], bg[4];
#pragma unroll
        for (int mf = 0; mf < 4; ++mf) {
          const int row = wm * 64 + mf * 16 + li;
          af[mf] = *(const v8bf*)&At[row * 128 + c16 * 8];
        }
#pragma unroll
        for (int nf = 0; nf < 4; ++nf) {
          const int row = wn * 64 + nf * 16 + li;
          bg[nf] = *(const v8bf*)&Bt[row * 128 + c16 * 8];
        }
#pragma unroll
        for (int mf = 0; mf < 4; ++mf)
#pragma unroll
          for (int nf = 0; nf < 4; ++nf)
            acc[mf][nf] = __builtin_amdgcn_mfma_f32_16x16x32_bf16(af[mf], bg[nf], acc[mf][nf], 0, 0, 0);
      }
    }
    __syncthreads();
  }

  // ---- epilogue: stage C through LDS, vectorized stores ----
  if (EPI == 1 || EPI == 2 || EPI == 4) {
    u16* Ct = smem;  // [128][128] bf16, col ^ ((row&7)<<3)
#pragma unroll
    for (int mf = 0; mf < 4; ++mf)
#pragma unroll
      for (int nf = 0; nf < 4; ++nf)
#pragma unroll
        for (int r = 0; r < 4; ++r) {
          const int row = wm * 64 + mf * 16 + lq * 4 + r;
          const int col = wn * 64 + nf * 16 + li;
          float v = acc[mf][nf][r] + bias[bn * 128 + col];
          if (EPI == 2) v = gelu_f(v);
          Ct[row * 128 + (col ^ ((row & 7) << 3))] = f2bf(v);
        }
    __syncthreads();
#pragma unroll
    for (int it = 0; it < 8; ++it) {
      const int row = it * 16 + (t >> 4);
      const int seg = t & 15;
      const int gr = bm * 128 + row;
      const int col8 = bn * 128 + seg * 8;
      if (gr < M && col8 < N) {
        v8u val = *(const v8u*)&Ct[row * 128 + ((seg ^ (row & 7)) * 8)];
        if (EPI == 4) {
          const int sec = col8 / 768;
          const int hm = col8 - sec * 768;
          const int hd = hm >> 6, dd = hm & 63;
          const int win = gr / 196, tk = gr - win * 196;
          *(v8u*)(outB + (size_t)(((win * HEADS + hd) * 3 + sec) * NTOK + tk) * 64 + dd) = val;
        } else {
          *(v8u*)(outB + (size_t)gr * N + col8) = val;
        }
      }
    }
  } else {  // EPI 3 / 5: f32, two wm-halves through [64][128] f32 tile
    float* Cf = (float*)smem;
#pragma unroll
    for (int h2 = 0; h2 < 2; ++h2) {
      if (h2) __syncthreads();               // half-0 reads done before overwrite
      if (wm == h2) {
#pragma unroll
        for (int mf = 0; mf < 4; ++mf)
#pragma unroll
          for (int nf = 0; nf < 4; ++nf)
#pragma unroll
            for (int r = 0; r < 4; ++r) {
              const int row = mf * 16 + lq * 4 + r;      // 0..63 within half
              const int col = wn * 64 + nf * 16 + li;
              const float v = acc[mf][nf][r] + bias[bn * 128 + col];
              Cf[row * 128 + (col ^ (((row >> 2) & 3) << 3))] = v;
            }
      }
      __syncthreads();
#pragma unroll
      for (int it = 0; it < 4; ++it) {
        const int row = it * 16 + (t >> 4);              // 0..63
        const int seg = t & 15;
        const int gr = bm * 128 + h2 * 64 + row;
        const int col8 = bn * 128 + seg * 8;
        if (gr < M && col8 < N) {
          v8f val = *(const v8f*)&Cf[row * 128 + ((seg ^ ((row >> 2) & 3)) * 8)];
          if (EPI == 3) {
            const float* rp = resid + (size_t)gr * N + col8;
#pragma unroll
            for (int e = 0; e < 8; ++e) val[e] += rp[e];
            *(v8f*)(outF + (size_t)gr * N + col8) = val;
          } else {  // EPI 5: window-unpartition + in-place residual add
            const int win = gr / 196, tk = gr - win * 196;
            const int img = win / 25, wrem = win - img * 25, wy = wrem / 5, wx = wrem - wy * 5;
            const int ty = tk / WINS, tx = tk - ty * WINS;
            const int y = wy * WINS + ty, x = wx * WINS + tx;
            if (y < 64 && x < 64) {
              const size_t o = (size_t)((img << 12) + (y << 6) + x) * DIMC + col8;
              const float* rp = resid + o;
#pragma unroll
              for (int e = 0; e < 8; ++e) val[e] += rp[e];
              *(v8f*)(outF + o) = val;
            }
          }
        }
      }
    }
  }
}

// ---------------- fused windowed attention, MFMA flash-style, 8 waves ----------------
// block = (win, head), 512 threads; wave w owns q-rows [32w, 32w+32).
// Q held in REGISTERS (qf[2][2], one-time global loads) -> LDS 47 KB.
// qkvR layout per (win,head): [Q(196x64) | K(196x64) | V(196x64)]
__global__ __launch_bounds__(512, 2)
void attn_k(const u16* __restrict__ qkvR, const float* __restrict__ relh,
            const float* __restrict__ relw, u16* __restrict__ out) {
  const int blk = (int)blockIdx.x;
  const int win = blk / HEADS, h = blk - win * HEADS;
  const int t = (int)threadIdx.x, w = t >> 6, lane = t & 63;
  const int li = lane & 15, g = lane >> 4;
  const int nmf = (w < 6) ? 2 : (w == 6 ? 1 : 0);   // valid 16-row fragments this wave

  __shared__ u16 Kt[64 * 64];     // 8 KB [j][d], swizzled (cp16 linear dest)
  __shared__ u16 Vt[64 * 64];     // 8 KB [d][j], seg-XOR swizzled
  __shared__ u16 Pb[8 * 32 * 32]; // 16 KB per-wave P/O chunks; aliases rel buf in phase A
  __shared__ u16 dhwT[28 * 268];  // 15 KB: rows 0..13 = dh[jh][i], 14..27 = dw[jw][i]

  const u16* Qb = qkvR + (size_t)(win * HEADS + h) * 3 * NTOK * 64;
  const u16* Kb = Qb + NTOK * 64;
  const u16* Vb = Kb + NTOK * 64;

  // ---- Q fragments in registers: qf[mf][ks], rows clamped to 195 ----
  v8bf qf[2][2];
#pragma unroll
  for (int mf = 0; mf < 2; ++mf) {
    const int row = min(32 * w + mf * 16 + li, NTOK - 1);
#pragma unroll
    for (int ks = 0; ks < 2; ++ks)
      qf[mf][ks] = *(const v8bf*)(Qb + (size_t)row * 64 + ks * 32 + g * 8);
  }

  // ---- stage rel tables into Pb (phase-A alias) ----
  u16* relb = Pb; // [2][32 rows][64 cols], swizzled like Kt
  for (int idx = t; idx < 2 * 32 * 64; idx += 512) {
    const int which = idx >> 11, rem = idx & 2047, r = rem >> 6, c = rem & 63;
    const float v = (r < 27) ? (which ? relw[r * 64 + c] : relh[r * 64 + c]) : 0.f;
    relb[which * 2048 + r * 64 + (((c >> 3) ^ (r & 7)) * 8) + (c & 7)] = f2bf(v);
  }
  __syncthreads();

  // ---- phase A: rel-pos tables via MFMA (Q from registers), scatter into dhwT ----
  {
    f32x4 dacc[2][2], eacc[2][2];
    const f32x4 vz = {0.f, 0.f, 0.f, 0.f};
#pragma unroll
    for (int mf = 0; mf < 2; ++mf)
#pragma unroll
      for (int nf = 0; nf < 2; ++nf) { dacc[mf][nf] = vz; eacc[mf][nf] = vz; }
#pragma unroll
    for (int ks = 0; ks < 2; ++ks) {
#pragma unroll
      for (int nf = 0; nf < 2; ++nf) {
        const int row = nf * 16 + li;
        const int off = row * 64 + (((ks * 4 + g) ^ (li & 7)) * 8);
        v8bf bh = *(const v8bf*)&relb[off];
        v8bf bw = *(const v8bf*)&relb[2048 + off];
#pragma unroll
        for (int mf = 0; mf < 2; ++mf) if (mf < nmf) {
          dacc[mf][nf] = __builtin_amdgcn_mfma_f32_16x16x32_bf16(qf[mf][ks], bh, dacc[mf][nf], 0, 0, 0);
          eacc[mf][nf] = __builtin_amdgcn_mfma_f32_16x16x32_bf16(qf[mf][ks], bw, eacc[mf][nf], 0, 0, 0);
        }
      }
    }
    // scatter D,E -> dhwT[jh][i] / dhwT[14+jw][i] (bijective per row)
#pragma unroll
    for (int mf = 0; mf < 2; ++mf) if (mf < nmf)
#pragma unroll
      for (int nf = 0; nf < 2; ++nf)
#pragma unroll
        for (int r = 0; r < 4; ++r) {
          const int i = 32 * w + mf * 16 + 4 * g + r;
          if (i < 196) {
            const int c = nf * 16 + li;
            const int ih = (i * 2341) >> 15, iw = i - ih * 14;
            const int jh = ih + 13 - c;
            if ((unsigned)jh < 14u) dhwT[jh * 268 + i] = f2bf(dacc[mf][nf][r]);
            const int jw = iw + 13 - c;
            if ((unsigned)jw < 14u) dhwT[(14 + jw) * 268 + i] = f2bf(eacc[mf][nf][r]);
          }
        }
  }
  __syncthreads();   // phase-A reads of relb done; Pb free for P chunks

  // ---- phase B: flash over 4 j-tiles of 64 ----
  f32x4 oacc[2][4];
  const f32x4 vz = {0.f, 0.f, 0.f, 0.f};
#pragma unroll
  for (int a = 0; a < 2; ++a)
#pragma unroll
    for (int b = 0; b < 4; ++b) oacc[a][b] = vz;
  float mrun[8], lrun[8];
#pragma unroll
  for (int a = 0; a < 8; ++a) { mrun[a] = -1e30f; lrun[a] = 0.f; }

  u16* Pw = Pb + w * 1024; // own chunk [32 i][32 j]
  const int jv = t & 63;   // V-staging: column j
  const int dv = w * 8;    // V-staging: 8-d slab

  for (int jt = 0; jt < 4; ++jt) {
    const int j0 = jt * 64;
    const int njf = (jt < 3) ? 4 : 1;    // valid 16-col j-fragments
    const int nhalf = (jt < 3) ? 2 : 1;  // valid 32-col PV halves

    // stage K FIRST (oldest vm op): 8 waves x 8 rows = 64 rows, one cp16 each
    {
      const int rbase = w * 8;
      const int row = rbase + (lane >> 3);
      const int jg = min(j0 + row, NTOK - 1);
      const int cbs = (lane & 7) ^ (row & 7);
      cp16(Kb + (size_t)jg * 64 + cbs * 8, &Kt[rbase * 64]);
    }
    __builtin_amdgcn_sched_barrier(0);       // pin: K issued before V
    // V prefetch into regs (newest vm op; rides through the K wait)
    const int jgv = min(j0 + jv, NTOK - 1);
    v8u vg = *(const v8u*)(Vb + (size_t)jgv * 64 + dv);
    __builtin_amdgcn_sched_barrier(0);
    asm volatile("s_waitcnt vmcnt(1)" ::: "memory");   // K landed; V still in flight
    __builtin_amdgcn_sched_barrier(0);
    __builtin_amdgcn_s_barrier();            // Kt visible to all waves
    __builtin_amdgcn_sched_barrier(0);

    // QK^T (Q from registers) — V latency hides under this
    f32x4 sacc[2][4];
#pragma unroll
    for (int a = 0; a < 2; ++a)
#pragma unroll
      for (int b = 0; b < 4; ++b) sacc[a][b] = vz;
    if (nmf > 0) {
#pragma unroll
      for (int ks = 0; ks < 2; ++ks) {
#pragma unroll
        for (int jf = 0; jf < 4; ++jf) if (jf < njf) {
          const int row = jf * 16 + li;
          v8bf kb = *(const v8bf*)&Kt[row * 64 + (((ks * 4 + g) ^ (li & 7)) * 8)];
#pragma unroll
          for (int mf = 0; mf < 2; ++mf) if (mf < nmf)
            sacc[mf][jf] = __builtin_amdgcn_mfma_f32_16x16x32_bf16(qf[mf][ks], kb, sacc[mf][jf], 0, 0, 0);
        }
      }
    }

    // V regs -> Vt (seg-XOR swizzled); visible to all waves at the pre-PV barrier
    asm volatile("s_waitcnt vmcnt(0)" ::: "memory");
    __builtin_amdgcn_sched_barrier(0);
#pragma unroll
    for (int e = 0; e < 8; ++e) {
      const int da = dv + e;
      Vt[da * 64 + (((jv >> 3) ^ (da & 7)) * 8) + (jv & 7)] = vg[e];
    }

    // bias + mask (vectorized b64 reads from dhwT)
#pragma unroll
    for (int jf = 0; jf < 4; ++jf) if (jf < njf) {
      const int j = j0 + jf * 16 + li;
      const bool jok = j < 196;
      int jh = (j * 2341) >> 15;
      const int jw = j - jh * 14;
      if (jh > 13) jh = 13;                  // clamp for padded j (masked below)
#pragma unroll
      for (int mf = 0; mf < 2; ++mf) if (mf < nmf) {
        const int i0 = 32 * w + mf * 16 + 4 * g;
        v4u hv = *(const v4u*)&dhwT[jh * 268 + i0];
        v4u wv = *(const v4u*)&dhwT[(14 + jw) * 268 + i0];
#pragma unroll
        for (int r = 0; r < 4; ++r) {
          float v;
          if (jok && (i0 + r) < 196)
            v = sacc[mf][jf][r] * 0.125f + bf2f(hv[r]) + bf2f(wv[r]);
          else v = -1e30f;
          sacc[mf][jf][r] = v;
        }
      }
    }

    // online softmax update
#pragma unroll
    for (int mf = 0; mf < 2; ++mf) if (mf < nmf)
#pragma unroll
      for (int r = 0; r < 4; ++r) {
        float tmx = -1e30f;
#pragma unroll
        for (int jf = 0; jf < 4; ++jf) if (jf < njf) tmx = fmaxf(tmx, sacc[mf][jf][r]);
#pragma unroll
        for (int o = 1; o < 16; o <<= 1) tmx = fmaxf(tmx, __shfl_xor(tmx, o, 16));
        const int idx = mf * 4 + r;
        const float mnew = fmaxf(mrun[idx], tmx);
        const float sf = __expf(mrun[idx] - mnew);
        mrun[idx] = mnew;
        float ls = 0.f;
#pragma unroll
        for (int jf = 0; jf < 4; ++jf) if (jf < njf) {
          const float p = __expf(sacc[mf][jf][r] - mnew);
          sacc[mf][jf][r] = p;
          ls += p;
        }
#pragma unroll
        for (int o = 1; o < 16; o <<= 1) ls += __shfl_xor(ls, o, 16);
        lrun[idx] = lrun[idx] * sf + ls;
#pragma unroll
        for (int nf = 0; nf < 4; ++nf) oacc[mf][nf][r] *= sf;
      }

    // P chunks (32i x 32j per half) -> PV, two halves; own-wave lgkm ordering
#pragma unroll
    for (int half = 0; half < 2; ++half) if (half < nhalf) {
#pragma unroll
      for (int c = 0; c < 2; ++c) {
        const int jf = half * 2 + c;
        const int jloc = c * 16 + li;
#pragma unroll
        for (int mf = 0; mf < 2; ++mf)
#pragma unroll
          for (int r = 0; r < 4; ++r) {
            const int il = mf * 16 + 4 * g + r;
            u16 pv = 0;
            if (mf < nmf && jf < njf) pv = f2bf(sacc[mf][jf][r]);
            Pw[il * 32 + (jloc ^ (g << 3))] = pv;
          }
      }
      if (half == 0) __syncthreads();        // Vt (all waves) + own P visible before PV
      // PV: O[i][d] += P[i][j-half] * V[j-half][d]   (K = 32 -> one MFMA per (mf,nf))
      if (nmf > 0) {
        v8bf pa[2];
#pragma unroll
        for (int mf = 0; mf < 2; ++mf) {
          const int row = mf * 16 + li;
          pa[mf] = *(const v8bf*)&Pw[row * 32 + ((g ^ ((li >> 2) & 3)) * 8)];
        }
#pragma unroll
        for (int nf = 0; nf < 4; ++nf) {
          const int d = nf * 16 + li;
          v8bf vb = *(const v8bf*)&Vt[d * 64 + (((half * 4 + g) ^ (li & 7)) * 8)];
#pragma unroll
          for (int mf = 0; mf < 2; ++mf)
            oacc[mf][nf] = __builtin_amdgcn_mfma_f32_16x16x32_bf16(pa[mf], vb, oacc[mf][nf], 0, 0, 0);
        }
      }
    }
    __syncthreads();   // everyone done with Kt/Vt before next tile's staging
  }

  // ---- epilogue: per d-half, transpose through own chunk, 16B stores ----
  if (nmf > 0) {
    float rinv[8];
#pragma unroll
    for (int a = 0; a < 8; ++a) rinv[a] = 1.0f / lrun[a];
#pragma unroll
    for (int half = 0; half < 2; ++half) {
#pragma unroll
      for (int c = 0; c < 2; ++c) {
        const int nf = half * 2 + c;
        const int dloc = c * 16 + li;
#pragma unroll
        for (int mf = 0; mf < 2; ++mf)
#pragma unroll
          for (int r = 0; r < 4; ++r) {
            const int il = mf * 16 + 4 * g + r;
            float val = (mf < nmf) ? oacc[mf][nf][r] * rinv[mf * 4 + r] : 0.f;
            Pw[il * 32 + (dloc ^ (g << 3))] = f2bf(val);
          }
      }
#pragma unroll
      for (int p = 0; p < 2; ++p) {
        const int row = p * 16 + (lane >> 2);
        const int seg = lane & 3;
        const int i = 32 * w + row;
        if (i < 196) {
          const int segp = seg ^ ((row >> 2) & 3);
          v8u val = *(const v8u*)&Pw[row * 32 + segp * 8];
          *(v8u*)(out + (size_t)(win * NTOK + i) * DIMC + h * 64 + half * 32 + seg * 8) = val;
        }
      }
    }
  }
}

extern "C" void kernel_launch(void* const* d_in, const int* in_sizes, int n_in,
                              void* d_out, int out_size, void* d_ws, size_t ws_size,
                              hipStream_t stream) {
  (void)in_sizes; (void)n_in; (void)out_size; (void)ws_size;
  const float* x0     = (const float*)d_in[0];
  const float* an1_w  = (const float*)d_in[1];
  const float* an1_b  = (const float*)d_in[2];
  const float* ad1_W  = (const float*)d_in[3];
  const float* ad1_b  = (const float*)d_in[4];
  const float* ac1_W  = (const float*)d_in[5];
  const float* ac1_b  = (const float*)d_in[6];
  const float* au1_W  = (const float*)d_in[7];
  const float* au1_b  = (const float*)d_in[8];
  const float* an2_w  = (const float*)d_in[9];
  const float* an2_b  = (const float*)d_in[10];
  const float* ad2_W  = (const float*)d_in[11];
  const float* ad2_b  = (const float*)d_in[12];
  const float* ac2_W  = (const float*)d_in[13];
  const float* ac2_b  = (const float*)d_in[14];
  const float* au2_W  = (const float*)d_in[15];
  const float* au2_b  = (const float*)d_in[16];
  const float* n1_w   = (const float*)d_in[17];
  const float* n1_b   = (const float*)d_in[18];
  const float* qkv_W  = (const float*)d_in[19];
  const float* qkv_b  = (const float*)d_in[20];
  const float* facu_W = (const float*)d_in[21];
  const float* facv_W = (const float*)d_in[22];
  const float* qfac_W = (const float*)d_in[23];
  const float* vfac_W = (const float*)d_in[24];
  const float* rel_h  = (const float*)d_in[25];
  const float* rel_w  = (const float*)d_in[26];
  const float* proj_W = (const float*)d_in[27];
  const float* proj_b = (const float*)d_in[28];
  const float* n2_w   = (const float*)d_in[29];
  const float* n2_b   = (const float*)d_in[30];
  const float* mlp_W1 = (const float*)d_in[31];
  const float* mlp_b1 = (const float*)d_in[32];
  const float* mlp_W2 = (const float*)d_in[33];
  const float* mlp_b2 = (const float*)d_in[34];

  char* ws = (char*)d_ws;
  size_t off = 0;
  auto alloc = [&](size_t bytes) -> void* {
    void* p = (void*)(ws + off);
    off += (bytes + 255) & ~(size_t)255;
    return p;
  };
  u16*  bufA  = (u16*)alloc((size_t)MS * 3072 * 2);      // qkvR bf16 / mlp hidden bf16
  u16*  bufB  = (u16*)alloc((size_t)MWP * DIMC * 2);     // LN/window tokens + attn out, bf16
  float* bufX = (float*)alloc((size_t)MS * DIMC * 4);    // residual stream f32
  u16*  bufD  = (u16*)alloc((size_t)MS * ACCH * 2);      // adapter down out
  u16*  bufE  = (u16*)alloc((size_t)MS * ACCH * 2);      // adapter conv+gelu out
  u16*  Wcomb = (u16*)alloc((size_t)2304 * 768 * 2);
  u16*  Wproj = (u16*)alloc((size_t)768 * 768 * 2);
  u16*  Wm1   = (u16*)alloc((size_t)3072 * 768 * 2);
  u16*  Wm2   = (u16*)alloc((size_t)768 * 3072 * 2);
  u16*  Wad1  = (u16*)alloc((size_t)256 * 768 * 2);
  u16*  Wau1  = (u16*)alloc((size_t)768 * 192 * 2);
  u16*  Wcv1  = (u16*)alloc((size_t)256 * 5184 * 2);
  u16*  Wad2  = (u16*)alloc((size_t)256 * 768 * 2);
  u16*  Wau2  = (u16*)alloc((size_t)768 * 192 * 2);
  u16*  Wcv2  = (u16*)alloc((size_t)256 * 5184 * 2);
  float* Uq   = (float*)alloc(768 * 32 * 4);
  float* Uv   = (float*)alloc(768 * 32 * 4);
  u16*  zrow  = (u16*)alloc(256);

  // ---- weight prep (every launch; deterministic) ----
  k_zero16<<<1, 256, 0, stream>>>(zrow, 128);
  k_compute_U<<<192, 256, 0, stream>>>(facu_W, qfac_W, vfac_W, Uq, Uv);
  k_build_wcomb<<<(2304 * 768 + 255) / 256, 256, 0, stream>>>(qkv_W, Uq, Uv, facv_W, Wcomb);
  k_cast_pad<<<(768 * 768 / 4 + 255) / 256, 256, 0, stream>>>(proj_W, Wproj, 768, 768, 768);
  k_cast_pad<<<(3072 * 768 / 4 + 255) / 256, 256, 0, stream>>>(mlp_W1, Wm1, 3072, 768, 3072);
  k_cast_pad<<<(768 * 3072 / 4 + 255) / 256, 256, 0, stream>>>(mlp_W2, Wm2, 768, 3072, 768);
  k_cast_pad<<<(256 * 768 / 4 + 255) / 256, 256, 0, stream>>>(ad1_W, Wad1, 192, 768, 256);
  k_cast_pad<<<(768 * 192 / 4 + 255) / 256, 256, 0, stream>>>(au1_W, Wau1, 768, 192, 768);
  k_cast_pad<<<(256 * 768 / 4 + 255) / 256, 256, 0, stream>>>(ad2_W, Wad2, 192, 768, 256);
  k_cast_pad<<<(768 * 192 / 4 + 255) / 256, 256, 0, stream>>>(au2_W, Wau2, 768, 192, 768);
  k_conv_repack<<<(256 * 5184 / 4 + 255) / 256, 256, 0, stream>>>(ac1_W, Wcv1);
  k_conv_repack<<<(256 * 5184 / 4 + 255) / 256, 256, 0, stream>>>(ac2_W, Wcv2);

  // ---- adapter 1: x1 = x0 + up(gelu(conv(down(LN(x0))))) ----
  ln_k<false><<<MS, 256, 0, stream>>>(x0, an1_w, an1_b, bufB);
  gemm_bt<1, false, 128><<<dim3(2, 160), 256, 0, stream>>>(bufB, Wad1, ad1_b, nullptr, nullptr, bufD, MS, 192, 768, nullptr, 2);
  gemm_bt<2, true, 64><<<dim3(2, 160), 256, 0, stream>>>(bufD, Wcv1, ac1_b, nullptr, nullptr, bufE, MS, 192, 5184, zrow, 2);
  gemm_bt<3, false, 64><<<dim3(6, 160), 256, 0, stream>>>(bufE, Wau1, au1_b, x0, bufX, nullptr, MS, 768, 192, nullptr, 6);

  // ---- windowed attention ----
  ln_k<true><<<MWP, 256, 0, stream>>>(bufX, n1_w, n1_b, bufB);
  gemm_bt<4, false, 128><<<dim3(18, 192), 256, 0, stream>>>(bufB, Wcomb, qkv_b, nullptr, nullptr, bufA, MW, 2304, 768, nullptr, 6);
  attn_k<<<125 * HEADS, 512, 0, stream>>>(bufA, rel_h, rel_w, bufB);
  gemm_bt<5, false, 128><<<dim3(6, 192), 256, 0, stream>>>(bufB, Wproj, proj_b, bufX, bufX, nullptr, MW, 768, 768, nullptr, 6);

  // ---- adapter 2 ----
  ln_k<false><<<MS, 256, 0, stream>>>(bufX, an2_w, an2_b, bufB);
  gemm_bt<1, false, 128><<<dim3(2, 160), 256, 0, stream>>>(bufB, Wad2, ad2_b, nullptr, nullptr, bufD, MS, 192, 768, nullptr, 2);
  gemm_bt<2, true, 64><<<dim3(2, 160), 256, 0, stream>>>(bufD, Wcv2, ac2_b, nullptr, nullptr, bufE, MS, 192, 5184, zrow, 2);
  gemm_bt<3, false, 64><<<dim3(6, 160), 256, 0, stream>>>(bufE, Wau2, au2_b, bufX, bufX, nullptr, MS, 768, 192, nullptr, 6);

  // ---- MLP ----
  ln_k<false><<<MS, 256, 0, stream>>>(bufX, n2_w, n2_b, bufB);
  gemm_bt<2, false, 128><<<dim3(24, 160), 256, 0, stream>>>(bufB, Wm1, mlp_b1, nullptr, nullptr, bufA, MS, 3072, 768, nullptr, 8);
  gemm_bt<3, false, 128><<<dim3(6, 160), 256, 0, stream>>>(bufA, Wm2, mlp_b2, bufX, (float*)d_out, nullptr, MS, 768, 3072, nullptr, 6);
}

// Round 17
// 1028.846 us; speedup vs baseline: 1.3067x; 1.0044x over previous
//
#include <hip/hip_runtime.h>

typedef unsigned short u16;
typedef __bf16 v8bf __attribute__((ext_vector_type(8)));
typedef unsigned short v8u __attribute__((ext_vector_type(8)));
typedef unsigned short v4u __attribute__((ext_vector_type(4)));
typedef float f32x4 __attribute__((ext_vector_type(4)));
typedef float f32x16 __attribute__((ext_vector_type(16)));
typedef float v8f __attribute__((ext_vector_type(8)));

static constexpr int DIMC = 768;
static constexpr int HEADS = 12;
static constexpr int WINS  = 14;
static constexpr int ACCH  = 192;   // adapter channels
static constexpr int NTOK  = 196;   // 14*14
static constexpr int MW    = 24500; // 125 windows * 196 tokens
static constexpr int MWP   = 24576; // padded to tile multiple
static constexpr int MS    = 20480; // 5*64*64 spatial tokens

__device__ __forceinline__ float bf2f(u16 u) {
  union { unsigned int i; float f; } x; x.i = ((unsigned int)u) << 16; return x.f;
}
__device__ __forceinline__ u16 f2bf(float f) {
  union { float f; unsigned int i; } x; x.f = f;
  unsigned int r = x.i + 0x7fffu + ((x.i >> 16) & 1u);
  return (u16)(r >> 16);
}
// fast tanh-form GELU: max abs err ~2e-3 (well under threshold)
__device__ __forceinline__ float gelu_f(float x) {
  float y = 0.79788456080286536f * (x + 0.044715f * x * x * x);
  y = fminf(fmaxf(y, -15.f), 15.f);
  const float e = __expf(2.f * y);
  const float th = 1.f - 2.f * __builtin_amdgcn_rcpf(e + 1.f);
  return 0.5f * x * (1.f + th);
}
// async global->LDS, 16B per lane. LDS dest is wave-uniform base + lane*16.
__device__ __forceinline__ void cp16(const u16* g, u16* l) {
  __builtin_amdgcn_global_load_lds(
      (const __attribute__((address_space(1))) unsigned int*)(const void*)g,
      (__attribute__((address_space(3))) unsigned int*)(void*)l, 16, 0, 0);
}

// ---------------- weight prep ----------------
__global__ void k_zero16(u16* p, int n) {
  int i = blockIdx.x * 256 + threadIdx.x;
  if (i < n) p[i] = 0;
}
// U[k][b] = sum_a facu_W[a][k] * fac_W[b][a]   (fac = qfac or vfac)
__global__ void k_compute_U(const float* __restrict__ facu, const float* __restrict__ qfac,
                            const float* __restrict__ vfac, float* __restrict__ Uq,
                            float* __restrict__ Uv) {
  int idx = blockIdx.x * 256 + threadIdx.x;
  if (idx >= 2 * 768 * 32) return;
  const int which = idx / (768 * 32);
  const int rem = idx - which * 768 * 32;
  const int k = rem >> 5, b = rem & 31;
  const float* fac = which ? vfac : qfac;
  float s = 0.f;
  for (int a = 0; a < 32; ++a) s += facu[a * 768 + k] * fac[b * 32 + a];
  (which ? Uv : Uq)[rem] = s;
}
// Wc[n][k] = qkv_W[n][k] (+ sum_b U{q,v}[k][b]*facv_W[n'][b] for q/v blocks), cast bf16
__global__ void k_build_wcomb(const float* __restrict__ qkvW, const float* __restrict__ Uq,
                              const float* __restrict__ Uv, const float* __restrict__ facv,
                              u16* __restrict__ Wc) {
  int idx = blockIdx.x * 256 + threadIdx.x;
  if (idx >= 2304 * 768) return;
  const int n = idx / 768, k = idx - n * 768;
  float v = qkvW[idx];
  if (n < 768) {
    float s = 0.f;
    for (int b = 0; b < 32; ++b) s += Uq[k * 32 + b] * facv[n * 32 + b];
    v += s;
  } else if (n >= 1536) {
    const int nn = n - 1536;
    float s = 0.f;
    for (int b = 0; b < 32; ++b) s += Uv[k * 32 + b] * facv[nn * 32 + b];
    v += s;
  }
  Wc[idx] = f2bf(v);
}
// vectorized cast+pad: 4 elems/thread (cols % 4 == 0 so a group shares its row)
__global__ void k_cast_pad(const float* __restrict__ src, u16* __restrict__ dst,
                           int rows, int cols, int rowsPad) {
  int idx = blockIdx.x * 256 + threadIdx.x;
  const int base = idx * 4;
  if (base >= rowsPad * cols) return;
  const int r = base / cols;
  v4u o;
  if (r < rows) {
    const float4 v = *(const float4*)(src + base);
    o[0] = f2bf(v.x); o[1] = f2bf(v.y); o[2] = f2bf(v.z); o[3] = f2bf(v.w);
  } else {
    o[0] = o[1] = o[2] = o[3] = 0;
  }
  *(v4u*)(dst + base) = o;
}
// ac_W [192][192][3][3][3] -> Wconv [256 pad][27*192] with k = tap*192+ci  (4 ci/thread)
__global__ void k_conv_repack(const float* __restrict__ src, u16* __restrict__ dst) {
  int idx = blockIdx.x * 256 + threadIdx.x;
  const int base = idx * 4;
  if (base >= 256 * 5184) return;
  const int co = base / 5184;
  const int rem = base - co * 5184;
  const int tap = rem / 192, ci = rem - tap * 192;   // ci % 4 == 0 (192 % 4 == 0)
  v4u o;
  if (co < 192) {
    const float* sp = src + co * 5184 + ci * 27 + tap;
#pragma unroll
    for (int e = 0; e < 4; ++e) o[e] = f2bf(sp[e * 27]);
  } else {
    o[0] = o[1] = o[2] = o[3] = 0;
  }
  *(v4u*)(dst + base) = o;
}

// ---------------- LayerNorm (optionally fused window-partition) ----------------
template<bool WINDOWED>
__global__ __launch_bounds__(256)
void ln_k(const float* __restrict__ X, const float* __restrict__ w,
          const float* __restrict__ b, u16* __restrict__ out) {
  const int r = (int)blockIdx.x;
  const int t = (int)threadIdx.x;
  int src = r;
  bool zero = false;
  if (WINDOWED) {
    if (r >= MW) zero = true;
    else {
      const int win = r / NTOK, tk = r - win * NTOK;
      const int img = win / 25, wrem = win - img * 25, wy = wrem / 5, wx = wrem - wy * 5;
      const int ty = tk / WINS, tx = tk - ty * WINS;
      const int y = wy * WINS + ty, x = wx * WINS + tx;
      if (y >= 64 || x >= 64) zero = true;
      else src = (img << 12) + (y << 6) + x;
    }
  }
  u16* orow = out + (size_t)r * DIMC;
  if (zero) {
    for (int c = t; c < DIMC; c += 256) orow[c] = 0;
    return;
  }
  const float* xr = X + (size_t)src * DIMC;
  const float v0 = xr[t], v1 = xr[t + 256], v2 = xr[t + 512];
  float s = v0 + v1 + v2, ss = v0 * v0 + v1 * v1 + v2 * v2;
#pragma unroll
  for (int o = 32; o > 0; o >>= 1) { s += __shfl_xor(s, o, 64); ss += __shfl_xor(ss, o, 64); }
  __shared__ float red[8];
  const int wave = t >> 6, lane = t & 63;
  if (lane == 0) { red[wave] = s; red[4 + wave] = ss; }
  __syncthreads();
  s = red[0] + red[1] + red[2] + red[3];
  ss = red[4] + red[5] + red[6] + red[7];
  const float mean = s * (1.0f / 768.0f);
  const float var = ss * (1.0f / 768.0f) - mean * mean;
  const float rstd = rsqrtf(var + 1e-5f);
  orow[t]       = f2bf((v0 - mean) * rstd * w[t]       + b[t]);
  orow[t + 256] = f2bf((v1 - mean) * rstd * w[t + 256] + b[t + 256]);
  orow[t + 512] = f2bf((v2 - mean) * rstd * w[t + 512] + b[t + 512]);
}

// ---------------- GEMM: C[M,N] = A[M,K] @ B[N,K]^T (+bias, epilogues) ----------------
// EPI: 1 = bf16 out (bias); 2 = bf16 out (bias+GELU); 3 = f32 out (bias+residual);
//      4 = bf16 qkv-scatter per (win,head); 5 = f32 window-unpartition + in-place resid add
// CONV: A rows gathered as 3x3x3 SAME conv over [5][64][64][192]; K = tap*192+ci (BK=64 only)
// BK=64: 16x16x32 MFMA. BK=128: 32x32x16 MFMA (half the MFMA instrs, ~15% faster pipe),
//        LDS 64 KB, same 2 blk/CU. Swizzle: store chunk c at phys c^(row&15) (BK=128).
// Block swizzle: XCD-chunked + bn-grouping GN. Epilogue: LDS-staged vectorized stores.
template<int EPI, bool CONV, int BK>
__global__ __launch_bounds__(256)
void gemm_bt(const u16* __restrict__ A, const u16* __restrict__ B,
             const float* __restrict__ bias, const float* __restrict__ resid,
             float* __restrict__ outF, u16* __restrict__ outB,
             int M, int N, int K, const u16* __restrict__ zrow, int GN) {
  __shared__ u16 smem[2 * 128 * BK];
  u16* At = smem;
  u16* Bt = smem + 128 * BK;
  const int gx = (int)gridDim.x;
  const int nwg = gx * (int)gridDim.y;
  const int lin = (int)blockIdx.y * gx + (int)blockIdx.x;
  const int csz = nwg >> 3;            // blocks per XCD chunk
  const int xcd = lin & 7;
  const int c = lin >> 3;              // position within chunk
  const int bmc = csz / gx;            // bm rows per chunk
  const int gsz = bmc * GN;
  const int grp = c / gsz, rr = c - grp * gsz;
  const int bn = grp * GN + (rr % GN);
  const int bm = xcd * bmc + (rr / GN);
  const int t = (int)threadIdx.x;
  const int wave = t >> 6, lane = t & 63;
  const int wm = wave >> 1, wn = wave & 1;
  const int li = lane & 15, lq = lane >> 4;
  const int l31 = lane & 31, lh = lane >> 5;

  f32x4 acc[4][4];        // BK==64 accumulators (16x16 blocks)
  f32x16 acc32[2][2];     // BK==128 accumulators (32x32 blocks)
  const f32x4 vzero = {0.f, 0.f, 0.f, 0.f};
  if (BK == 64) {
#pragma unroll
    for (int a = 0; a < 4; ++a)
#pragma unroll
      for (int b = 0; b < 4; ++b) acc[a][b] = vzero;
  } else {
#pragma unroll
    for (int a = 0; a < 2; ++a)
#pragma unroll
      for (int b = 0; b < 2; ++b)
#pragma unroll
        for (int e = 0; e < 16; ++e) acc32[a][b][e] = 0.f;
  }

  const int nk = K / BK;
  for (int kt = 0; kt < nk; ++kt) {
    if (BK == 64) {
      const int lrow = lane >> 3;                // 0..7
      const int c16s = (lane & 7) ^ lrow;        // pre-swizzled source chunk
      int cD = 0, cY = 0, cX = 0, cblk = 0;
      if (CONV) {
        const int tap = kt / 3;
        cblk = (kt - tap * 3) << 6;
        const int kd = tap / 9, r9 = tap - kd * 9, ky = r9 / 3;
        cD = kd - 1; cY = ky - 1; cX = (r9 - ky * 3) - 1;
      }
#pragma unroll
      for (int i = 0; i < 4; ++i) {           // stage A: 128x64 bf16
        const int r0 = i * 32 + wave * 8;
        const int grow = bm * 128 + r0 + lrow;
        const u16* src;
        if (CONV) {
          const int d = (grow >> 12) + cD, y = ((grow >> 6) & 63) + cY, x = (grow & 63) + cX;
          if ((unsigned)d < 5u && (unsigned)y < 64u && (unsigned)x < 64u)
            src = A + (size_t)((d << 12) + (y << 6) + x) * ACCH + cblk + c16s * 8;
          else
            src = zrow + c16s * 8;
        } else {
          src = A + (size_t)grow * K + (kt << 6) + c16s * 8;
        }
        cp16(src, &At[r0 * 64]);
      }
#pragma unroll
      for (int i = 0; i < 4; ++i) {           // stage B: 128x64 bf16
        const int r0 = i * 32 + wave * 8;
        const int grow = bn * 128 + r0 + lrow;
        cp16(B + (size_t)grow * K + (kt << 6) + c16s * 8, &Bt[r0 * 64]);
      }
    } else {  // BK == 128: rows of 16 chunks; store chunk c at phys c^(row&15)
      const int srow4 = lane >> 4;               // 0..3 (4 rows per cp16)
      const int sc = lane & 15;                  // phys chunk
#pragma unroll
      for (int i = 0; i < 8; ++i) {           // stage A: 128x128 bf16
        const int rbase = i * 16 + wave * 4;
        const int row = rbase + srow4;
        const int c16s = sc ^ (row & 15);        // logical source chunk
        cp16(A + (size_t)(bm * 128 + row) * K + kt * 128 + c16s * 8, &At[rbase * 128]);
      }
#pragma unroll
      for (int i = 0; i < 8; ++i) {           // stage B: 128x128 bf16
        const int rbase = i * 16 + wave * 4;
        const int row = rbase + srow4;
        const int c16s = sc ^ (row & 15);
        cp16(B + (size_t)(bn * 128 + row) * K + kt * 128 + c16s * 8, &Bt[rbase * 128]);
      }
    }
    __syncthreads();                         // drains vmcnt for global_load_lds
    if (BK == 64) {
#pragma unroll
      for (int kk = 0; kk < 2; ++kk) {
        v8bf af[4], bg[4];
#pragma unroll
        for (int mf = 0; mf < 4; ++mf) {
          const int row = wm * 64 + mf * 16 + li;
          const int c16 = (kk * 4 + lq) ^ (li & 7);
          af[mf] = *(const v8bf*)&At[row * 64 + c16 * 8];
        }
#pragma unroll
        for (int nf = 0; nf < 4; ++nf) {
          const int row = wn * 64 + nf * 16 + li;
          const int c16 = (kk * 4 + lq) ^ (li & 7);
          bg[nf] = *(const v8bf*)&Bt[row * 64 + c16 * 8];
        }
#pragma unroll
        for (int mf = 0; mf < 4; ++mf)
#pragma unroll
          for (int nf = 0; nf < 4; ++nf)
            acc[mf][nf] = __builtin_amdgcn_mfma_f32_16x16x32_bf16(af[mf], bg[nf], acc[mf][nf], 0, 0, 0);
      }
    } else {  // 32x32x16: lane holds A[row=l31][k=lh*8+e]; same mapping for B
#pragma unroll
      for (int kk = 0; kk < 8; ++kk) {
        const int ch = kk * 2 + lh;              // logical chunk (8 k-elems)
        v8bf a2[2], b2[2];
#pragma unroll
        for (int mb = 0; mb < 2; ++mb) {
          const int row = wm * 64 + mb * 32 + l31;
          a2[mb] = *(const v8bf*)&At[row * 128 + (ch ^ (row & 15)) * 8];
        }
#pragma unroll
        for (int nb = 0; nb < 2; ++nb) {
          const int row = wn * 64 + nb * 32 + l31;
          b2[nb] = *(const v8bf*)&Bt[row * 128 + (ch ^ (row & 15)) * 8];
        }
#pragma unroll
        for (int mb = 0; mb < 2; ++mb)
#pragma unroll
          for (int nb = 0; nb < 2; ++nb)
            acc32[mb][nb] = __builtin_amdgcn_mfma_f32_32x32x16_bf16(a2[mb], b2[nb], acc32[mb][nb], 0, 0, 0);
      }
    }
    __syncthreads();
  }

  // ---- epilogue: stage C through LDS, vectorized stores ----
  // 32x32 C/D mapping: col = lane&31, row = (reg&3) + 8*(reg>>2) + 4*(lane>>5)
  if (EPI == 1 || EPI == 2 || EPI == 4) {
    u16* Ct = smem;  // [128][128] bf16, col ^ ((row&7)<<3)
    if (BK == 64) {
#pragma unroll
      for (int mf = 0; mf < 4; ++mf)
#pragma unroll
        for (int nf = 0; nf < 4; ++nf)
#pragma unroll
          for (int r = 0; r < 4; ++r) {
            const int row = wm * 64 + mf * 16 + lq * 4 + r;
            const int col = wn * 64 + nf * 16 + li;
            float v = acc[mf][nf][r] + bias[bn * 128 + col];
            if (EPI == 2) v = gelu_f(v);
            Ct[row * 128 + (col ^ ((row & 7) << 3))] = f2bf(v);
          }
    } else {
#pragma unroll
      for (int mb = 0; mb < 2; ++mb)
#pragma unroll
        for (int nb = 0; nb < 2; ++nb)
#pragma unroll
          for (int rg = 0; rg < 16; ++rg) {
            const int row = wm * 64 + mb * 32 + (rg & 3) + 8 * (rg >> 2) + 4 * lh;
            const int col = wn * 64 + nb * 32 + l31;
            float v = acc32[mb][nb][rg] + bias[bn * 128 + col];
            if (EPI == 2) v = gelu_f(v);
            Ct[row * 128 + (col ^ ((row & 7) << 3))] = f2bf(v);
          }
    }
    __syncthreads();
#pragma unroll
    for (int it = 0; it < 8; ++it) {
      const int row = it * 16 + (t >> 4);
      const int seg = t & 15;
      const int gr = bm * 128 + row;
      const int col8 = bn * 128 + seg * 8;
      if (gr < M && col8 < N) {
        v8u val = *(const v8u*)&Ct[row * 128 + ((seg ^ (row & 7)) * 8)];
        if (EPI == 4) {
          const int sec = col8 / 768;
          const int hm = col8 - sec * 768;
          const int hd = hm >> 6, dd = hm & 63;
          const int win = gr / 196, tk = gr - win * 196;
          *(v8u*)(outB + (size_t)(((win * HEADS + hd) * 3 + sec) * NTOK + tk) * 64 + dd) = val;
        } else {
          *(v8u*)(outB + (size_t)gr * N + col8) = val;
        }
      }
    }
  } else {  // EPI 3 / 5: f32, two wm-halves through [64][128] f32 tile
    float* Cf = (float*)smem;
#pragma unroll
    for (int h2 = 0; h2 < 2; ++h2) {
      if (h2) __syncthreads();               // half-0 reads done before overwrite
      if (wm == h2) {
        if (BK == 64) {
#pragma unroll
          for (int mf = 0; mf < 4; ++mf)
#pragma unroll
            for (int nf = 0; nf < 4; ++nf)
#pragma unroll
              for (int r = 0; r < 4; ++r) {
                const int row = mf * 16 + lq * 4 + r;      // 0..63 within half
                const int col = wn * 64 + nf * 16 + li;
                const float v = acc[mf][nf][r] + bias[bn * 128 + col];
                Cf[row * 128 + (col ^ (((row >> 2) & 3) << 3))] = v;
              }
        } else {
#pragma unroll
          for (int mb = 0; mb < 2; ++mb)
#pragma unroll
            for (int nb = 0; nb < 2; ++nb)
#pragma unroll
              for (int rg = 0; rg < 16; ++rg) {
                const int row = mb * 32 + (rg & 3) + 8 * (rg >> 2) + 4 * lh;  // 0..63
                const int col = wn * 64 + nb * 32 + l31;
                const float v = acc32[mb][nb][rg] + bias[bn * 128 + col];
                Cf[row * 128 + (col ^ (((row >> 2) & 3) << 3))] = v;
              }
        }
      }
      __syncthreads();
#pragma unroll
      for (int it = 0; it < 4; ++it) {
        const int row = it * 16 + (t >> 4);              // 0..63
        const int seg = t & 15;
        const int gr = bm * 128 + h2 * 64 + row;
        const int col8 = bn * 128 + seg * 8;
        if (gr < M && col8 < N) {
          v8f val = *(const v8f*)&Cf[row * 128 + ((seg ^ ((row >> 2) & 3)) * 8)];
          if (EPI == 3) {
            const float* rp = resid + (size_t)gr * N + col8;
#pragma unroll
            for (int e = 0; e < 8; ++e) val[e] += rp[e];
            *(v8f*)(outF + (size_t)gr * N + col8) = val;
          } else {  // EPI 5: window-unpartition + in-place residual add
            const int win = gr / 196, tk = gr - win * 196;
            const int img = win / 25, wrem = win - img * 25, wy = wrem / 5, wx = wrem - wy * 5;
            const int ty = tk / WINS, tx = tk - ty * WINS;
            const int y = wy * WINS + ty, x = wx * WINS + tx;
            if (y < 64 && x < 64) {
              const size_t o = (size_t)((img << 12) + (y << 6) + x) * DIMC + col8;
              const float* rp = resid + o;
#pragma unroll
              for (int e = 0; e < 8; ++e) val[e] += rp[e];
              *(v8f*)(outF + o) = val;
            }
          }
        }
      }
    }
  }
}

// ---------------- fused windowed attention, MFMA flash-style, 8 waves ----------------
// block = (win, head), 512 threads; wave w owns q-rows [32w, 32w+32).
// Q held in REGISTERS (qf[2][2], one-time global loads) -> LDS 47 KB.
// qkvR layout per (win,head): [Q(196x64) | K(196x64) | V(196x64)]
__global__ __launch_bounds__(512, 2)
void attn_k(const u16* __restrict__ qkvR, const float* __restrict__ relh,
            const float* __restrict__ relw, u16* __restrict__ out) {
  const int blk = (int)blockIdx.x;
  const int win = blk / HEADS, h = blk - win * HEADS;
  const int t = (int)threadIdx.x, w = t >> 6, lane = t & 63;
  const int li = lane & 15, g = lane >> 4;
  const int nmf = (w < 6) ? 2 : (w == 6 ? 1 : 0);   // valid 16-row fragments this wave

  __shared__ u16 Kt[64 * 64];     // 8 KB [j][d], swizzled (cp16 linear dest)
  __shared__ u16 Vt[64 * 64];     // 8 KB [d][j], seg-XOR swizzled
  __shared__ u16 Pb[8 * 32 * 32]; // 16 KB per-wave P/O chunks; aliases rel buf in phase A
  __shared__ u16 dhwT[28 * 268];  // 15 KB: rows 0..13 = dh[jh][i], 14..27 = dw[jw][i]

  const u16* Qb = qkvR + (size_t)(win * HEADS + h) * 3 * NTOK * 64;
  const u16* Kb = Qb + NTOK * 64;
  const u16* Vb = Kb + NTOK * 64;

  // ---- Q fragments in registers: qf[mf][ks], rows clamped to 195 ----
  v8bf qf[2][2];
#pragma unroll
  for (int mf = 0; mf < 2; ++mf) {
    const int row = min(32 * w + mf * 16 + li, NTOK - 1);
#pragma unroll
    for (int ks = 0; ks < 2; ++ks)
      qf[mf][ks] = *(const v8bf*)(Qb + (size_t)row * 64 + ks * 32 + g * 8);
  }

  // ---- stage rel tables into Pb (phase-A alias) ----
  u16* relb = Pb; // [2][32 rows][64 cols], swizzled like Kt
  for (int idx = t; idx < 2 * 32 * 64; idx += 512) {
    const int which = idx >> 11, rem = idx & 2047, r = rem >> 6, c = rem & 63;
    const float v = (r < 27) ? (which ? relw[r * 64 + c] : relh[r * 64 + c]) : 0.f;
    relb[which * 2048 + r * 64 + (((c >> 3) ^ (r & 7)) * 8) + (c & 7)] = f2bf(v);
  }
  __syncthreads();

  // ---- phase A: rel-pos tables via MFMA (Q from registers), scatter into dhwT ----
  {
    f32x4 dacc[2][2], eacc[2][2];
    const f32x4 vz = {0.f, 0.f, 0.f, 0.f};
#pragma unroll
    for (int mf = 0; mf < 2; ++mf)
#pragma unroll
      for (int nf = 0; nf < 2; ++nf) { dacc[mf][nf] = vz; eacc[mf][nf] = vz; }
#pragma unroll
    for (int ks = 0; ks < 2; ++ks) {
#pragma unroll
      for (int nf = 0; nf < 2; ++nf) {
        const int row = nf * 16 + li;
        const int off = row * 64 + (((ks * 4 + g) ^ (li & 7)) * 8);
        v8bf bh = *(const v8bf*)&relb[off];
        v8bf bw = *(const v8bf*)&relb[2048 + off];
#pragma unroll
        for (int mf = 0; mf < 2; ++mf) if (mf < nmf) {
          dacc[mf][nf] = __builtin_amdgcn_mfma_f32_16x16x32_bf16(qf[mf][ks], bh, dacc[mf][nf], 0, 0, 0);
          eacc[mf][nf] = __builtin_amdgcn_mfma_f32_16x16x32_bf16(qf[mf][ks], bw, eacc[mf][nf], 0, 0, 0);
        }
      }
    }
    // scatter D,E -> dhwT[jh][i] / dhwT[14+jw][i] (bijective per row)
#pragma unroll
    for (int mf = 0; mf < 2; ++mf) if (mf < nmf)
#pragma unroll
      for (int nf = 0; nf < 2; ++nf)
#pragma unroll
        for (int r = 0; r < 4; ++r) {
          const int i = 32 * w + mf * 16 + 4 * g + r;
          if (i < 196) {
            const int c = nf * 16 + li;
            const int ih = (i * 2341) >> 15, iw = i - ih * 14;
            const int jh = ih + 13 - c;
            if ((unsigned)jh < 14u) dhwT[jh * 268 + i] = f2bf(dacc[mf][nf][r]);
            const int jw = iw + 13 - c;
            if ((unsigned)jw < 14u) dhwT[(14 + jw) * 268 + i] = f2bf(eacc[mf][nf][r]);
          }
        }
  }
  __syncthreads();   // phase-A reads of relb done; Pb free for P chunks

  // ---- phase B: flash over 4 j-tiles of 64 ----
  f32x4 oacc[2][4];
  const f32x4 vz = {0.f, 0.f, 0.f, 0.f};
#pragma unroll
  for (int a = 0; a < 2; ++a)
#pragma unroll
    for (int b = 0; b < 4; ++b) oacc[a][b] = vz;
  float mrun[8], lrun[8];
#pragma unroll
  for (int a = 0; a < 8; ++a) { mrun[a] = -1e30f; lrun[a] = 0.f; }

  u16* Pw = Pb + w * 1024; // own chunk [32 i][32 j]
  const int jv = t & 63;   // V-staging: column j
  const int dv = w * 8;    // V-staging: 8-d slab

  for (int jt = 0; jt < 4; ++jt) {
    const int j0 = jt * 64;
    const int njf = (jt < 3) ? 4 : 1;    // valid 16-col j-fragments
    const int nhalf = (jt < 3) ? 2 : 1;  // valid 32-col PV halves

    // stage K FIRST (oldest vm op): 8 waves x 8 rows = 64 rows, one cp16 each
    {
      const int rbase = w * 8;
      const int row = rbase + (lane >> 3);
      const int jg = min(j0 + row, NTOK - 1);
      const int cbs = (lane & 7) ^ (row & 7);
      cp16(Kb + (size_t)jg * 64 + cbs * 8, &Kt[rbase * 64]);
    }
    __builtin_amdgcn_sched_barrier(0);       // pin: K issued before V
    // V prefetch into regs (newest vm op; rides through the K wait)
    const int jgv = min(j0 + jv, NTOK - 1);
    v8u vg = *(const v8u*)(Vb + (size_t)jgv * 64 + dv);
    __builtin_amdgcn_sched_barrier(0);
    asm volatile("s_waitcnt vmcnt(1)" ::: "memory");   // K landed; V still in flight
    __builtin_amdgcn_sched_barrier(0);
    __builtin_amdgcn_s_barrier();            // Kt visible to all waves
    __builtin_amdgcn_sched_barrier(0);

    // QK^T (Q from registers) — V latency hides under this
    f32x4 sacc[2][4];
#pragma unroll
    for (int a = 0; a < 2; ++a)
#pragma unroll
      for (int b = 0; b < 4; ++b) sacc[a][b] = vz;
    if (nmf > 0) {
#pragma unroll
      for (int ks = 0; ks < 2; ++ks) {
#pragma unroll
        for (int jf = 0; jf < 4; ++jf) if (jf < njf) {
          const int row = jf * 16 + li;
          v8bf kb = *(const v8bf*)&Kt[row * 64 + (((ks * 4 + g) ^ (li & 7)) * 8)];
#pragma unroll
          for (int mf = 0; mf < 2; ++mf) if (mf < nmf)
            sacc[mf][jf] = __builtin_amdgcn_mfma_f32_16x16x32_bf16(qf[mf][ks], kb, sacc[mf][jf], 0, 0, 0);
        }
      }
    }

    // V regs -> Vt (seg-XOR swizzled); visible to all waves at the pre-PV barrier
    asm volatile("s_waitcnt vmcnt(0)" ::: "memory");
    __builtin_amdgcn_sched_barrier(0);
#pragma unroll
    for (int e = 0; e < 8; ++e) {
      const int da = dv + e;
      Vt[da * 64 + (((jv >> 3) ^ (da & 7)) * 8) + (jv & 7)] = vg[e];
    }

    // bias + mask (vectorized b64 reads from dhwT)
#pragma unroll
    for (int jf = 0; jf < 4; ++jf) if (jf < njf) {
      const int j = j0 + jf * 16 + li;
      const bool jok = j < 196;
      int jh = (j * 2341) >> 15;
      const int jw = j - jh * 14;
      if (jh > 13) jh = 13;                  // clamp for padded j (masked below)
#pragma unroll
      for (int mf = 0; mf < 2; ++mf) if (mf < nmf) {
        const int i0 = 32 * w + mf * 16 + 4 * g;
        v4u hv = *(const v4u*)&dhwT[jh * 268 + i0];
        v4u wv = *(const v4u*)&dhwT[(14 + jw) * 268 + i0];
#pragma unroll
        for (int r = 0; r < 4; ++r) {
          float v;
          if (jok && (i0 + r) < 196)
            v = sacc[mf][jf][r] * 0.125f + bf2f(hv[r]) + bf2f(wv[r]);
          else v = -1e30f;
          sacc[mf][jf][r] = v;
        }
      }
    }

    // online softmax update
#pragma unroll
    for (int mf = 0; mf < 2; ++mf) if (mf < nmf)
#pragma unroll
      for (int r = 0; r < 4; ++r) {
        float tmx = -1e30f;
#pragma unroll
        for (int jf = 0; jf < 4; ++jf) if (jf < njf) tmx = fmaxf(tmx, sacc[mf][jf][r]);
#pragma unroll
        for (int o = 1; o < 16; o <<= 1) tmx = fmaxf(tmx, __shfl_xor(tmx, o, 16));
        const int idx = mf * 4 + r;
        const float mnew = fmaxf(mrun[idx], tmx);
        const float sf = __expf(mrun[idx] - mnew);
        mrun[idx] = mnew;
        float ls = 0.f;
#pragma unroll
        for (int jf = 0; jf < 4; ++jf) if (jf < njf) {
          const float p = __expf(sacc[mf][jf][r] - mnew);
          sacc[mf][jf][r] = p;
          ls += p;
        }
#pragma unroll
        for (int o = 1; o < 16; o <<= 1) ls += __shfl_xor(ls, o, 16);
        lrun[idx] = lrun[idx] * sf + ls;
#pragma unroll
        for (int nf = 0; nf < 4; ++nf) oacc[mf][nf][r] *= sf;
      }

    // P chunks (32i x 32j per half) -> PV, two halves; own-wave lgkm ordering
#pragma unroll
    for (int half = 0; half < 2; ++half) if (half < nhalf) {
#pragma unroll
      for (int c = 0; c < 2; ++c) {
        const int jf = half * 2 + c;
        const int jloc = c * 16 + li;
#pragma unroll
        for (int mf = 0; mf < 2; ++mf)
#pragma unroll
          for (int r = 0; r < 4; ++r) {
            const int il = mf * 16 + 4 * g + r;
            u16 pv = 0;
            if (mf < nmf && jf < njf) pv = f2bf(sacc[mf][jf][r]);
            Pw[il * 32 + (jloc ^ (g << 3))] = pv;
          }
      }
      if (half == 0) __syncthreads();        // Vt (all waves) + own P visible before PV
      // PV: O[i][d] += P[i][j-half] * V[j-half][d]   (K = 32 -> one MFMA per (mf,nf))
      if (nmf > 0) {
        v8bf pa[2];
#pragma unroll
        for (int mf = 0; mf < 2; ++mf) {
          const int row = mf * 16 + li;
          pa[mf] = *(const v8bf*)&Pw[row * 32 + ((g ^ ((li >> 2) & 3)) * 8)];
        }
#pragma unroll
        for (int nf = 0; nf < 4; ++nf) {
          const int d = nf * 16 + li;
          v8bf vb = *(const v8bf*)&Vt[d * 64 + (((half * 4 + g) ^ (li & 7)) * 8)];
#pragma unroll
          for (int mf = 0; mf < 2; ++mf)
            oacc[mf][nf] = __builtin_amdgcn_mfma_f32_16x16x32_bf16(pa[mf], vb, oacc[mf][nf], 0, 0, 0);
        }
      }
    }
    __syncthreads();   // everyone done with Kt/Vt before next tile's staging
  }

  // ---- epilogue: per d-half, transpose through own chunk, 16B stores ----
  if (nmf > 0) {
    float rinv[8];
#pragma unroll
    for (int a = 0; a < 8; ++a) rinv[a] = 1.0f / lrun[a];
#pragma unroll
    for (int half = 0; half < 2; ++half) {
#pragma unroll
      for (int c = 0; c < 2; ++c) {
        const int nf = half * 2 + c;
        const int dloc = c * 16 + li;
#pragma unroll
        for (int mf = 0; mf < 2; ++mf)
#pragma unroll
          for (int r = 0; r < 4; ++r) {
            const int il = mf * 16 + 4 * g + r;
            float val = (mf < nmf) ? oacc[mf][nf][r] * rinv[mf * 4 + r] : 0.f;
            Pw[il * 32 + (dloc ^ (g << 3))] = f2bf(val);
          }
      }
#pragma unroll
      for (int p = 0; p < 2; ++p) {
        const int row = p * 16 + (lane >> 2);
        const int seg = lane & 3;
        const int i = 32 * w + row;
        if (i < 196) {
          const int segp = seg ^ ((row >> 2) & 3);
          v8u val = *(const v8u*)&Pw[row * 32 + segp * 8];
          *(v8u*)(out + (size_t)(win * NTOK + i) * DIMC + h * 64 + half * 32 + seg * 8) = val;
        }
      }
    }
  }
}

extern "C" void kernel_launch(void* const* d_in, const int* in_sizes, int n_in,
                              void* d_out, int out_size, void* d_ws, size_t ws_size,
                              hipStream_t stream) {
  (void)in_sizes; (void)n_in; (void)out_size; (void)ws_size;
  const float* x0     = (const float*)d_in[0];
  const float* an1_w  = (const float*)d_in[1];
  const float* an1_b  = (const float*)d_in[2];
  const float* ad1_W  = (const float*)d_in[3];
  const float* ad1_b  = (const float*)d_in[4];
  const float* ac1_W  = (const float*)d_in[5];
  const float* ac1_b  = (const float*)d_in[6];
  const float* au1_W  = (const float*)d_in[7];
  const float* au1_b  = (const float*)d_in[8];
  const float* an2_w  = (const float*)d_in[9];
  const float* an2_b  = (const float*)d_in[10];
  const float* ad2_W  = (const float*)d_in[11];
  const float* ad2_b  = (const float*)d_in[12];
  const float* ac2_W  = (const float*)d_in[13];
  const float* ac2_b  = (const float*)d_in[14];
  const float* au2_W  = (const float*)d_in[15];
  const float* au2_b  = (const float*)d_in[16];
  const float* n1_w   = (const float*)d_in[17];
  const float* n1_b   = (const float*)d_in[18];
  const float* qkv_W  = (const float*)d_in[19];
  const float* qkv_b  = (const float*)d_in[20];
  const float* facu_W = (const float*)d_in[21];
  const float* facv_W = (const float*)d_in[22];
  const float* qfac_W = (const float*)d_in[23];
  const float* vfac_W = (const float*)d_in[24];
  const float* rel_h  = (const float*)d_in[25];
  const float* rel_w  = (const float*)d_in[26];
  const float* proj_W = (const float*)d_in[27];
  const float* proj_b = (const float*)d_in[28];
  const float* n2_w   = (const float*)d_in[29];
  const float* n2_b   = (const float*)d_in[30];
  const float* mlp_W1 = (const float*)d_in[31];
  const float* mlp_b1 = (const float*)d_in[32];
  const float* mlp_W2 = (const float*)d_in[33];
  const float* mlp_b2 = (const float*)d_in[34];

  char* ws = (char*)d_ws;
  size_t off = 0;
  auto alloc = [&](size_t bytes) -> void* {
    void* p = (void*)(ws + off);
    off += (bytes + 255) & ~(size_t)255;
    return p;
  };
  u16*  bufA  = (u16*)alloc((size_t)MS * 3072 * 2);      // qkvR bf16 / mlp hidden bf16
  u16*  bufB  = (u16*)alloc((size_t)MWP * DIMC * 2);     // LN/window tokens + attn out, bf16
  float* bufX = (float*)alloc((size_t)MS * DIMC * 4);    // residual stream f32
  u16*  bufD  = (u16*)alloc((size_t)MS * ACCH * 2);      // adapter down out
  u16*  bufE  = (u16*)alloc((size_t)MS * ACCH * 2);      // adapter conv+gelu out
  u16*  Wcomb = (u16*)alloc((size_t)2304 * 768 * 2);
  u16*  Wproj = (u16*)alloc((size_t)768 * 768 * 2);
  u16*  Wm1   = (u16*)alloc((size_t)3072 * 768 * 2);
  u16*  Wm2   = (u16*)alloc((size_t)768 * 3072 * 2);
  u16*  Wad1  = (u16*)alloc((size_t)256 * 768 * 2);
  u16*  Wau1  = (u16*)alloc((size_t)768 * 192 * 2);
  u16*  Wcv1  = (u16*)alloc((size_t)256 * 5184 * 2);
  u16*  Wad2  = (u16*)alloc((size_t)256 * 768 * 2);
  u16*  Wau2  = (u16*)alloc((size_t)768 * 192 * 2);
  u16*  Wcv2  = (u16*)alloc((size_t)256 * 5184 * 2);
  float* Uq   = (float*)alloc(768 * 32 * 4);
  float* Uv   = (float*)alloc(768 * 32 * 4);
  u16*  zrow  = (u16*)alloc(256);

  // ---- weight prep (every launch; deterministic) ----
  k_zero16<<<1, 256, 0, stream>>>(zrow, 128);
  k_compute_U<<<192, 256, 0, stream>>>(facu_W, qfac_W, vfac_W, Uq, Uv);
  k_build_wcomb<<<(2304 * 768 + 255) / 256, 256, 0, stream>>>(qkv_W, Uq, Uv, facv_W, Wcomb);
  k_cast_pad<<<(768 * 768 / 4 + 255) / 256, 256, 0, stream>>>(proj_W, Wproj, 768, 768, 768);
  k_cast_pad<<<(3072 * 768 / 4 + 255) / 256, 256, 0, stream>>>(mlp_W1, Wm1, 3072, 768, 3072);
  k_cast_pad<<<(768 * 3072 / 4 + 255) / 256, 256, 0, stream>>>(mlp_W2, Wm2, 768, 3072, 768);
  k_cast_pad<<<(256 * 768 / 4 + 255) / 256, 256, 0, stream>>>(ad1_W, Wad1, 192, 768, 256);
  k_cast_pad<<<(768 * 192 / 4 + 255) / 256, 256, 0, stream>>>(au1_W, Wau1, 768, 192, 768);
  k_cast_pad<<<(256 * 768 / 4 + 255) / 256, 256, 0, stream>>>(ad2_W, Wad2, 192, 768, 256);
  k_cast_pad<<<(768 * 192 / 4 + 255) / 256, 256, 0, stream>>>(au2_W, Wau2, 768, 192, 768);
  k_conv_repack<<<(256 * 5184 / 4 + 255) / 256, 256, 0, stream>>>(ac1_W, Wcv1);
  k_conv_repack<<<(256 * 5184 / 4 + 255) / 256, 256, 0, stream>>>(ac2_W, Wcv2);

  // ---- adapter 1: x1 = x0 + up(gelu(conv(down(LN(x0))))) ----
  ln_k<false><<<MS, 256, 0, stream>>>(x0, an1_w, an1_b, bufB);
  gemm_bt<1, false, 128><<<dim3(2, 160), 256, 0, stream>>>(bufB, Wad1, ad1_b, nullptr, nullptr, bufD, MS, 192, 768, nullptr, 2);
  gemm_bt<2, true, 64><<<dim3(2, 160), 256, 0, stream>>>(bufD, Wcv1, ac1_b, nullptr, nullptr, bufE, MS, 192, 5184, zrow, 2);
  gemm_bt<3, false, 64><<<dim3(6, 160), 256, 0, stream>>>(bufE, Wau1, au1_b, x0, bufX, nullptr, MS, 768, 192, nullptr, 6);

  // ---- windowed attention ----
  ln_k<true><<<MWP, 256, 0, stream>>>(bufX, n1_w, n1_b, bufB);
  gemm_bt<4, false, 128><<<dim3(18, 192), 256, 0, stream>>>(bufB, Wcomb, qkv_b, nullptr, nullptr, bufA, MW, 2304, 768, nullptr, 6);
  attn_k<<<125 * HEADS, 512, 0, stream>>>(bufA, rel_h, rel_w, bufB);
  gemm_bt<5, false, 128><<<dim3(6, 192), 256, 0, stream>>>(bufB, Wproj, proj_b, bufX, bufX, nullptr, MW, 768, 768, nullptr, 6);

  // ---- adapter 2 ----
  ln_k<false><<<MS, 256, 0, stream>>>(bufX, an2_w, an2_b, bufB);
  gemm_bt<1, false, 128><<<dim3(2, 160), 256, 0, stream>>>(bufB, Wad2, ad2_b, nullptr, nullptr, bufD, MS, 192, 768, nullptr, 2);
  gemm_bt<2, true, 64><<<dim3(2, 160), 256, 0, stream>>>(bufD, Wcv2, ac2_b, nullptr, nullptr, bufE, MS, 192, 5184, zrow, 2);
  gemm_bt<3, false, 64><<<dim3(6, 160), 256, 0, stream>>>(bufE, Wau2, au2_b, bufX, bufX, nullptr, MS, 768, 192, nullptr, 6);

  // ---- MLP ----
  ln_k<false><<<MS, 256, 0, stream>>>(bufX, n2_w, n2_b, bufB);
  gemm_bt<2, false, 128><<<dim3(24, 160), 256, 0, stream>>>(bufB, Wm1, mlp_b1, nullptr, nullptr, bufA, MS, 3072, 768, nullptr, 8);
  gemm_bt<3, false, 128><<<dim3(6, 160), 256, 0, stream>>>(bufA, Wm2, mlp_b2, bufX, (float*)d_out, nullptr, MS, 768, 3072, nullptr, 6);
}

// Round 18
// 998.040 us; speedup vs baseline: 1.3470x; 1.0309x over previous
//
#include <hip/hip_runtime.h>

typedef unsigned short u16;
typedef __bf16 v8bf __attribute__((ext_vector_type(8)));
typedef unsigned short v8u __attribute__((ext_vector_type(8)));
typedef unsigned short v4u __attribute__((ext_vector_type(4)));
typedef float f32x4 __attribute__((ext_vector_type(4)));
typedef float f32x16 __attribute__((ext_vector_type(16)));
typedef float v8f __attribute__((ext_vector_type(8)));

static constexpr int DIMC = 768;
static constexpr int HEADS = 12;
static constexpr int WINS  = 14;
static constexpr int ACCH  = 192;   // adapter channels
static constexpr int NTOK  = 196;   // 14*14
static constexpr int MW    = 24500; // 125 windows * 196 tokens
static constexpr int MWP   = 24576; // padded to tile multiple
static constexpr int MS    = 20480; // 5*64*64 spatial tokens

__device__ __forceinline__ float bf2f(u16 u) {
  union { unsigned int i; float f; } x; x.i = ((unsigned int)u) << 16; return x.f;
}
__device__ __forceinline__ u16 f2bf(float f) {
  union { float f; unsigned int i; } x; x.f = f;
  unsigned int r = x.i + 0x7fffu + ((x.i >> 16) & 1u);
  return (u16)(r >> 16);
}
// fast tanh-form GELU: max abs err ~2e-3 (well under threshold)
__device__ __forceinline__ float gelu_f(float x) {
  float y = 0.79788456080286536f * (x + 0.044715f * x * x * x);
  y = fminf(fmaxf(y, -15.f), 15.f);
  const float e = __expf(2.f * y);
  const float th = 1.f - 2.f * __builtin_amdgcn_rcpf(e + 1.f);
  return 0.5f * x * (1.f + th);
}
// async global->LDS, 16B per lane. LDS dest is wave-uniform base + lane*16.
__device__ __forceinline__ void cp16(const u16* g, u16* l) {
  __builtin_amdgcn_global_load_lds(
      (const __attribute__((address_space(1))) unsigned int*)(const void*)g,
      (__attribute__((address_space(3))) unsigned int*)(void*)l, 16, 0, 0);
}

// ---------------- weight prep ----------------
__global__ void k_zero16(u16* p, int n) {
  int i = blockIdx.x * 256 + threadIdx.x;
  if (i < n) p[i] = 0;
}
// U[k][b] = sum_a facu_W[a][k] * fac_W[b][a]   (fac = qfac or vfac)
__global__ void k_compute_U(const float* __restrict__ facu, const float* __restrict__ qfac,
                            const float* __restrict__ vfac, float* __restrict__ Uq,
                            float* __restrict__ Uv) {
  int idx = blockIdx.x * 256 + threadIdx.x;
  if (idx >= 2 * 768 * 32) return;
  const int which = idx / (768 * 32);
  const int rem = idx - which * 768 * 32;
  const int k = rem >> 5, b = rem & 31;
  const float* fac = which ? vfac : qfac;
  float s = 0.f;
  for (int a = 0; a < 32; ++a) s += facu[a * 768 + k] * fac[b * 32 + a];
  (which ? Uv : Uq)[rem] = s;
}
// Wc[n][k] = qkv_W[n][k] (+ sum_b U{q,v}[k][b]*facv_W[n'][b] for q/v blocks), cast bf16
__global__ void k_build_wcomb(const float* __restrict__ qkvW, const float* __restrict__ Uq,
                              const float* __restrict__ Uv, const float* __restrict__ facv,
                              u16* __restrict__ Wc) {
  int idx = blockIdx.x * 256 + threadIdx.x;
  if (idx >= 2304 * 768) return;
  const int n = idx / 768, k = idx - n * 768;
  float v = qkvW[idx];
  if (n < 768) {
    float s = 0.f;
    for (int b = 0; b < 32; ++b) s += Uq[k * 32 + b] * facv[n * 32 + b];
    v += s;
  } else if (n >= 1536) {
    const int nn = n - 1536;
    float s = 0.f;
    for (int b = 0; b < 32; ++b) s += Uv[k * 32 + b] * facv[nn * 32 + b];
    v += s;
  }
  Wc[idx] = f2bf(v);
}
// vectorized cast+pad: 4 elems/thread (cols % 4 == 0 so a group shares its row)
__global__ void k_cast_pad(const float* __restrict__ src, u16* __restrict__ dst,
                           int rows, int cols, int rowsPad) {
  int idx = blockIdx.x * 256 + threadIdx.x;
  const int base = idx * 4;
  if (base >= rowsPad * cols) return;
  const int r = base / cols;
  v4u o;
  if (r < rows) {
    const float4 v = *(const float4*)(src + base);
    o[0] = f2bf(v.x); o[1] = f2bf(v.y); o[2] = f2bf(v.z); o[3] = f2bf(v.w);
  } else {
    o[0] = o[1] = o[2] = o[3] = 0;
  }
  *(v4u*)(dst + base) = o;
}
// ac_W [192][192][3][3][3] -> Wconv [256 pad][27*192] with k = tap*192+ci  (4 ci/thread)
__global__ void k_conv_repack(const float* __restrict__ src, u16* __restrict__ dst) {
  int idx = blockIdx.x * 256 + threadIdx.x;
  const int base = idx * 4;
  if (base >= 256 * 5184) return;
  const int co = base / 5184;
  const int rem = base - co * 5184;
  const int tap = rem / 192, ci = rem - tap * 192;   // ci % 4 == 0 (192 % 4 == 0)
  v4u o;
  if (co < 192) {
    const float* sp = src + co * 5184 + ci * 27 + tap;
#pragma unroll
    for (int e = 0; e < 4; ++e) o[e] = f2bf(sp[e * 27]);
  } else {
    o[0] = o[1] = o[2] = o[3] = 0;
  }
  *(v4u*)(dst + base) = o;
}

// ---------------- LayerNorm (optionally fused window-partition) ----------------
template<bool WINDOWED>
__global__ __launch_bounds__(256)
void ln_k(const float* __restrict__ X, const float* __restrict__ w,
          const float* __restrict__ b, u16* __restrict__ out) {
  const int r = (int)blockIdx.x;
  const int t = (int)threadIdx.x;
  int src = r;
  bool zero = false;
  if (WINDOWED) {
    if (r >= MW) zero = true;
    else {
      const int win = r / NTOK, tk = r - win * NTOK;
      const int img = win / 25, wrem = win - img * 25, wy = wrem / 5, wx = wrem - wy * 5;
      const int ty = tk / WINS, tx = tk - ty * WINS;
      const int y = wy * WINS + ty, x = wx * WINS + tx;
      if (y >= 64 || x >= 64) zero = true;
      else src = (img << 12) + (y << 6) + x;
    }
  }
  u16* orow = out + (size_t)r * DIMC;
  if (zero) {
    for (int c = t; c < DIMC; c += 256) orow[c] = 0;
    return;
  }
  const float* xr = X + (size_t)src * DIMC;
  const float v0 = xr[t], v1 = xr[t + 256], v2 = xr[t + 512];
  float s = v0 + v1 + v2, ss = v0 * v0 + v1 * v1 + v2 * v2;
#pragma unroll
  for (int o = 32; o > 0; o >>= 1) { s += __shfl_xor(s, o, 64); ss += __shfl_xor(ss, o, 64); }
  __shared__ float red[8];
  const int wave = t >> 6, lane = t & 63;
  if (lane == 0) { red[wave] = s; red[4 + wave] = ss; }
  __syncthreads();
  s = red[0] + red[1] + red[2] + red[3];
  ss = red[4] + red[5] + red[6] + red[7];
  const float mean = s * (1.0f / 768.0f);
  const float var = ss * (1.0f / 768.0f) - mean * mean;
  const float rstd = rsqrtf(var + 1e-5f);
  orow[t]       = f2bf((v0 - mean) * rstd * w[t]       + b[t]);
  orow[t + 256] = f2bf((v1 - mean) * rstd * w[t + 256] + b[t + 256]);
  orow[t + 512] = f2bf((v2 - mean) * rstd * w[t + 512] + b[t + 512]);
}

// ---------------- GEMM: C[M,N] = A[M,K] @ B[N,K]^T (+bias, epilogues) ----------------
// EPI: 1 = bf16 out (bias); 2 = bf16 out (bias+GELU); 3 = f32 out (bias+residual);
//      4 = bf16 qkv-scatter per (win,head); 5 = f32 window-unpartition + in-place resid add
// CONV: A rows gathered as 3x3x3 SAME conv over [5][64][64][192]; K = tap*192+ci (BK=64 only)
// BK=64: 16x16x32 MFMA. BK=128: 32x32x16 MFMA, LDS 64 KB, same 2 blk/CU.
// Block swizzle: XCD-chunked + bn-grouping GN. Epilogue: LDS-staged vectorized stores.
template<int EPI, bool CONV, int BK>
__global__ __launch_bounds__(256)
void gemm_bt(const u16* __restrict__ A, const u16* __restrict__ B,
             const float* __restrict__ bias, const float* __restrict__ resid,
             float* __restrict__ outF, u16* __restrict__ outB,
             int M, int N, int K, const u16* __restrict__ zrow, int GN) {
  __shared__ u16 smem[2 * 128 * BK];
  u16* At = smem;
  u16* Bt = smem + 128 * BK;
  const int gx = (int)gridDim.x;
  const int nwg = gx * (int)gridDim.y;
  const int lin = (int)blockIdx.y * gx + (int)blockIdx.x;
  const int csz = nwg >> 3;            // blocks per XCD chunk
  const int xcd = lin & 7;
  const int c = lin >> 3;              // position within chunk
  const int bmc = csz / gx;            // bm rows per chunk
  const int gsz = bmc * GN;
  const int grp = c / gsz, rr = c - grp * gsz;
  const int bn = grp * GN + (rr % GN);
  const int bm = xcd * bmc + (rr / GN);
  const int t = (int)threadIdx.x;
  const int wave = t >> 6, lane = t & 63;
  const int wm = wave >> 1, wn = wave & 1;
  const int li = lane & 15, lq = lane >> 4;
  const int l31 = lane & 31, lh = lane >> 5;

  f32x4 acc[4][4];        // BK==64 accumulators (16x16 blocks)
  f32x16 acc32[2][2];     // BK==128 accumulators (32x32 blocks)
  const f32x4 vzero = {0.f, 0.f, 0.f, 0.f};
  if (BK == 64) {
#pragma unroll
    for (int a = 0; a < 4; ++a)
#pragma unroll
      for (int b = 0; b < 4; ++b) acc[a][b] = vzero;
  } else {
#pragma unroll
    for (int a = 0; a < 2; ++a)
#pragma unroll
      for (int b = 0; b < 2; ++b)
#pragma unroll
        for (int e = 0; e < 16; ++e) acc32[a][b][e] = 0.f;
  }

  const int nk = K / BK;
  for (int kt = 0; kt < nk; ++kt) {
    if (BK == 64) {
      const int lrow = lane >> 3;                // 0..7
      const int c16s = (lane & 7) ^ lrow;        // pre-swizzled source chunk
      int cD = 0, cY = 0, cX = 0, cblk = 0;
      if (CONV) {
        const int tap = kt / 3;
        cblk = (kt - tap * 3) << 6;
        const int kd = tap / 9, r9 = tap - kd * 9, ky = r9 / 3;
        cD = kd - 1; cY = ky - 1; cX = (r9 - ky * 3) - 1;
      }
#pragma unroll
      for (int i = 0; i < 4; ++i) {           // stage A: 128x64 bf16
        const int r0 = i * 32 + wave * 8;
        const int grow = bm * 128 + r0 + lrow;
        const u16* src;
        if (CONV) {
          const int d = (grow >> 12) + cD, y = ((grow >> 6) & 63) + cY, x = (grow & 63) + cX;
          if ((unsigned)d < 5u && (unsigned)y < 64u && (unsigned)x < 64u)
            src = A + (size_t)((d << 12) + (y << 6) + x) * ACCH + cblk + c16s * 8;
          else
            src = zrow + c16s * 8;
        } else {
          src = A + (size_t)grow * K + (kt << 6) + c16s * 8;
        }
        cp16(src, &At[r0 * 64]);
      }
#pragma unroll
      for (int i = 0; i < 4; ++i) {           // stage B: 128x64 bf16
        const int r0 = i * 32 + wave * 8;
        const int grow = bn * 128 + r0 + lrow;
        cp16(B + (size_t)grow * K + (kt << 6) + c16s * 8, &Bt[r0 * 64]);
      }
    } else {  // BK == 128: rows of 16 chunks; store chunk c at phys c^(row&15)
      const int srow4 = lane >> 4;               // 0..3 (4 rows per cp16)
      const int sc = lane & 15;                  // phys chunk
#pragma unroll
      for (int i = 0; i < 8; ++i) {           // stage A: 128x128 bf16
        const int rbase = i * 16 + wave * 4;
        const int row = rbase + srow4;
        const int c16s = sc ^ (row & 15);        // logical source chunk
        cp16(A + (size_t)(bm * 128 + row) * K + kt * 128 + c16s * 8, &At[rbase * 128]);
      }
#pragma unroll
      for (int i = 0; i < 8; ++i) {           // stage B: 128x128 bf16
        const int rbase = i * 16 + wave * 4;
        const int row = rbase + srow4;
        const int c16s = sc ^ (row & 15);
        cp16(B + (size_t)(bn * 128 + row) * K + kt * 128 + c16s * 8, &Bt[rbase * 128]);
      }
    }
    __syncthreads();                         // drains vmcnt for global_load_lds
    if (BK == 64) {
#pragma unroll
      for (int kk = 0; kk < 2; ++kk) {
        v8bf af[4], bg[4];
#pragma unroll
        for (int mf = 0; mf < 4; ++mf) {
          const int row = wm * 64 + mf * 16 + li;
          const int c16 = (kk * 4 + lq) ^ (li & 7);
          af[mf] = *(const v8bf*)&At[row * 64 + c16 * 8];
        }
#pragma unroll
        for (int nf = 0; nf < 4; ++nf) {
          const int row = wn * 64 + nf * 16 + li;
          const int c16 = (kk * 4 + lq) ^ (li & 7);
          bg[nf] = *(const v8bf*)&Bt[row * 64 + c16 * 8];
        }
#pragma unroll
        for (int mf = 0; mf < 4; ++mf)
#pragma unroll
          for (int nf = 0; nf < 4; ++nf)
            acc[mf][nf] = __builtin_amdgcn_mfma_f32_16x16x32_bf16(af[mf], bg[nf], acc[mf][nf], 0, 0, 0);
      }
    } else {  // 32x32x16: lane holds A[row=l31][k=lh*8+e]; same mapping for B
#pragma unroll
      for (int kk = 0; kk < 8; ++kk) {
        const int ch = kk * 2 + lh;              // logical chunk (8 k-elems)
        v8bf a2[2], b2[2];
#pragma unroll
        for (int mb = 0; mb < 2; ++mb) {
          const int row = wm * 64 + mb * 32 + l31;
          a2[mb] = *(const v8bf*)&At[row * 128 + (ch ^ (row & 15)) * 8];
        }
#pragma unroll
        for (int nb = 0; nb < 2; ++nb) {
          const int row = wn * 64 + nb * 32 + l31;
          b2[nb] = *(const v8bf*)&Bt[row * 128 + (ch ^ (row & 15)) * 8];
        }
#pragma unroll
        for (int mb = 0; mb < 2; ++mb)
#pragma unroll
          for (int nb = 0; nb < 2; ++nb)
            acc32[mb][nb] = __builtin_amdgcn_mfma_f32_32x32x16_bf16(a2[mb], b2[nb], acc32[mb][nb], 0, 0, 0);
      }
    }
    __syncthreads();
  }

  // ---- epilogue: stage C through LDS, vectorized stores ----
  // 32x32 C/D mapping: col = lane&31, row = (reg&3) + 8*(reg>>2) + 4*(lane>>5)
  if (EPI == 1 || EPI == 2 || EPI == 4) {
    u16* Ct = smem;  // [128][128] bf16, col ^ ((row&7)<<3)
    if (BK == 64) {
#pragma unroll
      for (int mf = 0; mf < 4; ++mf)
#pragma unroll
        for (int nf = 0; nf < 4; ++nf)
#pragma unroll
          for (int r = 0; r < 4; ++r) {
            const int row = wm * 64 + mf * 16 + lq * 4 + r;
            const int col = wn * 64 + nf * 16 + li;
            float v = acc[mf][nf][r] + bias[bn * 128 + col];
            if (EPI == 2) v = gelu_f(v);
            Ct[row * 128 + (col ^ ((row & 7) << 3))] = f2bf(v);
          }
    } else {
#pragma unroll
      for (int mb = 0; mb < 2; ++mb)
#pragma unroll
        for (int nb = 0; nb < 2; ++nb)
#pragma unroll
          for (int rg = 0; rg < 16; ++rg) {
            const int row = wm * 64 + mb * 32 + (rg & 3) + 8 * (rg >> 2) + 4 * lh;
            const int col = wn * 64 + nb * 32 + l31;
            float v = acc32[mb][nb][rg] + bias[bn * 128 + col];
            if (EPI == 2) v = gelu_f(v);
            Ct[row * 128 + (col ^ ((row & 7) << 3))] = f2bf(v);
          }
    }
    __syncthreads();
#pragma unroll
    for (int it = 0; it < 8; ++it) {
      const int row = it * 16 + (t >> 4);
      const int seg = t & 15;
      const int gr = bm * 128 + row;
      const int col8 = bn * 128 + seg * 8;
      if (gr < M && col8 < N) {
        v8u val = *(const v8u*)&Ct[row * 128 + ((seg ^ (row & 7)) * 8)];
        if (EPI == 4) {
          const int sec = col8 / 768;
          const int hm = col8 - sec * 768;
          const int hd = hm >> 6, dd = hm & 63;
          const int win = gr / 196, tk = gr - win * 196;
          *(v8u*)(outB + (size_t)(((win * HEADS + hd) * 3 + sec) * NTOK + tk) * 64 + dd) = val;
        } else {
          *(v8u*)(outB + (size_t)gr * N + col8) = val;
        }
      }
    }
  } else {  // EPI 3 / 5: f32, two wm-halves through [64][128] f32 tile
    float* Cf = (float*)smem;
#pragma unroll
    for (int h2 = 0; h2 < 2; ++h2) {
      if (h2) __syncthreads();               // half-0 reads done before overwrite
      if (wm == h2) {
        if (BK == 64) {
#pragma unroll
          for (int mf = 0; mf < 4; ++mf)
#pragma unroll
            for (int nf = 0; nf < 4; ++nf)
#pragma unroll
              for (int r = 0; r < 4; ++r) {
                const int row = mf * 16 + lq * 4 + r;      // 0..63 within half
                const int col = wn * 64 + nf * 16 + li;
                const float v = acc[mf][nf][r] + bias[bn * 128 + col];
                Cf[row * 128 + (col ^ (((row >> 2) & 3) << 3))] = v;
              }
        } else {
#pragma unroll
          for (int mb = 0; mb < 2; ++mb)
#pragma unroll
            for (int nb = 0; nb < 2; ++nb)
#pragma unroll
              for (int rg = 0; rg < 16; ++rg) {
                const int row = mb * 32 + (rg & 3) + 8 * (rg >> 2) + 4 * lh;  // 0..63
                const int col = wn * 64 + nb * 32 + l31;
                const float v = acc32[mb][nb][rg] + bias[bn * 128 + col];
                Cf[row * 128 + (col ^ (((row >> 2) & 3) << 3))] = v;
              }
        }
      }
      __syncthreads();
#pragma unroll
      for (int it = 0; it < 4; ++it) {
        const int row = it * 16 + (t >> 4);              // 0..63
        const int seg = t & 15;
        const int gr = bm * 128 + h2 * 64 + row;
        const int col8 = bn * 128 + seg * 8;
        if (gr < M && col8 < N) {
          v8f val = *(const v8f*)&Cf[row * 128 + ((seg ^ ((row >> 2) & 3)) * 8)];
          if (EPI == 3) {
            const float* rp = resid + (size_t)gr * N + col8;
#pragma unroll
            for (int e = 0; e < 8; ++e) val[e] += rp[e];
            *(v8f*)(outF + (size_t)gr * N + col8) = val;
          } else {  // EPI 5: window-unpartition + in-place residual add
            const int win = gr / 196, tk = gr - win * 196;
            const int img = win / 25, wrem = win - img * 25, wy = wrem / 5, wx = wrem - wy * 5;
            const int ty = tk / WINS, tx = tk - ty * WINS;
            const int y = wy * WINS + ty, x = wx * WINS + tx;
            if (y < 64 && x < 64) {
              const size_t o = (size_t)((img << 12) + (y << 6) + x) * DIMC + col8;
              const float* rp = resid + o;
#pragma unroll
              for (int e = 0; e < 8; ++e) val[e] += rp[e];
              *(v8f*)(outF + o) = val;
            }
          }
        }
      }
    }
  }
}

// ---------------- fused windowed attention, MFMA flash-style, 4 waves ----------------
// block = (win, head, row-half): 256 threads; global wave gw = rh*4 + w owns rows
// [32*gw, 32*gw+32). 3 blocks/CU co-resident (regs ~148, LDS 39 KB) vs 1 for 512-thr.
// qkvR layout per (win,head): [Q(196x64) | K(196x64) | V(196x64)]
__global__ __launch_bounds__(256, 3)
void attn_k(const u16* __restrict__ qkvR, const float* __restrict__ relh,
            const float* __restrict__ relw, u16* __restrict__ out) {
  const int blk = (int)blockIdx.x;
  const int rh = blk & 1;
  const int wh = blk >> 1;
  const int win = wh / HEADS, h = wh - win * HEADS;
  const int t = (int)threadIdx.x, w = t >> 6, lane = t & 63;
  const int gw = rh * 4 + w;                       // global row-group 0..7
  const int li = lane & 15, g = lane >> 4;
  const int nmf = (gw < 6) ? 2 : (gw == 6 ? 1 : 0); // valid 16-row fragments this wave

  __shared__ u16 Kt[64 * 64];     // 8 KB [j][d], swizzled (cp16 linear dest)
  __shared__ u16 Vt[64 * 64];     // 8 KB [d][j], seg-XOR swizzled
  __shared__ u16 Pb[4 * 32 * 32]; // 8 KB per-wave P/O chunks; aliases rel buf in phase A
  __shared__ u16 dhwT[28 * 268];  // 15 KB: rows 0..13 = dh[jh][i], 14..27 = dw[jw][i]

  const u16* Qb = qkvR + (size_t)(win * HEADS + h) * 3 * NTOK * 64;
  const u16* Kb = Qb + NTOK * 64;
  const u16* Vb = Kb + NTOK * 64;

  // ---- Q fragments in registers: qf[mf][ks], rows clamped to 195 ----
  v8bf qf[2][2];
#pragma unroll
  for (int mf = 0; mf < 2; ++mf) {
    const int row = min(32 * gw + mf * 16 + li, NTOK - 1);
#pragma unroll
    for (int ks = 0; ks < 2; ++ks)
      qf[mf][ks] = *(const v8bf*)(Qb + (size_t)row * 64 + ks * 32 + g * 8);
  }

  // ---- stage rel tables into Pb (phase-A alias; exactly 8 KB) ----
  u16* relb = Pb; // [2][32 rows][64 cols], swizzled like Kt
  for (int idx = t; idx < 2 * 32 * 64; idx += 256) {
    const int which = idx >> 11, rem = idx & 2047, r = rem >> 6, c = rem & 63;
    const float v = (r < 27) ? (which ? relw[r * 64 + c] : relh[r * 64 + c]) : 0.f;
    relb[which * 2048 + r * 64 + (((c >> 3) ^ (r & 7)) * 8) + (c & 7)] = f2bf(v);
  }
  __syncthreads();

  // ---- phase A: rel-pos tables via MFMA (own rows only), scatter into dhwT ----
  {
    f32x4 dacc[2][2], eacc[2][2];
    const f32x4 vz = {0.f, 0.f, 0.f, 0.f};
#pragma unroll
    for (int mf = 0; mf < 2; ++mf)
#pragma unroll
      for (int nf = 0; nf < 2; ++nf) { dacc[mf][nf] = vz; eacc[mf][nf] = vz; }
#pragma unroll
    for (int ks = 0; ks < 2; ++ks) {
#pragma unroll
      for (int nf = 0; nf < 2; ++nf) {
        const int row = nf * 16 + li;
        const int off = row * 64 + (((ks * 4 + g) ^ (li & 7)) * 8);
        v8bf bh = *(const v8bf*)&relb[off];
        v8bf bw = *(const v8bf*)&relb[2048 + off];
#pragma unroll
        for (int mf = 0; mf < 2; ++mf) if (mf < nmf) {
          dacc[mf][nf] = __builtin_amdgcn_mfma_f32_16x16x32_bf16(qf[mf][ks], bh, dacc[mf][nf], 0, 0, 0);
          eacc[mf][nf] = __builtin_amdgcn_mfma_f32_16x16x32_bf16(qf[mf][ks], bw, eacc[mf][nf], 0, 0, 0);
        }
      }
    }
    // scatter D,E -> dhwT[jh][i] / dhwT[14+jw][i] (bijective per row)
#pragma unroll
    for (int mf = 0; mf < 2; ++mf) if (mf < nmf)
#pragma unroll
      for (int nf = 0; nf < 2; ++nf)
#pragma unroll
        for (int r = 0; r < 4; ++r) {
          const int i = 32 * gw + mf * 16 + 4 * g + r;
          if (i < 196) {
            const int c = nf * 16 + li;
            const int ih = (i * 2341) >> 15, iw = i - ih * 14;
            const int jh = ih + 13 - c;
            if ((unsigned)jh < 14u) dhwT[jh * 268 + i] = f2bf(dacc[mf][nf][r]);
            const int jw = iw + 13 - c;
            if ((unsigned)jw < 14u) dhwT[(14 + jw) * 268 + i] = f2bf(eacc[mf][nf][r]);
          }
        }
  }
  __syncthreads();   // phase-A reads of relb done; Pb free for P chunks

  // ---- phase B: flash over 4 j-tiles of 64 ----
  f32x4 oacc[2][4];
  const f32x4 vz = {0.f, 0.f, 0.f, 0.f};
#pragma unroll
  for (int a = 0; a < 2; ++a)
#pragma unroll
    for (int b = 0; b < 4; ++b) oacc[a][b] = vz;
  float mrun[8], lrun[8];
#pragma unroll
  for (int a = 0; a < 8; ++a) { mrun[a] = -1e30f; lrun[a] = 0.f; }

  u16* Pw = Pb + w * 1024; // own chunk [32 i][32 j]
  const int jv = t & 63;   // V-staging: column j
  const int dv = (t >> 6) * 16;  // V-staging: 16-d slab per wave

  for (int jt = 0; jt < 4; ++jt) {
    const int j0 = jt * 64;
    const int njf = (jt < 3) ? 4 : 1;    // valid 16-col j-fragments
    const int nhalf = (jt < 3) ? 2 : 1;  // valid 32-col PV halves

    // stage K FIRST (oldest vm ops): 4 waves x 16 rows = 64 rows, two cp16 each
#pragma unroll
    for (int is = 0; is < 2; ++is) {
      const int rbase = w * 16 + is * 8;
      const int row = rbase + (lane >> 3);
      const int jg = min(j0 + row, NTOK - 1);
      const int cbs = (lane & 7) ^ (row & 7);
      cp16(Kb + (size_t)jg * 64 + cbs * 8, &Kt[rbase * 64]);
    }
    __builtin_amdgcn_sched_barrier(0);       // pin: K issued before V
    // V prefetch into regs (newest vm ops; ride through the K wait)
    const int jgv = min(j0 + jv, NTOK - 1);
    const u16* vp = Vb + (size_t)jgv * 64 + dv;
    v8u vg0 = *(const v8u*)vp;
    v8u vg1 = *(const v8u*)(vp + 8);
    __builtin_amdgcn_sched_barrier(0);
    asm volatile("s_waitcnt vmcnt(2)" ::: "memory");   // K landed; V still in flight
    __builtin_amdgcn_sched_barrier(0);
    __builtin_amdgcn_s_barrier();            // Kt visible to all waves
    __builtin_amdgcn_sched_barrier(0);

    // QK^T (Q from registers) — V latency hides under this
    f32x4 sacc[2][4];
#pragma unroll
    for (int a = 0; a < 2; ++a)
#pragma unroll
      for (int b = 0; b < 4; ++b) sacc[a][b] = vz;
    if (nmf > 0) {
#pragma unroll
      for (int ks = 0; ks < 2; ++ks) {
#pragma unroll
        for (int jf = 0; jf < 4; ++jf) if (jf < njf) {
          const int row = jf * 16 + li;
          v8bf kb = *(const v8bf*)&Kt[row * 64 + (((ks * 4 + g) ^ (li & 7)) * 8)];
#pragma unroll
          for (int mf = 0; mf < 2; ++mf) if (mf < nmf)
            sacc[mf][jf] = __builtin_amdgcn_mfma_f32_16x16x32_bf16(qf[mf][ks], kb, sacc[mf][jf], 0, 0, 0);
        }
      }
    }

    // V regs -> Vt (seg-XOR swizzled); visible to all waves at the pre-PV barrier
    asm volatile("s_waitcnt vmcnt(0)" ::: "memory");
    __builtin_amdgcn_sched_barrier(0);
#pragma unroll
    for (int e = 0; e < 8; ++e) {
      const int da = dv + e, db = dv + 8 + e;
      Vt[da * 64 + (((jv >> 3) ^ (da & 7)) * 8) + (jv & 7)] = vg0[e];
      Vt[db * 64 + (((jv >> 3) ^ (db & 7)) * 8) + (jv & 7)] = vg1[e];
    }

    // bias + mask (vectorized b64 reads from dhwT)
#pragma unroll
    for (int jf = 0; jf < 4; ++jf) if (jf < njf) {
      const int j = j0 + jf * 16 + li;
      const bool jok = j < 196;
      int jh = (j * 2341) >> 15;
      const int jw = j - jh * 14;
      if (jh > 13) jh = 13;                  // clamp for padded j (masked below)
#pragma unroll
      for (int mf = 0; mf < 2; ++mf) if (mf < nmf) {
        const int i0 = 32 * gw + mf * 16 + 4 * g;
        v4u hv = *(const v4u*)&dhwT[jh * 268 + i0];
        v4u wv = *(const v4u*)&dhwT[(14 + jw) * 268 + i0];
#pragma unroll
        for (int r = 0; r < 4; ++r) {
          float v;
          if (jok && (i0 + r) < 196)
            v = sacc[mf][jf][r] * 0.125f + bf2f(hv[r]) + bf2f(wv[r]);
          else v = -1e30f;
          sacc[mf][jf][r] = v;
        }
      }
    }

    // online softmax update
#pragma unroll
    for (int mf = 0; mf < 2; ++mf) if (mf < nmf)
#pragma unroll
      for (int r = 0; r < 4; ++r) {
        float tmx = -1e30f;
#pragma unroll
        for (int jf = 0; jf < 4; ++jf) if (jf < njf) tmx = fmaxf(tmx, sacc[mf][jf][r]);
#pragma unroll
        for (int o = 1; o < 16; o <<= 1) tmx = fmaxf(tmx, __shfl_xor(tmx, o, 16));
        const int idx = mf * 4 + r;
        const float mnew = fmaxf(mrun[idx], tmx);
        const float sf = __expf(mrun[idx] - mnew);
        mrun[idx] = mnew;
        float ls = 0.f;
#pragma unroll
        for (int jf = 0; jf < 4; ++jf) if (jf < njf) {
          const float p = __expf(sacc[mf][jf][r] - mnew);
          sacc[mf][jf][r] = p;
          ls += p;
        }
#pragma unroll
        for (int o = 1; o < 16; o <<= 1) ls += __shfl_xor(ls, o, 16);
        lrun[idx] = lrun[idx] * sf + ls;
#pragma unroll
        for (int nf = 0; nf < 4; ++nf) oacc[mf][nf][r] *= sf;
      }

    // P chunks (32i x 32j per half) -> PV, two halves; own-wave lgkm ordering
#pragma unroll
    for (int half = 0; half < 2; ++half) if (half < nhalf) {
#pragma unroll
      for (int c = 0; c < 2; ++c) {
        const int jf = half * 2 + c;
        const int jloc = c * 16 + li;
#pragma unroll
        for (int mf = 0; mf < 2; ++mf)
#pragma unroll
          for (int r = 0; r < 4; ++r) {
            const int il = mf * 16 + 4 * g + r;
            u16 pv = 0;
            if (mf < nmf && jf < njf) pv = f2bf(sacc[mf][jf][r]);
            Pw[il * 32 + (jloc ^ (g << 3))] = pv;
          }
      }
      if (half == 0) __syncthreads();        // Vt (all waves) + own P visible before PV
      // PV: O[i][d] += P[i][j-half] * V[j-half][d]   (K = 32 -> one MFMA per (mf,nf))
      if (nmf > 0) {
        v8bf pa[2];
#pragma unroll
        for (int mf = 0; mf < 2; ++mf) {
          const int row = mf * 16 + li;
          pa[mf] = *(const v8bf*)&Pw[row * 32 + ((g ^ ((li >> 2) & 3)) * 8)];
        }
#pragma unroll
        for (int nf = 0; nf < 4; ++nf) {
          const int d = nf * 16 + li;
          v8bf vb = *(const v8bf*)&Vt[d * 64 + (((half * 4 + g) ^ (li & 7)) * 8)];
#pragma unroll
          for (int mf = 0; mf < 2; ++mf)
            oacc[mf][nf] = __builtin_amdgcn_mfma_f32_16x16x32_bf16(pa[mf], vb, oacc[mf][nf], 0, 0, 0);
        }
      }
    }
    __syncthreads();   // everyone done with Kt/Vt before next tile's staging
  }

  // ---- epilogue: per d-half, transpose through own chunk, 16B stores ----
  if (nmf > 0) {
    float rinv[8];
#pragma unroll
    for (int a = 0; a < 8; ++a) rinv[a] = 1.0f / lrun[a];
#pragma unroll
    for (int half = 0; half < 2; ++half) {
#pragma unroll
      for (int c = 0; c < 2; ++c) {
        const int nf = half * 2 + c;
        const int dloc = c * 16 + li;
#pragma unroll
        for (int mf = 0; mf < 2; ++mf)
#pragma unroll
          for (int r = 0; r < 4; ++r) {
            const int il = mf * 16 + 4 * g + r;
            float val = (mf < nmf) ? oacc[mf][nf][r] * rinv[mf * 4 + r] : 0.f;
            Pw[il * 32 + (dloc ^ (g << 3))] = f2bf(val);
          }
      }
#pragma unroll
      for (int p = 0; p < 2; ++p) {
        const int row = p * 16 + (lane >> 2);
        const int seg = lane & 3;
        const int i = 32 * gw + row;
        if (i < 196) {
          const int segp = seg ^ ((row >> 2) & 3);
          v8u val = *(const v8u*)&Pw[row * 32 + segp * 8];
          *(v8u*)(out + (size_t)(win * NTOK + i) * DIMC + h * 64 + half * 32 + seg * 8) = val;
        }
      }
    }
  }
}

extern "C" void kernel_launch(void* const* d_in, const int* in_sizes, int n_in,
                              void* d_out, int out_size, void* d_ws, size_t ws_size,
                              hipStream_t stream) {
  (void)in_sizes; (void)n_in; (void)out_size; (void)ws_size;
  const float* x0     = (const float*)d_in[0];
  const float* an1_w  = (const float*)d_in[1];
  const float* an1_b  = (const float*)d_in[2];
  const float* ad1_W  = (const float*)d_in[3];
  const float* ad1_b  = (const float*)d_in[4];
  const float* ac1_W  = (const float*)d_in[5];
  const float* ac1_b  = (const float*)d_in[6];
  const float* au1_W  = (const float*)d_in[7];
  const float* au1_b  = (const float*)d_in[8];
  const float* an2_w  = (const float*)d_in[9];
  const float* an2_b  = (const float*)d_in[10];
  const float* ad2_W  = (const float*)d_in[11];
  const float* ad2_b  = (const float*)d_in[12];
  const float* ac2_W  = (const float*)d_in[13];
  const float* ac2_b  = (const float*)d_in[14];
  const float* au2_W  = (const float*)d_in[15];
  const float* au2_b  = (const float*)d_in[16];
  const float* n1_w   = (const float*)d_in[17];
  const float* n1_b   = (const float*)d_in[18];
  const float* qkv_W  = (const float*)d_in[19];
  const float* qkv_b  = (const float*)d_in[20];
  const float* facu_W = (const float*)d_in[21];
  const float* facv_W = (const float*)d_in[22];
  const float* qfac_W = (const float*)d_in[23];
  const float* vfac_W = (const float*)d_in[24];
  const float* rel_h  = (const float*)d_in[25];
  const float* rel_w  = (const float*)d_in[26];
  const float* proj_W = (const float*)d_in[27];
  const float* proj_b = (const float*)d_in[28];
  const float* n2_w   = (const float*)d_in[29];
  const float* n2_b   = (const float*)d_in[30];
  const float* mlp_W1 = (const float*)d_in[31];
  const float* mlp_b1 = (const float*)d_in[32];
  const float* mlp_W2 = (const float*)d_in[33];
  const float* mlp_b2 = (const float*)d_in[34];

  char* ws = (char*)d_ws;
  size_t off = 0;
  auto alloc = [&](size_t bytes) -> void* {
    void* p = (void*)(ws + off);
    off += (bytes + 255) & ~(size_t)255;
    return p;
  };
  u16*  bufA  = (u16*)alloc((size_t)MS * 3072 * 2);      // qkvR bf16 / mlp hidden bf16
  u16*  bufB  = (u16*)alloc((size_t)MWP * DIMC * 2);     // LN/window tokens + attn out, bf16
  float* bufX = (float*)alloc((size_t)MS * DIMC * 4);    // residual stream f32
  u16*  bufD  = (u16*)alloc((size_t)MS * ACCH * 2);      // adapter down out
  u16*  bufE  = (u16*)alloc((size_t)MS * ACCH * 2);      // adapter conv+gelu out
  u16*  Wcomb = (u16*)alloc((size_t)2304 * 768 * 2);
  u16*  Wproj = (u16*)alloc((size_t)768 * 768 * 2);
  u16*  Wm1   = (u16*)alloc((size_t)3072 * 768 * 2);
  u16*  Wm2   = (u16*)alloc((size_t)768 * 3072 * 2);
  u16*  Wad1  = (u16*)alloc((size_t)256 * 768 * 2);
  u16*  Wau1  = (u16*)alloc((size_t)768 * 192 * 2);
  u16*  Wcv1  = (u16*)alloc((size_t)256 * 5184 * 2);
  u16*  Wad2  = (u16*)alloc((size_t)256 * 768 * 2);
  u16*  Wau2  = (u16*)alloc((size_t)768 * 192 * 2);
  u16*  Wcv2  = (u16*)alloc((size_t)256 * 5184 * 2);
  float* Uq   = (float*)alloc(768 * 32 * 4);
  float* Uv   = (float*)alloc(768 * 32 * 4);
  u16*  zrow  = (u16*)alloc(256);

  // ---- weight prep (every launch; deterministic) ----
  k_zero16<<<1, 256, 0, stream>>>(zrow, 128);
  k_compute_U<<<192, 256, 0, stream>>>(facu_W, qfac_W, vfac_W, Uq, Uv);
  k_build_wcomb<<<(2304 * 768 + 255) / 256, 256, 0, stream>>>(qkv_W, Uq, Uv, facv_W, Wcomb);
  k_cast_pad<<<(768 * 768 / 4 + 255) / 256, 256, 0, stream>>>(proj_W, Wproj, 768, 768, 768);
  k_cast_pad<<<(3072 * 768 / 4 + 255) / 256, 256, 0, stream>>>(mlp_W1, Wm1, 3072, 768, 3072);
  k_cast_pad<<<(768 * 3072 / 4 + 255) / 256, 256, 0, stream>>>(mlp_W2, Wm2, 768, 3072, 768);
  k_cast_pad<<<(256 * 768 / 4 + 255) / 256, 256, 0, stream>>>(ad1_W, Wad1, 192, 768, 256);
  k_cast_pad<<<(768 * 192 / 4 + 255) / 256, 256, 0, stream>>>(au1_W, Wau1, 768, 192, 768);
  k_cast_pad<<<(256 * 768 / 4 + 255) / 256, 256, 0, stream>>>(ad2_W, Wad2, 192, 768, 256);
  k_cast_pad<<<(768 * 192 / 4 + 255) / 256, 256, 0, stream>>>(au2_W, Wau2, 768, 192, 768);
  k_conv_repack<<<(256 * 5184 / 4 + 255) / 256, 256, 0, stream>>>(ac1_W, Wcv1);
  k_conv_repack<<<(256 * 5184 / 4 + 255) / 256, 256, 0, stream>>>(ac2_W, Wcv2);

  // ---- adapter 1: x1 = x0 + up(gelu(conv(down(LN(x0))))) ----
  ln_k<false><<<MS, 256, 0, stream>>>(x0, an1_w, an1_b, bufB);
  gemm_bt<1, false, 128><<<dim3(2, 160), 256, 0, stream>>>(bufB, Wad1, ad1_b, nullptr, nullptr, bufD, MS, 192, 768, nullptr, 2);
  gemm_bt<2, true, 64><<<dim3(2, 160), 256, 0, stream>>>(bufD, Wcv1, ac1_b, nullptr, nullptr, bufE, MS, 192, 5184, zrow, 2);
  gemm_bt<3, false, 64><<<dim3(6, 160), 256, 0, stream>>>(bufE, Wau1, au1_b, x0, bufX, nullptr, MS, 768, 192, nullptr, 6);

  // ---- windowed attention ----
  ln_k<true><<<MWP, 256, 0, stream>>>(bufX, n1_w, n1_b, bufB);
  gemm_bt<4, false, 128><<<dim3(18, 192), 256, 0, stream>>>(bufB, Wcomb, qkv_b, nullptr, nullptr, bufA, MW, 2304, 768, nullptr, 6);
  attn_k<<<125 * HEADS * 2, 256, 0, stream>>>(bufA, rel_h, rel_w, bufB);
  gemm_bt<5, false, 128><<<dim3(6, 192), 256, 0, stream>>>(bufB, Wproj, proj_b, bufX, bufX, nullptr, MW, 768, 768, nullptr, 6);

  // ---- adapter 2 ----
  ln_k<false><<<MS, 256, 0, stream>>>(bufX, an2_w, an2_b, bufB);
  gemm_bt<1, false, 128><<<dim3(2, 160), 256, 0, stream>>>(bufB, Wad2, ad2_b, nullptr, nullptr, bufD, MS, 192, 768, nullptr, 2);
  gemm_bt<2, true, 64><<<dim3(2, 160), 256, 0, stream>>>(bufD, Wcv2, ac2_b, nullptr, nullptr, bufE, MS, 192, 5184, zrow, 2);
  gemm_bt<3, false, 64><<<dim3(6, 160), 256, 0, stream>>>(bufE, Wau2, au2_b, bufX, bufX, nullptr, MS, 768, 192, nullptr, 6);

  // ---- MLP ----
  ln_k<false><<<MS, 256, 0, stream>>>(bufX, n2_w, n2_b, bufB);
  gemm_bt<2, false, 128><<<dim3(24, 160), 256, 0, stream>>>(bufB, Wm1, mlp_b1, nullptr, nullptr, bufA, MS, 3072, 768, nullptr, 8);
  gemm_bt<3, false, 128><<<dim3(6, 160), 256, 0, stream>>>(bufA, Wm2, mlp_b2, bufX, (float*)d_out, nullptr, MS, 768, 3072, nullptr, 6);
}